// Round 2
// baseline (971.154 us; speedup 1.0000x reference)
//
#include <hip/hip_runtime.h>
#include <hip/hip_bf16.h>
#include <stdint.h>

typedef __bf16 bf16;
typedef __bf16 bf16x8 __attribute__((ext_vector_type(8)));
typedef __bf16 bf16x4 __attribute__((ext_vector_type(4)));
typedef float f32x4v __attribute__((ext_vector_type(4)));

#define SEQ    2048
#define DMODEL 2048
#define DI     4096
#define NH     64
#define PDIM   64
#define CHUNKL 128
#define NCH    16
#define CONVD  4352
#define DPROJ  8512
#define DPROJP 8576
#define NTOK   4096

__device__ __forceinline__ float sigmoid_f(float x){ return 1.f/(1.f+expf(-x)); }
__device__ __forceinline__ float silu_f(float x){ return x*sigmoid_f(x); }
__device__ __forceinline__ float softplus_f(float x){ return x > 20.f ? x : log1pf(expf(x)); }

// ---------------- conversions ----------------
__global__ __launch_bounds__(256) void cvt_f32_bf16(const float* __restrict__ src,
                                                    bf16* __restrict__ dst, int n){
    int i = (blockIdx.x*256 + threadIdx.x)*4;
    if (i + 3 >= n) return;
    float4 v = *(const float4*)&src[i];
    bf16x4 o; o[0]=(bf16)v.x; o[1]=(bf16)v.y; o[2]=(bf16)v.z; o[3]=(bf16)v.w;
    *(bf16x4*)&dst[i] = o;
}

// W_in (8512x2048) -> bf16 padded to 8576 rows (zeros)
__global__ __launch_bounds__(256) void cvt_pad_rows(const float* __restrict__ src,
                                                    bf16* __restrict__ dst,
                                                    int rows_valid, int total){
    int i = (blockIdx.x*256 + threadIdx.x)*4;
    if (i + 3 >= total) return;
    int r = i >> 11;   // 2048 cols
    bf16x4 o;
    if (r < rows_valid){
        float4 v = *(const float4*)&src[i];
        o[0]=(bf16)v.x; o[1]=(bf16)v.y; o[2]=(bf16)v.z; o[3]=(bf16)v.w;
    } else {
        o[0]=(bf16)0.f; o[1]=(bf16)0.f; o[2]=(bf16)0.f; o[3]=(bf16)0.f;
    }
    *(bf16x4*)&dst[i] = o;
}

// ---------------- bf16 MFMA GEMM: C = A * B^T (both row-major, K contiguous) ----------------
// MODE 0: f32 C.  MODE 1: bf16 C, plus f32 side-channel for columns [8448,8512) -> dtf[row][c-8448]
template<int MODE>
__global__ __launch_bounds__(256) void gemm_bt_kernel(const bf16* __restrict__ A,
                                                      const bf16* __restrict__ B,
                                                      void* __restrict__ Cout,
                                                      float* __restrict__ dtf,
                                                      int M, int N, int K, int ldc){
    __shared__ __align__(16) bf16 As[128*64];
    __shared__ __align__(16) bf16 Bs[128*64];
    const int tid  = threadIdx.x;
    const int w    = tid >> 6;
    const int lane = tid & 63;
    const int tm   = blockIdx.y * 128;
    const int tn   = blockIdx.x * 128;
    const int wr   = w >> 1, wc = w & 1;

    f32x4v acc[4][4];
    #pragma unroll
    for (int mi=0;mi<4;mi++)
        #pragma unroll
        for (int ni=0;ni<4;ni++)
            acc[mi][ni] = {0.f,0.f,0.f,0.f};

    const int srow = (w*4)*8 + (lane>>3);   // + i*8
    const int scol = (lane&7)*8;
    const bf16* Ag = A + (long)(tm + srow)*K + scol;
    const bf16* Bg = B + (long)(tn + srow)*K + scol;
    bf16* AsBase = &As[(w*4)*512];
    bf16* BsBase = &Bs[(w*4)*512];

    for (int kt = 0; kt < K; kt += 64){
        __syncthreads();
        #pragma unroll
        for (int i=0;i<4;i++){
            __builtin_amdgcn_global_load_lds(
                (const __attribute__((address_space(1))) void*)(Ag + (long)i*8*K + kt),
                (__attribute__((address_space(3))) void*)(AsBase + i*512), 16, 0, 0);
            __builtin_amdgcn_global_load_lds(
                (const __attribute__((address_space(1))) void*)(Bg + (long)i*8*K + kt),
                (__attribute__((address_space(3))) void*)(BsBase + i*512), 16, 0, 0);
        }
        __syncthreads();
        #pragma unroll
        for (int kk=0; kk<64; kk+=32){
            bf16x8 af[4], bfr[4];
            #pragma unroll
            for (int mi=0;mi<4;mi++)
                af[mi] = *(const bf16x8*)&As[(wr*64 + mi*16 + (lane&15))*64 + kk + (lane>>4)*8];
            #pragma unroll
            for (int ni=0;ni<4;ni++)
                bfr[ni] = *(const bf16x8*)&Bs[(wc*64 + ni*16 + (lane&15))*64 + kk + (lane>>4)*8];
            #pragma unroll
            for (int mi=0;mi<4;mi++)
                #pragma unroll
                for (int ni=0;ni<4;ni++)
                    acc[mi][ni] = __builtin_amdgcn_mfma_f32_16x16x32_bf16(af[mi], bfr[ni], acc[mi][ni], 0,0,0);
        }
    }
    const int er = (lane>>4)*4, ec = lane&15;
    #pragma unroll
    for (int mi=0;mi<4;mi++)
        #pragma unroll
        for (int ni=0;ni<4;ni++){
            int r0 = tm + wr*64 + mi*16 + er;
            int c0 = tn + wc*64 + ni*16 + ec;
            #pragma unroll
            for (int j=0;j<4;j++){
                float val = acc[mi][ni][j];
                if (MODE == 0){
                    ((float*)Cout)[(long)(r0+j)*ldc + c0] = val;
                } else {
                    ((bf16*)Cout)[(long)(r0+j)*ldc + c0] = (bf16)val;
                    if (c0 >= 8448 && c0 < 8512)
                        dtf[(long)(r0+j)*64 + (c0 - 8448)] = val;
                }
            }
        }
}

// ---------------- depthwise causal conv(4) + bias + silu (bf16 in/out) ----------------
__global__ __launch_bounds__(256) void conv_silu_kernel(const bf16* __restrict__ zx,
                                                        const float* __restrict__ Wc,
                                                        const float* __restrict__ bc,
                                                        bf16* __restrict__ xc){
    int ch  = blockIdx.x*256 + threadIdx.x;   // 0..4351
    int tok = blockIdx.y;                      // 0..4095
    int b = tok >> 11, t = tok & 2047;
    float w0=Wc[ch*4+0], w1=Wc[ch*4+1], w2=Wc[ch*4+2], w3=Wc[ch*4+3];
    const bf16* col = zx + (long)(b*SEQ)*DPROJP + 4096 + ch;
    float acc = bc[ch];
    if (t>=3) acc += (float)col[(long)(t-3)*DPROJP]*w0;
    if (t>=2) acc += (float)col[(long)(t-2)*DPROJP]*w1;
    if (t>=1) acc += (float)col[(long)(t-1)*DPROJP]*w2;
    acc += (float)col[(long)t*DPROJP]*w3;
    xc[(long)tok*CONVD + ch] = (bf16)silu_f(acc);
}

// ---------------- dt softplus + per-chunk cumsum (reads f32 dtf side-channel) ----------------
__global__ void dtcum_kernel(const float* __restrict__ dtf, const float* __restrict__ A_log,
                             const float* __restrict__ dt_bias,
                             float* __restrict__ dtv, float* __restrict__ dacs,
                             float* __restrict__ cdec){
    int blk = blockIdx.x;        // b*16+c
    int h   = threadIdx.x;       // 0..63
    int b = blk >> 4, c = blk & 15;
    float Ah = -expf(A_log[h]);
    float bias = dt_bias[h];
    float cs = 0.f;
    long base_h = ((long)blk*64 + h)*128;
    const float* src = dtf + (long)(b*SEQ + c*CHUNKL)*64 + h;
    for (int l=0;l<CHUNKL;l++){
        float d = softplus_f(src[(long)l*64] + bias);
        cs += d*Ah;
        dtv[base_h+l]  = d;
        dacs[base_h+l] = cs;
    }
    cdec[blk*64 + h] = expf(cs);
}

// ---------------- CB[l][s] = sum_n C[l][n]*B[s][n], per (b,c) ----------------
__global__ __launch_bounds__(256) void cb_kernel(const bf16* __restrict__ xc,
                                                 float* __restrict__ cb){
    __shared__ __align__(16) bf16 CsT[128*128];  // [n][l]
    __shared__ __align__(16) bf16 BsT[128*128];  // [n][s]
    int blk = blockIdx.x;  int b = blk>>4, c = blk&15;
    int tid = threadIdx.x;
    const bf16* base = xc + (long)(b*SEQ + c*CHUNKL)*CONVD;
    for (int i=0;i<64;i++){
        int idx = tid + i*256;
        int l = idx >> 7, n = idx & 127;
        CsT[n*128 + l] = base[(long)l*CONVD + 4224 + n];
        BsT[n*128 + l] = base[(long)l*CONVD + 4096 + n];
    }
    __syncthreads();
    int l = tid >> 1, s0 = (tid&1)*64;
    float acc[64];
    #pragma unroll
    for (int j=0;j<64;j++) acc[j]=0.f;
    for (int n=0;n<128;n++){
        float cl = (float)CsT[n*128 + l];
        const bf16x8* brow = (const bf16x8*)&BsT[n*128 + s0];
        #pragma unroll
        for (int v=0;v<8;v++){
            bf16x8 bv = brow[v];
            #pragma unroll
            for (int e=0;e<8;e++) acc[v*8+e] += cl*(float)bv[e];
        }
    }
    float* out = cb + (long)blk*16384 + (long)l*128 + s0;
    #pragma unroll
    for (int j=0;j<64;j++) out[j] = acc[j];
}

// ---------------- states[h][p][n] = sum_l B[l][n]*decay[l]*u[l][p], per (b,c,h) ----------------
__global__ __launch_bounds__(256) void states_kernel(const bf16* __restrict__ xc,
                                                     const float* __restrict__ dtv,
                                                     const float* __restrict__ dacs,
                                                     float* __restrict__ states){
    __shared__ __align__(16) bf16 Bs[128*128];  // [l][n]
    __shared__ __align__(16) bf16 xw[128*64];   // [l][p]
    int blk = blockIdx.x;              // (b*16+c)*64+h
    int h = blk & 63, bc = blk >> 6;
    int b = bc >> 4, c = bc & 15;
    int tid = threadIdx.x;
    const bf16* base = xc + (long)(b*SEQ + c*CHUNKL)*CONVD;
    long base_h = (long)blk*128;
    float cs_last = dacs[base_h + 127];
    for (int i=0;i<64;i++){
        int idx = tid + i*256;
        int l = idx>>7, n = idx&127;
        Bs[idx] = base[(long)l*CONVD + 4096 + n];
    }
    for (int i=0;i<32;i++){
        int idx = tid + i*256;
        int l = idx>>6, p = idx&63;
        float wgt = dtv[base_h+l] * expf(cs_last - dacs[base_h+l]);
        xw[idx] = (bf16)((float)base[(long)l*CONVD + h*64 + p] * wgt);
    }
    __syncthreads();
    int n = tid & 127, p0 = (tid >> 7)*32;
    float acc[32];
    #pragma unroll
    for (int i=0;i<32;i++) acc[i]=0.f;
    for (int l=0;l<128;l++){
        float bval = (float)Bs[l*128 + n];
        const bf16x8* xrow = (const bf16x8*)&xw[l*64 + p0];
        #pragma unroll
        for (int v=0;v<4;v++){
            bf16x8 xv = xrow[v];
            #pragma unroll
            for (int e=0;e<8;e++) acc[v*8+e] += bval*(float)xv[e];
        }
    }
    float* out = states + (long)blk*8192;
    #pragma unroll
    for (int i=0;i<32;i++) out[(p0+i)*128 + n] = acc[i];
}

// ---------------- sequential chunk scan: h_starts (bf16 out) ----------------
__global__ __launch_bounds__(256) void scan_kernel(const float* __restrict__ states,
                                                   const float* __restrict__ cdec,
                                                   bf16* __restrict__ hst){
    long gid = (long)blockIdx.x*256 + threadIdx.x;   // 2*64*64*128 = 1048576
    int n = gid & 127;
    int p = (gid >> 7) & 63;
    int h = (gid >> 13) & 63;
    int b = (int)(gid >> 19);
    float hrun = 0.f;
    for (int c=0;c<16;c++){
        long idx = ((((long)(b*16 + c)*64 + h)*64 + p)*128) + n;
        hst[idx] = (bf16)hrun;
        hrun = hrun * cdec[(b*16+c)*64 + h] + states[idx];
    }
}

// ---------------- Y = Y_diag + D*x, per (b,c,h) ----------------
__global__ __launch_bounds__(256) void ydiag_kernel(const bf16* __restrict__ xc,
                                                    const float* __restrict__ cb,
                                                    const float* __restrict__ dtv,
                                                    const float* __restrict__ dacs,
                                                    const float* __restrict__ Dp,
                                                    float* __restrict__ Y){
    __shared__ __align__(16) bf16 CBt[128*128];  // [s][l]
    __shared__ __align__(16) bf16 us[128*64];    // [s][p]
    __shared__ float csl[128];
    int blk = blockIdx.x;
    int h = blk & 63, bc = blk >> 6;
    int b = bc >> 4, c = bc & 15;
    int tid = threadIdx.x;
    long base_h = (long)blk*128;
    const bf16* base = xc + (long)(b*SEQ + c*CHUNKL)*CONVD;
    const float* cbp  = cb + (long)bc*16384;
    for (int i=0;i<64;i++){
        int idx = tid + i*256;
        int l = idx>>7, s = idx&127;
        CBt[s*128 + l] = (bf16)cbp[idx];
    }
    for (int i=0;i<32;i++){
        int idx = tid + i*256;
        int s = idx>>6, p = idx&63;
        us[idx] = (bf16)((float)base[(long)s*CONVD + h*64 + p] * dtv[base_h + s]);
    }
    if (tid < 128) csl[tid] = dacs[base_h + tid];
    __syncthreads();
    int l = tid >> 1, ph = (tid&1)*32;
    float acc[32];
    #pragma unroll
    for (int i=0;i<32;i++) acc[i]=0.f;
    float myc = csl[l];
    for (int s=0; s<=l; ++s){
        float wgt = (float)CBt[s*128 + l] * expf(myc - csl[s]);
        const bf16x8* urow = (const bf16x8*)&us[s*64 + ph];
        #pragma unroll
        for (int v=0;v<4;v++){
            bf16x8 uv = urow[v];
            #pragma unroll
            for (int e=0;e<8;e++) acc[v*8+e] += wgt*(float)uv[e];
        }
    }
    float dh = Dp[h];
    const bf16* xrow = base + (long)l*CONVD + h*64 + ph;
    #pragma unroll
    for (int v=0;v<4;v++){
        bf16x8 xv = *(const bf16x8*)&xrow[v*8];
        #pragma unroll
        for (int e=0;e<8;e++) acc[v*8+e] += dh*(float)xv[e];
    }
    float* yout = Y + (long)(b*SEQ + c*CHUNKL + l)*DI + h*64 + ph;
    #pragma unroll
    for (int v=0;v<8;v++){
        float4 o; o.x=acc[v*4+0]; o.y=acc[v*4+1]; o.z=acc[v*4+2]; o.w=acc[v*4+3];
        *(float4*)&yout[v*4] = o;
    }
}

// ---------------- Y += sdo[l] * sum_n C[l][n]*h_start[p][n], per (b,c,h) ----------------
__global__ __launch_bounds__(256) void yoff_kernel(const bf16* __restrict__ xc,
                                                   const bf16* __restrict__ hst,
                                                   const float* __restrict__ dacs,
                                                   float* __restrict__ Y){
    __shared__ __align__(16) bf16 CsT[128*128];  // [n][l]
    __shared__ __align__(16) bf16 hsT[128*64];   // [n][p]
    int blk = blockIdx.x;
    int h = blk & 63, bc = blk >> 6;
    int b = bc >> 4, c = bc & 15;
    int tid = threadIdx.x;
    long base_h = (long)blk*128;
    const bf16* base = xc + (long)(b*SEQ + c*CHUNKL)*CONVD;
    const bf16* hsrc = hst + (long)blk*8192;    // [p][n]
    for (int i=0;i<64;i++){
        int idx = tid + i*256;
        int l = idx>>7, n = idx&127;
        CsT[n*128 + l] = base[(long)l*CONVD + 4224 + n];
    }
    for (int i=0;i<32;i++){
        int idx = tid + i*256;
        int p = idx>>7, n = idx&127;
        hsT[n*64 + p] = hsrc[idx];
    }
    __syncthreads();
    int l = tid >> 1, ph = (tid&1)*32;
    float acc[32];
    #pragma unroll
    for (int i=0;i<32;i++) acc[i]=0.f;
    for (int n=0;n<128;n++){
        float cv = (float)CsT[n*128 + l];
        const bf16x8* hrow = (const bf16x8*)&hsT[n*64 + ph];
        #pragma unroll
        for (int v=0;v<4;v++){
            bf16x8 hv = hrow[v];
            #pragma unroll
            for (int e=0;e<8;e++) acc[v*8+e] += cv*(float)hv[e];
        }
    }
    float wl = expf(dacs[base_h + l]);
    float* yout = Y + (long)(b*SEQ + c*CHUNKL + l)*DI + h*64 + ph;
    #pragma unroll
    for (int v=0;v<8;v++){
        float4 o = *(const float4*)&yout[v*4];
        o.x += wl*acc[v*4+0]; o.y += wl*acc[v*4+1];
        o.z += wl*acc[v*4+2]; o.w += wl*acc[v*4+3];
        *(float4*)&yout[v*4] = o;
    }
}

// ---------------- gate (silu(z)) + RMSNorm + cast bf16 ----------------
__global__ __launch_bounds__(256) void gatenorm_kernel(const float* __restrict__ Y,
                                                       const bf16* __restrict__ zx,
                                                       const float* __restrict__ nw,
                                                       bf16* __restrict__ ybn){
    __shared__ float red[4];
    int tok = blockIdx.x, tid = threadIdx.x;
    const float* yrow = Y  + (long)tok*DI;
    const bf16*  zrow = zx + (long)tok*DPROJP;
    float yg[16];
    float ss = 0.f;
    #pragma unroll
    for (int k=0;k<4;k++){
        int d = (tid + k*256)*4;
        float4 yv = *(const float4*)&yrow[d];
        bf16x4 zv = *(const bf16x4*)&zrow[d];
        float g0 = yv.x*silu_f((float)zv[0]), g1 = yv.y*silu_f((float)zv[1]);
        float g2 = yv.z*silu_f((float)zv[2]), g3 = yv.w*silu_f((float)zv[3]);
        yg[k*4+0]=g0; yg[k*4+1]=g1; yg[k*4+2]=g2; yg[k*4+3]=g3;
        ss += g0*g0 + g1*g1 + g2*g2 + g3*g3;
    }
    #pragma unroll
    for (int off=32; off>0; off>>=1) ss += __shfl_down(ss, off, 64);
    if ((tid & 63) == 0) red[tid>>6] = ss;
    __syncthreads();
    float tot = red[0]+red[1]+red[2]+red[3];
    float scale = rsqrtf(tot/(float)DI + 1e-5f);
    #pragma unroll
    for (int k=0;k<4;k++){
        int d = (tid + k*256)*4;
        float4 wv = *(const float4*)&nw[d];
        bf16x4 o;
        o[0]=(bf16)(yg[k*4+0]*scale*wv.x);
        o[1]=(bf16)(yg[k*4+1]*scale*wv.y);
        o[2]=(bf16)(yg[k*4+2]*scale*wv.z);
        o[3]=(bf16)(yg[k*4+3]*scale*wv.w);
        *(bf16x4*)&ybn[(long)tok*DI + d] = o;
    }
}

// ---------------- launch ----------------
extern "C" void kernel_launch(void* const* d_in, const int* in_sizes, int n_in,
                              void* d_out, int out_size, void* d_ws, size_t ws_size,
                              hipStream_t stream){
    const float* hs      = (const float*)d_in[0];
    const float* W_in    = (const float*)d_in[1];
    const float* W_conv  = (const float*)d_in[2];
    const float* b_conv  = (const float*)d_in[3];
    const float* A_log   = (const float*)d_in[4];
    const float* Dp      = (const float*)d_in[5];
    const float* dt_bias = (const float*)d_in[6];
    const float* nw      = (const float*)d_in[7];
    const float* W_out   = (const float*)d_in[8];
    float* out = (float*)d_out;

    char* ws = (char*)d_ws;
    // ---- workspace map (total 228,597,760 B) ----
    const size_t OFF_ZX    = 0;                    // bf16 [4096][8576]      70,254,592
    const size_t OFF_DTF   = 70254592;             // f32  [4096][64]         1,048,576
    const size_t OFF_XC    = 71303168;             // bf16 [4096][4352]      35,651,584
    const size_t OFF_DTV   = 106954752;            // f32  [2][16][64][128]   1,048,576
    const size_t OFF_DACS  = 108003328;            //                         1,048,576
    const size_t OFF_CDEC  = 109051904;            // f32  [2048]                 8,192
    const size_t OFF_CB    = 109060096;            // f32  [32][128][128]     2,097,152
    const size_t OFF_SLOTA = 111157248;            // 67,108,864: hsb+winb -> states -> Ybuf
    const size_t OFF_SLOTB = 178266112;            // 33,554,432: hst(bf16) -> ybn
    const size_t OFF_WOUTB = 211820544;            // bf16 [2048][4096]      16,777,216

    bf16*  zx    = (bf16*)(ws + OFF_ZX);
    float* dtf   = (float*)(ws + OFF_DTF);
    bf16*  xc    = (bf16*)(ws + OFF_XC);
    float* dtv   = (float*)(ws + OFF_DTV);
    float* dacs  = (float*)(ws + OFF_DACS);
    float* cdec  = (float*)(ws + OFF_CDEC);
    float* cbuf  = (float*)(ws + OFF_CB);
    bf16*  hsb   = (bf16*)(ws + OFF_SLOTA);
    bf16*  winb  = (bf16*)(ws + OFF_SLOTA + 16777216);
    float* states= (float*)(ws + OFF_SLOTA);
    float* Ybuf  = (float*)(ws + OFF_SLOTA);
    bf16*  hst   = (bf16*)(ws + OFF_SLOTB);
    bf16*  ybn   = (bf16*)(ws + OFF_SLOTB);
    bf16*  woutb = (bf16*)(ws + OFF_WOUTB);

    cvt_f32_bf16<<<8192, 256, 0, stream>>>(hs, hsb, NTOK*DMODEL);
    cvt_pad_rows<<<17152, 256, 0, stream>>>(W_in, winb, DPROJ, DPROJP*DMODEL);
    cvt_f32_bf16<<<8192, 256, 0, stream>>>(W_out, woutb, DMODEL*DI);

    gemm_bt_kernel<1><<<dim3(DPROJP/128, NTOK/128), 256, 0, stream>>>(
        hsb, winb, (void*)zx, dtf, NTOK, DPROJP, DMODEL, DPROJP);

    conv_silu_kernel<<<dim3(17, NTOK), 256, 0, stream>>>(zx, W_conv, b_conv, xc);
    dtcum_kernel<<<32, 64, 0, stream>>>(dtf, A_log, dt_bias, dtv, dacs, cdec);
    cb_kernel<<<32, 256, 0, stream>>>(xc, cbuf);
    states_kernel<<<2048, 256, 0, stream>>>(xc, dtv, dacs, states);
    scan_kernel<<<4096, 256, 0, stream>>>(states, cdec, hst);
    ydiag_kernel<<<2048, 256, 0, stream>>>(xc, cbuf, dtv, dacs, Dp, Ybuf);
    yoff_kernel<<<2048, 256, 0, stream>>>(xc, hst, dacs, Ybuf);
    gatenorm_kernel<<<4096, 256, 0, stream>>>(Ybuf, zx, nw, ybn);

    gemm_bt_kernel<0><<<dim3(DMODEL/128, NTOK/128), 256, 0, stream>>>(
        ybn, woutb, (void*)out, nullptr, NTOK, DMODEL, DI, DMODEL);
}

// Round 3
// 670.860 us; speedup vs baseline: 1.4476x; 1.4476x over previous
//
#include <hip/hip_runtime.h>
#include <hip/hip_bf16.h>
#include <stdint.h>

typedef __bf16 bf16;
typedef __bf16 bf16x8 __attribute__((ext_vector_type(8)));
typedef __bf16 bf16x4 __attribute__((ext_vector_type(4)));
typedef float f32x4v __attribute__((ext_vector_type(4)));

#define SEQ    2048
#define DMODEL 2048
#define DI     4096
#define NH     64
#define PDIM   64
#define CHUNKL 128
#define NCH    16
#define CONVD  4352
#define DPROJ  8512
#define DPROJP 8576
#define NTOK   4096
#define LP     136   // padded LDS leading dim (stride 272B = 17*16B -> 2-way only)

__device__ __forceinline__ float sigmoid_f(float x){ return 1.f/(1.f+expf(-x)); }
__device__ __forceinline__ float silu_f(float x){ return x*sigmoid_f(x); }
__device__ __forceinline__ float softplus_f(float x){ return x > 20.f ? x : log1pf(expf(x)); }

// ---------------- conversions ----------------
__global__ __launch_bounds__(256) void cvt_f32_bf16(const float* __restrict__ src,
                                                    bf16* __restrict__ dst, int n){
    int i = (blockIdx.x*256 + threadIdx.x)*4;
    if (i + 3 >= n) return;
    float4 v = *(const float4*)&src[i];
    bf16x4 o; o[0]=(bf16)v.x; o[1]=(bf16)v.y; o[2]=(bf16)v.z; o[3]=(bf16)v.w;
    *(bf16x4*)&dst[i] = o;
}

__global__ __launch_bounds__(256) void cvt_pad_rows(const float* __restrict__ src,
                                                    bf16* __restrict__ dst,
                                                    int rows_valid, int total){
    int i = (blockIdx.x*256 + threadIdx.x)*4;
    if (i + 3 >= total) return;
    int r = i >> 11;
    bf16x4 o;
    if (r < rows_valid){
        float4 v = *(const float4*)&src[i];
        o[0]=(bf16)v.x; o[1]=(bf16)v.y; o[2]=(bf16)v.z; o[3]=(bf16)v.w;
    } else {
        o[0]=(bf16)0.f; o[1]=(bf16)0.f; o[2]=(bf16)0.f; o[3]=(bf16)0.f;
    }
    *(bf16x4*)&dst[i] = o;
}

// ---------------- bf16 MFMA GEMM: C = A * B^T, 1D grid + XCD/supertile remap ----------------
// MODE 0: f32 C.  MODE 1: bf16 C + f32 side-channel cols [8448,8512) -> dtf
template<int MODE>
__global__ __launch_bounds__(256) void gemm_bt_kernel(const bf16* __restrict__ A,
                                                      const bf16* __restrict__ B,
                                                      void* __restrict__ Cout,
                                                      float* __restrict__ dtf,
                                                      int NXB, int NYB,
                                                      int K, int ldc){
    __shared__ __align__(16) bf16 As[128*64];
    __shared__ __align__(16) bf16 Bs[128*64];
    // ---- block remap: XCD-bijective (nb%8==0) then 8-wide supertile, M fastest ----
    int bid = blockIdx.x;
    int nb  = gridDim.x;
    int wg  = (bid & 7)*(nb >> 3) + (bid >> 3);
    const int W = 8;
    int sup = wg / (W*NYB);
    int rr  = wg % (W*NYB);
    int x0  = sup*W;
    int wl  = (NXB - x0 < W) ? (NXB - x0) : W;
    int x   = x0 + rr % wl;
    int y   = rr / wl;
    const int tm = y*128, tn = x*128;

    const int tid  = threadIdx.x;
    const int w    = tid >> 6;
    const int lane = tid & 63;
    const int wr   = w >> 1, wc = w & 1;

    f32x4v acc[4][4];
    #pragma unroll
    for (int mi=0;mi<4;mi++)
        #pragma unroll
        for (int ni=0;ni<4;ni++)
            acc[mi][ni] = {0.f,0.f,0.f,0.f};

    const int srow = (w*4)*8 + (lane>>3);
    const int scol = (lane&7)*8;
    const bf16* Ag = A + (long)(tm + srow)*K + scol;
    const bf16* Bg = B + (long)(tn + srow)*K + scol;
    bf16* AsBase = &As[(w*4)*512];
    bf16* BsBase = &Bs[(w*4)*512];

    for (int kt = 0; kt < K; kt += 64){
        __syncthreads();
        #pragma unroll
        for (int i=0;i<4;i++){
            __builtin_amdgcn_global_load_lds(
                (const __attribute__((address_space(1))) void*)(Ag + (long)i*8*K + kt),
                (__attribute__((address_space(3))) void*)(AsBase + i*512), 16, 0, 0);
            __builtin_amdgcn_global_load_lds(
                (const __attribute__((address_space(1))) void*)(Bg + (long)i*8*K + kt),
                (__attribute__((address_space(3))) void*)(BsBase + i*512), 16, 0, 0);
        }
        __syncthreads();
        #pragma unroll
        for (int kk=0; kk<64; kk+=32){
            bf16x8 af[4], bfr[4];
            #pragma unroll
            for (int mi=0;mi<4;mi++)
                af[mi] = *(const bf16x8*)&As[(wr*64 + mi*16 + (lane&15))*64 + kk + (lane>>4)*8];
            #pragma unroll
            for (int ni=0;ni<4;ni++)
                bfr[ni] = *(const bf16x8*)&Bs[(wc*64 + ni*16 + (lane&15))*64 + kk + (lane>>4)*8];
            #pragma unroll
            for (int mi=0;mi<4;mi++)
                #pragma unroll
                for (int ni=0;ni<4;ni++)
                    acc[mi][ni] = __builtin_amdgcn_mfma_f32_16x16x32_bf16(af[mi], bfr[ni], acc[mi][ni], 0,0,0);
        }
    }
    const int er = (lane>>4)*4, ec = lane&15;
    #pragma unroll
    for (int mi=0;mi<4;mi++)
        #pragma unroll
        for (int ni=0;ni<4;ni++){
            int r0 = tm + wr*64 + mi*16 + er;
            int c0 = tn + wc*64 + ni*16 + ec;
            #pragma unroll
            for (int j=0;j<4;j++){
                float val = acc[mi][ni][j];
                if (MODE == 0){
                    ((float*)Cout)[(long)(r0+j)*ldc + c0] = val;
                } else {
                    ((bf16*)Cout)[(long)(r0+j)*ldc + c0] = (bf16)val;
                    if (c0 >= 8448 && c0 < 8512)
                        dtf[(long)(r0+j)*64 + (c0 - 8448)] = val;
                }
            }
        }
}

// ---------------- depthwise causal conv(4) + bias + silu ----------------
__global__ __launch_bounds__(256) void conv_silu_kernel(const bf16* __restrict__ zx,
                                                        const float* __restrict__ Wc,
                                                        const float* __restrict__ bc,
                                                        bf16* __restrict__ xc){
    int ch  = blockIdx.x*256 + threadIdx.x;
    int tok = blockIdx.y;
    int b = tok >> 11, t = tok & 2047;
    float w0=Wc[ch*4+0], w1=Wc[ch*4+1], w2=Wc[ch*4+2], w3=Wc[ch*4+3];
    const bf16* col = zx + (long)(b*SEQ)*DPROJP + 4096 + ch;
    float acc = bc[ch];
    if (t>=3) acc += (float)col[(long)(t-3)*DPROJP]*w0;
    if (t>=2) acc += (float)col[(long)(t-2)*DPROJP]*w1;
    if (t>=1) acc += (float)col[(long)(t-1)*DPROJP]*w2;
    acc += (float)col[(long)t*DPROJP]*w3;
    xc[(long)tok*CONVD + ch] = (bf16)silu_f(acc);
}

// ---------------- dt softplus + per-chunk cumsum ----------------
__global__ void dtcum_kernel(const float* __restrict__ dtf, const float* __restrict__ A_log,
                             const float* __restrict__ dt_bias,
                             float* __restrict__ dtv, float* __restrict__ dacs,
                             float* __restrict__ cdec){
    int blk = blockIdx.x;        // b*16+c
    int h   = threadIdx.x;       // 0..63
    int b = blk >> 4, c = blk & 15;
    float Ah = -expf(A_log[h]);
    float bias = dt_bias[h];
    float cs = 0.f;
    long base_h = ((long)blk*64 + h)*128;
    const float* src = dtf + (long)(b*SEQ + c*CHUNKL)*64 + h;
    for (int l=0;l<CHUNKL;l++){
        float d = softplus_f(src[(long)l*64] + bias);
        cs += d*Ah;
        dtv[base_h+l]  = d;
        dacs[base_h+l] = cs;
    }
    cdec[blk*64 + h] = expf(cs);
}

// ---------------- CB[l][s] = sum_n C[l][n]*B[s][n] via MFMA, per (b,c) ----------------
__global__ __launch_bounds__(256) void cb_mfma_kernel(const bf16* __restrict__ xc,
                                                      float* __restrict__ cb){
    __shared__ __align__(16) bf16 A1[128*LP];   // C rows [l][n]
    __shared__ __align__(16) bf16 B1[128*LP];   // B rows [s][n]
    int blk = blockIdx.x;  int b = blk>>4, c = blk&15;
    int tid = threadIdx.x;
    const int w = tid >> 6, lane = tid & 63;
    long tok0 = (long)(b*SEQ + c*CHUNKL);
    int l = tid>>1, n0 = (tid&1)*64;
    const bf16* crow = xc + tok0*CONVD + (long)l*CONVD;  // row l
    #pragma unroll
    for (int v=0;v<8;v++){
        *(bf16x8*)&A1[l*LP + n0 + v*8] = *(const bf16x8*)&crow[4224 + n0 + v*8];
        *(bf16x8*)&B1[l*LP + n0 + v*8] = *(const bf16x8*)&crow[4096 + n0 + v*8];
    }
    __syncthreads();
    f32x4v acc[2][8];
    #pragma unroll
    for (int mi=0;mi<2;mi++)
        #pragma unroll
        for (int ni=0;ni<8;ni++) acc[mi][ni] = {0.f,0.f,0.f,0.f};
    #pragma unroll
    for (int kk=0; kk<128; kk+=32){
        bf16x8 af[2], bfr[8];
        #pragma unroll
        for (int mi=0;mi<2;mi++)
            af[mi] = *(const bf16x8*)&A1[(w*32 + mi*16 + (lane&15))*LP + kk + (lane>>4)*8];
        #pragma unroll
        for (int ni=0;ni<8;ni++)
            bfr[ni] = *(const bf16x8*)&B1[(ni*16 + (lane&15))*LP + kk + (lane>>4)*8];
        #pragma unroll
        for (int mi=0;mi<2;mi++)
            #pragma unroll
            for (int ni=0;ni<8;ni++)
                acc[mi][ni] = __builtin_amdgcn_mfma_f32_16x16x32_bf16(af[mi], bfr[ni], acc[mi][ni], 0,0,0);
    }
    float* out = cb + (long)blk*16384;
    #pragma unroll
    for (int mi=0;mi<2;mi++)
        #pragma unroll
        for (int ni=0;ni<8;ni++){
            int r0 = w*32 + mi*16 + (lane>>4)*4;
            int c0 = ni*16 + (lane&15);
            #pragma unroll
            for (int j=0;j<4;j++) out[(long)(r0+j)*128 + c0] = acc[mi][ni][j];
        }
}

// ---------------- states[p][n] = sum_l (x[l][hp]*wgt[l]) * B[l][n] via MFMA, per (b,c,h) ----------------
__global__ __launch_bounds__(256) void states_mfma_kernel(const bf16* __restrict__ xc,
                                                          const float* __restrict__ dtv,
                                                          const float* __restrict__ dacs,
                                                          float* __restrict__ states){
    __shared__ __align__(16) bf16 A1[64*LP];    // [p][l]
    __shared__ __align__(16) bf16 B1[128*LP];   // [n][l]
    __shared__ float wgtl[128];
    int blk = blockIdx.x;              // (b*16+c)*64+h
    int h = blk & 63, bc = blk >> 6;
    int b = bc >> 4, c = bc & 15;
    int tid = threadIdx.x;
    const int w = tid >> 6, lane = tid & 63;
    long tok0 = (long)(b*SEQ + c*CHUNKL);
    long base_h = (long)blk*128;
    float cs_last = dacs[base_h + 127];
    if (tid < 128) wgtl[tid] = dtv[base_h+tid] * expf(cs_last - dacs[base_h+tid]);
    __syncthreads();
    // A: x^T weighted
    #pragma unroll
    for (int t=0;t<4;t++){
        int l = (tid>>3) + t*32;
        int p0 = (tid&7)*8;
        bf16x8 xv = *(const bf16x8*)&xc[(tok0+l)*CONVD + h*64 + p0];
        float wv = wgtl[l];
        #pragma unroll
        for (int e=0;e<8;e++) A1[(p0+e)*LP + l] = (bf16)((float)xv[e]*wv);
    }
    // B: Bmat^T
    {
        int l = tid>>1, n0 = (tid&1)*64;
        const bf16* brow = xc + (tok0+l)*CONVD + 4096;
        #pragma unroll
        for (int v=0;v<8;v++){
            bf16x8 bv = *(const bf16x8*)&brow[n0 + v*8];
            #pragma unroll
            for (int e=0;e<8;e++) B1[(n0+v*8+e)*LP + l] = bv[e];
        }
    }
    __syncthreads();
    f32x4v acc[8];
    #pragma unroll
    for (int ni=0;ni<8;ni++) acc[ni] = {0.f,0.f,0.f,0.f};
    #pragma unroll
    for (int kk=0; kk<128; kk+=32){
        bf16x8 af = *(const bf16x8*)&A1[(w*16 + (lane&15))*LP + kk + (lane>>4)*8];
        #pragma unroll
        for (int ni=0;ni<8;ni++){
            bf16x8 bfr = *(const bf16x8*)&B1[(ni*16 + (lane&15))*LP + kk + (lane>>4)*8];
            acc[ni] = __builtin_amdgcn_mfma_f32_16x16x32_bf16(af, bfr, acc[ni], 0,0,0);
        }
    }
    float* out = states + (long)blk*8192;
    #pragma unroll
    for (int ni=0;ni<8;ni++){
        int p0 = w*16 + (lane>>4)*4;
        int n  = ni*16 + (lane&15);
        #pragma unroll
        for (int j=0;j<4;j++) out[(long)(p0+j)*128 + n] = acc[ni][j];
    }
}

// ---------------- sequential chunk scan: h_starts (bf16 out) ----------------
__global__ __launch_bounds__(256) void scan_kernel(const float* __restrict__ states,
                                                   const float* __restrict__ cdec,
                                                   bf16* __restrict__ hst){
    long gid = (long)blockIdx.x*256 + threadIdx.x;
    int n = gid & 127;
    int p = (gid >> 7) & 63;
    int h = (gid >> 13) & 63;
    int b = (int)(gid >> 19);
    float hrun = 0.f;
    for (int c=0;c<16;c++){
        long idx = ((((long)(b*16 + c)*64 + h)*64 + p)*128) + n;
        hst[idx] = (bf16)hrun;
        hrun = hrun * cdec[(b*16+c)*64 + h] + states[idx];
    }
}

// ---------------- fused Y = P@u^T + (C*sdo)@hst^T  (bf16 out), per (b,c,h) ----------------
__global__ __launch_bounds__(256) void yfused_kernel(const bf16* __restrict__ xc,
                                                     const float* __restrict__ cb,
                                                     const bf16* __restrict__ hst,
                                                     const float* __restrict__ dtv,
                                                     const float* __restrict__ dacs,
                                                     bf16* __restrict__ Ybf){
    __shared__ __align__(16) bf16 A1[128*LP];   // phase A: P[l][s]; phase B: Cw[l][n]
    __shared__ __align__(16) bf16 B1[64*LP];    // phase A: uT[p][s]; phase B: hT[p][n]
    __shared__ float csl[128];
    int blk = blockIdx.x;
    int h = blk & 63, bc = blk >> 6;
    int b = bc >> 4, c = bc & 15;
    int tid = threadIdx.x;
    const int w = tid >> 6, lane = tid & 63;
    long tok0 = (long)(b*SEQ + c*CHUNKL);
    long base_h = (long)blk*128;
    if (tid < 128) csl[tid] = dacs[base_h + tid];
    __syncthreads();
    // ---- phase A staging: P and uT ----
    {
        int l = tid>>1, s0 = (tid&1)*64;
        float el = csl[l];
        const float* cbrow = cb + (long)bc*16384 + (long)l*128 + s0;
        #pragma unroll 8
        for (int j=0;j<64;j++){
            int s = s0 + j;
            float v = (s <= l) ? cbrow[j]*expf(el - csl[s]) : 0.f;
            A1[l*LP + s] = (bf16)v;
        }
    }
    #pragma unroll
    for (int t=0;t<4;t++){
        int s = (tid>>3) + t*32;
        int p0 = (tid&7)*8;
        bf16x8 xv = *(const bf16x8*)&xc[(tok0+s)*CONVD + h*64 + p0];
        float wv = dtv[base_h + s];
        #pragma unroll
        for (int e=0;e<8;e++) B1[(p0+e)*LP + s] = (bf16)((float)xv[e]*wv);
    }
    __syncthreads();
    f32x4v acc[2][4];
    #pragma unroll
    for (int mi=0;mi<2;mi++)
        #pragma unroll
        for (int ni=0;ni<4;ni++) acc[mi][ni] = {0.f,0.f,0.f,0.f};
    #pragma unroll
    for (int kk=0; kk<128; kk+=32){
        bf16x8 af[2], bfr[4];
        #pragma unroll
        for (int mi=0;mi<2;mi++)
            af[mi] = *(const bf16x8*)&A1[(w*32 + mi*16 + (lane&15))*LP + kk + (lane>>4)*8];
        #pragma unroll
        for (int ni=0;ni<4;ni++)
            bfr[ni] = *(const bf16x8*)&B1[(ni*16 + (lane&15))*LP + kk + (lane>>4)*8];
        #pragma unroll
        for (int mi=0;mi<2;mi++)
            #pragma unroll
            for (int ni=0;ni<4;ni++)
                acc[mi][ni] = __builtin_amdgcn_mfma_f32_16x16x32_bf16(af[mi], bfr[ni], acc[mi][ni], 0,0,0);
    }
    __syncthreads();
    // ---- phase B staging: Cw and hT ----
    {
        int l = tid>>1, n0 = (tid&1)*64;
        float e1 = expf(csl[l]);
        const bf16* crow = xc + (tok0+l)*CONVD + 4224;
        #pragma unroll
        for (int v=0;v<8;v++){
            bf16x8 cv = *(const bf16x8*)&crow[n0 + v*8];
            bf16x8 o;
            #pragma unroll
            for (int e=0;e<8;e++) o[e] = (bf16)((float)cv[e]*e1);
            *(bf16x8*)&A1[l*LP + n0 + v*8] = o;
        }
    }
    {
        int p = tid>>2, n0 = (tid&3)*32;
        const bf16* hrow = hst + (long)blk*8192 + (long)p*128 + n0;
        #pragma unroll
        for (int v=0;v<4;v++)
            *(bf16x8*)&B1[p*LP + n0 + v*8] = *(const bf16x8*)&hrow[v*8];
    }
    __syncthreads();
    #pragma unroll
    for (int kk=0; kk<128; kk+=32){
        bf16x8 af[2], bfr[4];
        #pragma unroll
        for (int mi=0;mi<2;mi++)
            af[mi] = *(const bf16x8*)&A1[(w*32 + mi*16 + (lane&15))*LP + kk + (lane>>4)*8];
        #pragma unroll
        for (int ni=0;ni<4;ni++)
            bfr[ni] = *(const bf16x8*)&B1[(ni*16 + (lane&15))*LP + kk + (lane>>4)*8];
        #pragma unroll
        for (int mi=0;mi<2;mi++)
            #pragma unroll
            for (int ni=0;ni<4;ni++)
                acc[mi][ni] = __builtin_amdgcn_mfma_f32_16x16x32_bf16(af[mi], bfr[ni], acc[mi][ni], 0,0,0);
    }
    // ---- epilogue: write bf16 Y (D*x folded into gatenorm) ----
    #pragma unroll
    for (int mi=0;mi<2;mi++)
        #pragma unroll
        for (int ni=0;ni<4;ni++){
            int l0 = w*32 + mi*16 + (lane>>4)*4;
            int p  = ni*16 + (lane&15);
            #pragma unroll
            for (int j=0;j<4;j++)
                Ybf[(tok0 + l0 + j)*DI + h*64 + p] = (bf16)acc[mi][ni][j];
        }
}

// ---------------- gate (silu(z)) + D*x + RMSNorm + cast bf16 ----------------
__global__ __launch_bounds__(256) void gatenorm_kernel(const bf16* __restrict__ Ybf,
                                                       const bf16* __restrict__ zx,
                                                       const bf16* __restrict__ xc,
                                                       const float* __restrict__ Dp,
                                                       const float* __restrict__ nw,
                                                       bf16* __restrict__ ybn){
    __shared__ float red[4];
    int tok = blockIdx.x, tid = threadIdx.x;
    const bf16* yrow = Ybf + (long)tok*DI;
    const bf16* zrow = zx  + (long)tok*DPROJP;
    const bf16* xrow = xc  + (long)tok*CONVD;
    float yg[16];
    float ss = 0.f;
    #pragma unroll
    for (int k=0;k<4;k++){
        int d = (tid + k*256)*4;
        bf16x4 yv = *(const bf16x4*)&yrow[d];
        bf16x4 zv = *(const bf16x4*)&zrow[d];
        bf16x4 xv = *(const bf16x4*)&xrow[d];
        float dh = Dp[d>>6];
        #pragma unroll
        for (int e=0;e<4;e++){
            float y = (float)yv[e] + dh*(float)xv[e];
            float g = y*silu_f((float)zv[e]);
            yg[k*4+e] = g;
            ss += g*g;
        }
    }
    #pragma unroll
    for (int off=32; off>0; off>>=1) ss += __shfl_down(ss, off, 64);
    if ((tid & 63) == 0) red[tid>>6] = ss;
    __syncthreads();
    float tot = red[0]+red[1]+red[2]+red[3];
    float scale = rsqrtf(tot/(float)DI + 1e-5f);
    #pragma unroll
    for (int k=0;k<4;k++){
        int d = (tid + k*256)*4;
        float4 wv = *(const float4*)&nw[d];
        bf16x4 o;
        o[0]=(bf16)(yg[k*4+0]*scale*wv.x);
        o[1]=(bf16)(yg[k*4+1]*scale*wv.y);
        o[2]=(bf16)(yg[k*4+2]*scale*wv.z);
        o[3]=(bf16)(yg[k*4+3]*scale*wv.w);
        *(bf16x4*)&ybn[(long)tok*DI + d] = o;
    }
}

// ---------------- launch ----------------
extern "C" void kernel_launch(void* const* d_in, const int* in_sizes, int n_in,
                              void* d_out, int out_size, void* d_ws, size_t ws_size,
                              hipStream_t stream){
    const float* hs      = (const float*)d_in[0];
    const float* W_in    = (const float*)d_in[1];
    const float* W_conv  = (const float*)d_in[2];
    const float* b_conv  = (const float*)d_in[3];
    const float* A_log   = (const float*)d_in[4];
    const float* Dp      = (const float*)d_in[5];
    const float* dt_bias = (const float*)d_in[6];
    const float* nw      = (const float*)d_in[7];
    const float* W_out   = (const float*)d_in[8];
    float* out = (float*)d_out;

    char* ws = (char*)d_ws;
    const size_t OFF_ZX    = 0;                    // bf16 [4096][8576]      70,254,592
    const size_t OFF_DTF   = 70254592;             // f32  [4096][64]         1,048,576
    const size_t OFF_XC    = 71303168;             // bf16 [4096][4352]      35,651,584
    const size_t OFF_DTV   = 106954752;            // f32                     1,048,576
    const size_t OFF_DACS  = 108003328;            //                         1,048,576
    const size_t OFF_CDEC  = 109051904;            // f32 [2048]                  8,192
    const size_t OFF_CB    = 109060096;            // f32 [32][128][128]      2,097,152
    const size_t OFF_SLOTA = 111157248;            // 67,108,864: hsb+winb -> states(f32 64MB) -> Ybf(bf16 33.5MB)
    const size_t OFF_SLOTB = 178266112;            // 33,554,432: hst(bf16) -> ybn
    const size_t OFF_WOUTB = 211820544;            // bf16 [2048][4096]      16,777,216

    bf16*  zx    = (bf16*)(ws + OFF_ZX);
    float* dtf   = (float*)(ws + OFF_DTF);
    bf16*  xc    = (bf16*)(ws + OFF_XC);
    float* dtv   = (float*)(ws + OFF_DTV);
    float* dacs  = (float*)(ws + OFF_DACS);
    float* cdec  = (float*)(ws + OFF_CDEC);
    float* cbuf  = (float*)(ws + OFF_CB);
    bf16*  hsb   = (bf16*)(ws + OFF_SLOTA);
    bf16*  winb  = (bf16*)(ws + OFF_SLOTA + 16777216);
    float* states= (float*)(ws + OFF_SLOTA);
    bf16*  Ybf   = (bf16*)(ws + OFF_SLOTA);
    bf16*  hst   = (bf16*)(ws + OFF_SLOTB);
    bf16*  ybn   = (bf16*)(ws + OFF_SLOTB);
    bf16*  woutb = (bf16*)(ws + OFF_WOUTB);

    cvt_f32_bf16<<<8192, 256, 0, stream>>>(hs, hsb, NTOK*DMODEL);
    cvt_pad_rows<<<17152, 256, 0, stream>>>(W_in, winb, DPROJ, DPROJP*DMODEL);
    cvt_f32_bf16<<<8192, 256, 0, stream>>>(W_out, woutb, DMODEL*DI);

    gemm_bt_kernel<1><<<(DPROJP/128)*(NTOK/128), 256, 0, stream>>>(
        hsb, winb, (void*)zx, dtf, DPROJP/128, NTOK/128, DMODEL, DPROJP);

    conv_silu_kernel<<<dim3(17, NTOK), 256, 0, stream>>>(zx, W_conv, b_conv, xc);
    dtcum_kernel<<<32, 64, 0, stream>>>(dtf, A_log, dt_bias, dtv, dacs, cdec);
    cb_mfma_kernel<<<32, 256, 0, stream>>>(xc, cbuf);
    states_mfma_kernel<<<2048, 256, 0, stream>>>(xc, dtv, dacs, states);
    scan_kernel<<<4096, 256, 0, stream>>>(states, cdec, hst);
    yfused_kernel<<<2048, 256, 0, stream>>>(xc, cbuf, hst, dtv, dacs, Ybf);
    gatenorm_kernel<<<4096, 256, 0, stream>>>(Ybf, zx, xc, Dp, nw, ybn);

    gemm_bt_kernel<0><<<(DMODEL/128)*(NTOK/128), 256, 0, stream>>>(
        ybn, woutb, (void*)out, nullptr, DMODEL/128, NTOK/128, DI, DMODEL);
}

// Round 4
// 605.825 us; speedup vs baseline: 1.6030x; 1.1073x over previous
//
#include <hip/hip_runtime.h>
#include <hip/hip_bf16.h>
#include <stdint.h>

typedef __bf16 bf16;
typedef __bf16 bf16x8 __attribute__((ext_vector_type(8)));
typedef __bf16 bf16x4 __attribute__((ext_vector_type(4)));
typedef float f32x4v __attribute__((ext_vector_type(4)));

#define SEQ    2048
#define DMODEL 2048
#define DI     4096
#define NH     64
#define PDIM   64
#define CHUNKL 128
#define NCH    16
#define CONVD  4352
#define DPROJ  8512
#define ZLD    8704   // zxbcdt leading dim, padded to 34*256
#define NTOK   4096
#define LP     136    // padded LDS leading dim for middle kernels

__device__ __forceinline__ float sigmoid_f(float x){ return 1.f/(1.f+expf(-x)); }
__device__ __forceinline__ float silu_f(float x){ return x*sigmoid_f(x); }
__device__ __forceinline__ float softplus_f(float x){ return x > 20.f ? x : log1pf(expf(x)); }

// ---------------- conversions ----------------
__global__ __launch_bounds__(256) void cvt_f32_bf16(const float* __restrict__ src,
                                                    bf16* __restrict__ dst, int n){
    int i = (blockIdx.x*256 + threadIdx.x)*4;
    if (i + 3 >= n) return;
    float4 v = *(const float4*)&src[i];
    bf16x4 o; o[0]=(bf16)v.x; o[1]=(bf16)v.y; o[2]=(bf16)v.z; o[3]=(bf16)v.w;
    *(bf16x4*)&dst[i] = o;
}

__global__ __launch_bounds__(256) void cvt_pad_rows(const float* __restrict__ src,
                                                    bf16* __restrict__ dst,
                                                    int rows_valid, int total){
    int i = (blockIdx.x*256 + threadIdx.x)*4;
    if (i + 3 >= total) return;
    int r = i >> 11;
    bf16x4 o;
    if (r < rows_valid){
        float4 v = *(const float4*)&src[i];
        o[0]=(bf16)v.x; o[1]=(bf16)v.y; o[2]=(bf16)v.z; o[3]=(bf16)v.w;
    } else {
        o[0]=(bf16)0.f; o[1]=(bf16)0.f; o[2]=(bf16)0.f; o[3]=(bf16)0.f;
    }
    *(bf16x4*)&dst[i] = o;
}

// ============ 256x256 8-phase bf16 GEMM: C = A * B^T ============
// MODE 1: bf16 C (ldc) + f32 side-channel cols [8448,8512) -> dtf
// MODE 2: split-K=2, f32 partials: Cout + kz*(NYB*256)*ldc
// LDS per buffer: A'[256][64] + B'[256][64]; row remap A': [qm][wm][64], B': [qn][wn][32]
// swizzle: 16B slot ^= (ldsrow&7) on BOTH global-source (stage) and ds_read.
#define MMA_PHASE(BUFP, QM, QN)                                                        \
    {                                                                                  \
        const bf16* Bp = (BUFP) + 16384;                                               \
        bf16x8 bfr[2][2];                                                              \
        _Pragma("unroll")                                                              \
        for (int nf=0;nf<2;nf++)                                                       \
            _Pragma("unroll")                                                          \
            for (int k2=0;k2<2;k2++){                                                  \
                int rb = (QN)*128 + wn*32 + nf*16 + (lane&15);                         \
                int slot = (k2*4 + (lane>>4)) ^ (rb&7);                                \
                bfr[nf][k2] = *(const bf16x8*)&Bp[rb*64 + slot*8];                     \
            }                                                                          \
        __builtin_amdgcn_s_setprio(1);                                                 \
        _Pragma("unroll")                                                              \
        for (int i=0;i<4;i++)                                                          \
            _Pragma("unroll")                                                          \
            for (int nf=0;nf<2;nf++)                                                   \
                _Pragma("unroll")                                                      \
                for (int k2=0;k2<2;k2++)                                               \
                    acc[(QM)*4+i][(QN)*2+nf] = __builtin_amdgcn_mfma_f32_16x16x32_bf16( \
                        af[i][k2], bfr[nf][k2], acc[(QM)*4+i][(QN)*2+nf], 0,0,0);      \
        __builtin_amdgcn_s_setprio(0);                                                 \
    }

#define READ_A(BUFP, QM)                                                               \
    {                                                                                  \
        _Pragma("unroll")                                                              \
        for (int i=0;i<4;i++)                                                          \
            _Pragma("unroll")                                                          \
            for (int k2=0;k2<2;k2++){                                                  \
                int ra = (QM)*128 + wm*64 + i*16 + (lane&15);                          \
                int slot = (k2*4 + (lane>>4)) ^ (ra&7);                                \
                af[i][k2] = *(const bf16x8*)&(BUFP)[ra*64 + slot*8];                   \
            }                                                                          \
    }

template<int MODE>
__global__ __launch_bounds__(512) void gemm256_kernel(const bf16* __restrict__ A,
                                                      const bf16* __restrict__ Bmat,
                                                      void* __restrict__ Cout,
                                                      float* __restrict__ dtf,
                                                      int NXB, int NYB, int K, int ldc){
    __shared__ __align__(16) bf16 lds[2][2*16384];   // [buf][A(16384) | B(16384)]
    const int tid  = threadIdx.x;
    const int w    = tid >> 6;
    const int lane = tid & 63;
    const int wm   = w >> 2, wn = w & 3;

    int bid  = blockIdx.x;
    int nb2  = (MODE==2) ? ((int)gridDim.x >> 1) : (int)gridDim.x;
    int kz   = (MODE==2) ? (bid / nb2) : 0;
    int bid2 = (MODE==2) ? (bid % nb2) : bid;
    int wg   = (bid2 & 7)*(nb2 >> 3) + (bid2 >> 3);
    const int SW = 8;
    int sup = wg / (SW*NYB);
    int rr  = wg % (SW*NYB);
    int x0  = sup*SW;
    int wl  = (NXB - x0 < SW) ? (NXB - x0) : SW;
    int x   = x0 + rr % wl;
    int y   = rr / wl;
    const int tm = y*256, tn = x*256;

    const int KT  = (MODE==2) ? (K >> 7) : (K >> 6);   // tiles this block handles
    const int kt0 = (MODE==2) ? kz*KT : 0;

    f32x4v acc[8][4];
    #pragma unroll
    for (int i=0;i<8;i++)
        #pragma unroll
        for (int j=0;j<4;j++) acc[i][j] = {0.f,0.f,0.f,0.f};
    bf16x8 af[4][2];

    auto stageA = [&](int buf, int t, int r0){
        bf16* mat = &lds[buf][0];
        int ktcol = (kt0 + t)*64;
        #pragma unroll
        for (int i=0;i<2;i++){
            int lr = r0 + i*64 + (tid>>3);
            int grow = tm + ((lr>>6)&1)*128 + (lr>>7)*64 + (lr&63);
            int gslot = (tid&7) ^ (lr&7);
            const bf16* src = A + (long)grow*K + ktcol + gslot*8;
            bf16* dst = mat + (size_t)(r0 + i*64 + w*8)*64;   // wave-uniform; HW adds lane*16B
            __builtin_amdgcn_global_load_lds(
                (const __attribute__((address_space(1))) void*)src,
                (__attribute__((address_space(3))) void*)dst, 16, 0, 0);
        }
    };
    auto stageB = [&](int buf, int t, int r0){
        bf16* mat = &lds[buf][16384];
        int ktcol = (kt0 + t)*64;
        #pragma unroll
        for (int i=0;i<2;i++){
            int lr = r0 + i*64 + (tid>>3);
            int grow = tn + ((lr>>5)&3)*64 + (lr>>7)*32 + (lr&31);
            int gslot = (tid&7) ^ (lr&7);
            const bf16* src = Bmat + (long)grow*K + ktcol + gslot*8;
            bf16* dst = mat + (size_t)(r0 + i*64 + w*8)*64;
            __builtin_amdgcn_global_load_lds(
                (const __attribute__((address_space(1))) void*)src,
                (__attribute__((address_space(3))) void*)dst, 16, 0, 0);
        }
    };

    // ---- prologue: t0 fully, t1 qm0A+qn0B ----
    stageA(0, 0, 0);
    stageB(0, 0, 0);
    stageA(0, 0, 128);
    stageB(0, 0, 128);
    if (KT > 1){ stageA(1, 1, 0); stageB(1, 1, 0); }

    int cur = 0;
    for (int t = 0; t < KT; ++t){
        int nxt = cur ^ 1;
        const bf16* bufc = &lds[cur][0];
        // ---- P0: quadrant (0,0) ----
        if (t+1 < KT) stageA(nxt, t+1, 128);
        asm volatile("s_waitcnt vmcnt(10)" ::: "memory");
        __builtin_amdgcn_s_barrier();
        __builtin_amdgcn_sched_barrier(0);
        READ_A(bufc, 0)
        MMA_PHASE(bufc, 0, 0)
        __builtin_amdgcn_s_barrier();
        __builtin_amdgcn_sched_barrier(0);
        // ---- P1: quadrant (0,1) ----
        if (t+1 < KT) stageB(nxt, t+1, 128);
        asm volatile("s_waitcnt vmcnt(8)" ::: "memory");
        __builtin_amdgcn_s_barrier();
        __builtin_amdgcn_sched_barrier(0);
        MMA_PHASE(bufc, 0, 1)
        __builtin_amdgcn_s_barrier();
        __builtin_amdgcn_sched_barrier(0);
        // ---- P2: quadrant (1,0) ----
        if (t+2 < KT) stageA(cur, t+2, 0);    // A' rows 0-127 freed after P0/P1
        __builtin_amdgcn_s_barrier();
        __builtin_amdgcn_sched_barrier(0);
        READ_A(bufc, 1)
        MMA_PHASE(bufc, 1, 0)
        __builtin_amdgcn_s_barrier();
        __builtin_amdgcn_sched_barrier(0);
        // ---- P3: quadrant (1,1) ----
        if (t+2 < KT) stageB(cur, t+2, 0);    // B' rows 0-127 freed after P2
        __builtin_amdgcn_s_barrier();
        __builtin_amdgcn_sched_barrier(0);
        MMA_PHASE(bufc, 1, 1)
        __builtin_amdgcn_s_barrier();
        __builtin_amdgcn_sched_barrier(0);
        cur = nxt;
    }

    // ---- epilogue ----
    const int er = (lane>>4)*4, ec = lane&15;
    #pragma unroll
    for (int mi=0;mi<8;mi++)
        #pragma unroll
        for (int ni=0;ni<4;ni++){
            long r0 = tm + wm*128 + mi*16 + er;
            int  c0 = tn + wn*64 + ni*16 + ec;
            #pragma unroll
            for (int j=0;j<4;j++){
                float val = acc[mi][ni][j];
                if (MODE == 1){
                    ((bf16*)Cout)[(r0+j)*ldc + c0] = (bf16)val;
                    if (c0 >= 8448 && c0 < 8512)
                        dtf[(r0+j)*64 + (c0 - 8448)] = val;
                } else {
                    ((float*)Cout)[(long)kz*NYB*256*ldc + (r0+j)*ldc + c0] = val;
                }
            }
        }
}

// ---------------- split-K reduce: out = p0 + p1 ----------------
__global__ __launch_bounds__(256) void reduce_add_kernel(const float* __restrict__ p,
                                                         float* __restrict__ out, int n){
    int i = (blockIdx.x*256 + threadIdx.x)*4;
    if (i + 3 >= n) return;
    float4 a = *(const float4*)&p[i];
    float4 b = *(const float4*)&p[i + 8388608];
    a.x+=b.x; a.y+=b.y; a.z+=b.z; a.w+=b.w;
    *(float4*)&out[i] = a;
}

// ---------------- depthwise causal conv(4) + bias + silu ----------------
__global__ __launch_bounds__(256) void conv_silu_kernel(const bf16* __restrict__ zx,
                                                        const float* __restrict__ Wc,
                                                        const float* __restrict__ bc,
                                                        bf16* __restrict__ xc){
    int ch  = blockIdx.x*256 + threadIdx.x;
    int tok = blockIdx.y;
    int b = tok >> 11, t = tok & 2047;
    float w0=Wc[ch*4+0], w1=Wc[ch*4+1], w2=Wc[ch*4+2], w3=Wc[ch*4+3];
    const bf16* col = zx + (long)(b*SEQ)*ZLD + 4096 + ch;
    float acc = bc[ch];
    if (t>=3) acc += (float)col[(long)(t-3)*ZLD]*w0;
    if (t>=2) acc += (float)col[(long)(t-2)*ZLD]*w1;
    if (t>=1) acc += (float)col[(long)(t-1)*ZLD]*w2;
    acc += (float)col[(long)t*ZLD]*w3;
    xc[(long)tok*CONVD + ch] = (bf16)silu_f(acc);
}

// ---------------- dt softplus + per-chunk cumsum ----------------
__global__ void dtcum_kernel(const float* __restrict__ dtf, const float* __restrict__ A_log,
                             const float* __restrict__ dt_bias,
                             float* __restrict__ dtv, float* __restrict__ dacs,
                             float* __restrict__ cdec){
    int blk = blockIdx.x;        // b*16+c
    int h   = threadIdx.x;       // 0..63
    int b = blk >> 4, c = blk & 15;
    float Ah = -expf(A_log[h]);
    float bias = dt_bias[h];
    float cs = 0.f;
    long base_h = ((long)blk*64 + h)*128;
    const float* src = dtf + (long)(b*SEQ + c*CHUNKL)*64 + h;
    for (int l=0;l<CHUNKL;l++){
        float d = softplus_f(src[(long)l*64] + bias);
        cs += d*Ah;
        dtv[base_h+l]  = d;
        dacs[base_h+l] = cs;
    }
    cdec[blk*64 + h] = expf(cs);
}

// ---------------- CB[l][s] = sum_n C[l][n]*B[s][n] via MFMA, per (b,c) ----------------
__global__ __launch_bounds__(256) void cb_mfma_kernel(const bf16* __restrict__ xc,
                                                      float* __restrict__ cb){
    __shared__ __align__(16) bf16 A1[128*LP];
    __shared__ __align__(16) bf16 B1[128*LP];
    int blk = blockIdx.x;  int b = blk>>4, c = blk&15;
    int tid = threadIdx.x;
    const int w = tid >> 6, lane = tid & 63;
    long tok0 = (long)(b*SEQ + c*CHUNKL);
    int l = tid>>1, n0 = (tid&1)*64;
    const bf16* crow = xc + tok0*CONVD + (long)l*CONVD;
    #pragma unroll
    for (int v=0;v<8;v++){
        *(bf16x8*)&A1[l*LP + n0 + v*8] = *(const bf16x8*)&crow[4224 + n0 + v*8];
        *(bf16x8*)&B1[l*LP + n0 + v*8] = *(const bf16x8*)&crow[4096 + n0 + v*8];
    }
    __syncthreads();
    f32x4v acc[2][8];
    #pragma unroll
    for (int mi=0;mi<2;mi++)
        #pragma unroll
        for (int ni=0;ni<8;ni++) acc[mi][ni] = {0.f,0.f,0.f,0.f};
    #pragma unroll
    for (int kk=0; kk<128; kk+=32){
        bf16x8 afr[2], bfr[8];
        #pragma unroll
        for (int mi=0;mi<2;mi++)
            afr[mi] = *(const bf16x8*)&A1[(w*32 + mi*16 + (lane&15))*LP + kk + (lane>>4)*8];
        #pragma unroll
        for (int ni=0;ni<8;ni++)
            bfr[ni] = *(const bf16x8*)&B1[(ni*16 + (lane&15))*LP + kk + (lane>>4)*8];
        #pragma unroll
        for (int mi=0;mi<2;mi++)
            #pragma unroll
            for (int ni=0;ni<8;ni++)
                acc[mi][ni] = __builtin_amdgcn_mfma_f32_16x16x32_bf16(afr[mi], bfr[ni], acc[mi][ni], 0,0,0);
    }
    float* out = cb + (long)blk*16384;
    #pragma unroll
    for (int mi=0;mi<2;mi++)
        #pragma unroll
        for (int ni=0;ni<8;ni++){
            int r0 = w*32 + mi*16 + (lane>>4)*4;
            int c0 = ni*16 + (lane&15);
            #pragma unroll
            for (int j=0;j<4;j++) out[(long)(r0+j)*128 + c0] = acc[mi][ni][j];
        }
}

// ---------------- states[p][n] via MFMA, per (b,c,h) ----------------
__global__ __launch_bounds__(256) void states_mfma_kernel(const bf16* __restrict__ xc,
                                                          const float* __restrict__ dtv,
                                                          const float* __restrict__ dacs,
                                                          float* __restrict__ states){
    __shared__ __align__(16) bf16 A1[64*LP];
    __shared__ __align__(16) bf16 B1[128*LP];
    __shared__ float wgtl[128];
    int blk = blockIdx.x;
    int h = blk & 63, bc = blk >> 6;
    int b = bc >> 4, c = bc & 15;
    int tid = threadIdx.x;
    const int w = tid >> 6, lane = tid & 63;
    long tok0 = (long)(b*SEQ + c*CHUNKL);
    long base_h = (long)blk*128;
    float cs_last = dacs[base_h + 127];
    if (tid < 128) wgtl[tid] = dtv[base_h+tid] * expf(cs_last - dacs[base_h+tid]);
    __syncthreads();
    #pragma unroll
    for (int t=0;t<4;t++){
        int l = (tid>>3) + t*32;
        int p0 = (tid&7)*8;
        bf16x8 xv = *(const bf16x8*)&xc[(tok0+l)*CONVD + h*64 + p0];
        float wv = wgtl[l];
        #pragma unroll
        for (int e=0;e<8;e++) A1[(p0+e)*LP + l] = (bf16)((float)xv[e]*wv);
    }
    {
        int l = tid>>1, n0 = (tid&1)*64;
        const bf16* brow = xc + (tok0+l)*CONVD + 4096;
        #pragma unroll
        for (int v=0;v<8;v++){
            bf16x8 bv = *(const bf16x8*)&brow[n0 + v*8];
            #pragma unroll
            for (int e=0;e<8;e++) B1[(n0+v*8+e)*LP + l] = bv[e];
        }
    }
    __syncthreads();
    f32x4v acc[8];
    #pragma unroll
    for (int ni=0;ni<8;ni++) acc[ni] = {0.f,0.f,0.f,0.f};
    #pragma unroll
    for (int kk=0; kk<128; kk+=32){
        bf16x8 afr = *(const bf16x8*)&A1[(w*16 + (lane&15))*LP + kk + (lane>>4)*8];
        #pragma unroll
        for (int ni=0;ni<8;ni++){
            bf16x8 bfr = *(const bf16x8*)&B1[(ni*16 + (lane&15))*LP + kk + (lane>>4)*8];
            acc[ni] = __builtin_amdgcn_mfma_f32_16x16x32_bf16(afr, bfr, acc[ni], 0,0,0);
        }
    }
    float* out = states + (long)blk*8192;
    #pragma unroll
    for (int ni=0;ni<8;ni++){
        int p0 = w*16 + (lane>>4)*4;
        int n  = ni*16 + (lane&15);
        #pragma unroll
        for (int j=0;j<4;j++) out[(long)(p0+j)*128 + n] = acc[ni][j];
    }
}

// ---------------- sequential chunk scan ----------------
__global__ __launch_bounds__(256) void scan_kernel(const float* __restrict__ states,
                                                   const float* __restrict__ cdec,
                                                   bf16* __restrict__ hst){
    long gid = (long)blockIdx.x*256 + threadIdx.x;
    int n = gid & 127;
    int p = (gid >> 7) & 63;
    int h = (gid >> 13) & 63;
    int b = (int)(gid >> 19);
    float hrun = 0.f;
    for (int c=0;c<16;c++){
        long idx = ((((long)(b*16 + c)*64 + h)*64 + p)*128) + n;
        hst[idx] = (bf16)hrun;
        hrun = hrun * cdec[(b*16+c)*64 + h] + states[idx];
    }
}

// ---------------- fused Y = P@u^T + (C*sdo)@hst^T ----------------
__global__ __launch_bounds__(256) void yfused_kernel(const bf16* __restrict__ xc,
                                                     const float* __restrict__ cb,
                                                     const bf16* __restrict__ hst,
                                                     const float* __restrict__ dtv,
                                                     const float* __restrict__ dacs,
                                                     bf16* __restrict__ Ybf){
    __shared__ __align__(16) bf16 A1[128*LP];
    __shared__ __align__(16) bf16 B1[64*LP];
    __shared__ float csl[128];
    int blk = blockIdx.x;
    int h = blk & 63, bc = blk >> 6;
    int b = bc >> 4, c = bc & 15;
    int tid = threadIdx.x;
    const int w = tid >> 6, lane = tid & 63;
    long tok0 = (long)(b*SEQ + c*CHUNKL);
    long base_h = (long)blk*128;
    if (tid < 128) csl[tid] = dacs[base_h + tid];
    __syncthreads();
    {
        int l = tid>>1, s0 = (tid&1)*64;
        float el = csl[l];
        const float* cbrow = cb + (long)bc*16384 + (long)l*128 + s0;
        #pragma unroll 8
        for (int j=0;j<64;j++){
            int s = s0 + j;
            float v = (s <= l) ? cbrow[j]*expf(el - csl[s]) : 0.f;
            A1[l*LP + s] = (bf16)v;
        }
    }
    #pragma unroll
    for (int t=0;t<4;t++){
        int s = (tid>>3) + t*32;
        int p0 = (tid&7)*8;
        bf16x8 xv = *(const bf16x8*)&xc[(tok0+s)*CONVD + h*64 + p0];
        float wv = dtv[base_h + s];
        #pragma unroll
        for (int e=0;e<8;e++) B1[(p0+e)*LP + s] = (bf16)((float)xv[e]*wv);
    }
    __syncthreads();
    f32x4v acc[2][4];
    #pragma unroll
    for (int mi=0;mi<2;mi++)
        #pragma unroll
        for (int ni=0;ni<4;ni++) acc[mi][ni] = {0.f,0.f,0.f,0.f};
    #pragma unroll
    for (int kk=0; kk<128; kk+=32){
        bf16x8 afr[2], bfr[4];
        #pragma unroll
        for (int mi=0;mi<2;mi++)
            afr[mi] = *(const bf16x8*)&A1[(w*32 + mi*16 + (lane&15))*LP + kk + (lane>>4)*8];
        #pragma unroll
        for (int ni=0;ni<4;ni++)
            bfr[ni] = *(const bf16x8*)&B1[(ni*16 + (lane&15))*LP + kk + (lane>>4)*8];
        #pragma unroll
        for (int mi=0;mi<2;mi++)
            #pragma unroll
            for (int ni=0;ni<4;ni++)
                acc[mi][ni] = __builtin_amdgcn_mfma_f32_16x16x32_bf16(afr[mi], bfr[ni], acc[mi][ni], 0,0,0);
    }
    __syncthreads();
    {
        int l = tid>>1, n0 = (tid&1)*64;
        float e1 = expf(csl[l]);
        const bf16* crow = xc + (tok0+l)*CONVD + 4224;
        #pragma unroll
        for (int v=0;v<8;v++){
            bf16x8 cv = *(const bf16x8*)&crow[n0 + v*8];
            bf16x8 o;
            #pragma unroll
            for (int e=0;e<8;e++) o[e] = (bf16)((float)cv[e]*e1);
            *(bf16x8*)&A1[l*LP + n0 + v*8] = o;
        }
    }
    {
        int p = tid>>2, n0 = (tid&3)*32;
        const bf16* hrow = hst + (long)blk*8192 + (long)p*128 + n0;
        #pragma unroll
        for (int v=0;v<4;v++)
            *(bf16x8*)&B1[p*LP + n0 + v*8] = *(const bf16x8*)&hrow[v*8];
    }
    __syncthreads();
    #pragma unroll
    for (int kk=0; kk<128; kk+=32){
        bf16x8 afr[2], bfr[4];
        #pragma unroll
        for (int mi=0;mi<2;mi++)
            afr[mi] = *(const bf16x8*)&A1[(w*32 + mi*16 + (lane&15))*LP + kk + (lane>>4)*8];
        #pragma unroll
        for (int ni=0;ni<4;ni++)
            bfr[ni] = *(const bf16x8*)&B1[(ni*16 + (lane&15))*LP + kk + (lane>>4)*8];
        #pragma unroll
        for (int mi=0;mi<2;mi++)
            #pragma unroll
            for (int ni=0;ni<4;ni++)
                acc[mi][ni] = __builtin_amdgcn_mfma_f32_16x16x32_bf16(afr[mi], bfr[ni], acc[mi][ni], 0,0,0);
    }
    #pragma unroll
    for (int mi=0;mi<2;mi++)
        #pragma unroll
        for (int ni=0;ni<4;ni++){
            int l0 = w*32 + mi*16 + (lane>>4)*4;
            int p  = ni*16 + (lane&15);
            #pragma unroll
            for (int j=0;j<4;j++)
                Ybf[(tok0 + l0 + j)*DI + h*64 + p] = (bf16)acc[mi][ni][j];
        }
}

// ---------------- gate (silu(z)) + D*x + RMSNorm + cast bf16 ----------------
__global__ __launch_bounds__(256) void gatenorm_kernel(const bf16* __restrict__ Ybf,
                                                       const bf16* __restrict__ zx,
                                                       const bf16* __restrict__ xc,
                                                       const float* __restrict__ Dp,
                                                       const float* __restrict__ nw,
                                                       bf16* __restrict__ ybn){
    __shared__ float red[4];
    int tok = blockIdx.x, tid = threadIdx.x;
    const bf16* yrow = Ybf + (long)tok*DI;
    const bf16* zrow = zx  + (long)tok*ZLD;
    const bf16* xrow = xc  + (long)tok*CONVD;
    float yg[16];
    float ss = 0.f;
    #pragma unroll
    for (int k=0;k<4;k++){
        int d = (tid + k*256)*4;
        bf16x4 yv = *(const bf16x4*)&yrow[d];
        bf16x4 zv = *(const bf16x4*)&zrow[d];
        bf16x4 xv = *(const bf16x4*)&xrow[d];
        float dh = Dp[d>>6];
        #pragma unroll
        for (int e=0;e<4;e++){
            float yy = (float)yv[e] + dh*(float)xv[e];
            float g = yy*silu_f((float)zv[e]);
            yg[k*4+e] = g;
            ss += g*g;
        }
    }
    #pragma unroll
    for (int off=32; off>0; off>>=1) ss += __shfl_down(ss, off, 64);
    if ((tid & 63) == 0) red[tid>>6] = ss;
    __syncthreads();
    float tot = red[0]+red[1]+red[2]+red[3];
    float scale = rsqrtf(tot/(float)DI + 1e-5f);
    #pragma unroll
    for (int k=0;k<4;k++){
        int d = (tid + k*256)*4;
        float4 wv = *(const float4*)&nw[d];
        bf16x4 o;
        o[0]=(bf16)(yg[k*4+0]*scale*wv.x);
        o[1]=(bf16)(yg[k*4+1]*scale*wv.y);
        o[2]=(bf16)(yg[k*4+2]*scale*wv.z);
        o[3]=(bf16)(yg[k*4+3]*scale*wv.w);
        *(bf16x4*)&ybn[(long)tok*DI + d] = o;
    }
}

// ---------------- launch ----------------
extern "C" void kernel_launch(void* const* d_in, const int* in_sizes, int n_in,
                              void* d_out, int out_size, void* d_ws, size_t ws_size,
                              hipStream_t stream){
    const float* hs      = (const float*)d_in[0];
    const float* W_in    = (const float*)d_in[1];
    const float* W_conv  = (const float*)d_in[2];
    const float* b_conv  = (const float*)d_in[3];
    const float* A_log   = (const float*)d_in[4];
    const float* Dp      = (const float*)d_in[5];
    const float* dt_bias = (const float*)d_in[6];
    const float* nw      = (const float*)d_in[7];
    const float* W_out   = (const float*)d_in[8];
    float* out = (float*)d_out;

    char* ws = (char*)d_ws;
    const size_t OFF_ZX    = 0;                    // bf16 [4096][8704]      71,303,168
    const size_t OFF_DTF   = 71303168;             // f32  [4096][64]         1,048,576
    const size_t OFF_XC    = 72351744;             // bf16 [4096][4352]      35,651,584
    const size_t OFF_DTV   = 108003328;            // f32                     1,048,576
    const size_t OFF_DACS  = 109051904;            //                         1,048,576
    const size_t OFF_CDEC  = 110100480;            // f32 [2048]                  8,192
    const size_t OFF_CB    = 110108672;            // f32 [32][128][128]      2,097,152
    const size_t OFF_SLOTA = 112205824;            // 67,108,864: hsb+winb -> states -> Ybf -> gemm2 partials
    const size_t OFF_SLOTB = 179314688;            // 33,554,432: hst(bf16) -> ybn
    const size_t OFF_WOUTB = 212869120;            // bf16 [2048][4096]      16,777,216

    bf16*  zx    = (bf16*)(ws + OFF_ZX);
    float* dtf   = (float*)(ws + OFF_DTF);
    bf16*  xc    = (bf16*)(ws + OFF_XC);
    float* dtv   = (float*)(ws + OFF_DTV);
    float* dacs  = (float*)(ws + OFF_DACS);
    float* cdec  = (float*)(ws + OFF_CDEC);
    float* cbuf  = (float*)(ws + OFF_CB);
    bf16*  hsb   = (bf16*)(ws + OFF_SLOTA);
    bf16*  winb  = (bf16*)(ws + OFF_SLOTA + 16777216);
    float* states= (float*)(ws + OFF_SLOTA);
    bf16*  Ybf   = (bf16*)(ws + OFF_SLOTA);
    float* part  = (float*)(ws + OFF_SLOTA);       // 2 x [4096][2048] f32 split-K partials
    bf16*  hst   = (bf16*)(ws + OFF_SLOTB);
    bf16*  ybn   = (bf16*)(ws + OFF_SLOTB);
    bf16*  woutb = (bf16*)(ws + OFF_WOUTB);

    cvt_f32_bf16<<<8192, 256, 0, stream>>>(hs, hsb, NTOK*DMODEL);
    cvt_pad_rows<<<17408, 256, 0, stream>>>(W_in, winb, DPROJ, ZLD*DMODEL);
    cvt_f32_bf16<<<8192, 256, 0, stream>>>(W_out, woutb, DMODEL*DI);

    // GEMM1: [4096,2048] x [8704,2048]^T -> zx bf16 [4096][8704] + dtf
    gemm256_kernel<1><<<544, 512, 0, stream>>>(hsb, winb, (void*)zx, dtf,
                                               34, 16, DMODEL, ZLD);

    conv_silu_kernel<<<dim3(17, NTOK), 256, 0, stream>>>(zx, W_conv, b_conv, xc);
    dtcum_kernel<<<32, 64, 0, stream>>>(dtf, A_log, dt_bias, dtv, dacs, cdec);
    cb_mfma_kernel<<<32, 256, 0, stream>>>(xc, cbuf);
    states_mfma_kernel<<<2048, 256, 0, stream>>>(xc, dtv, dacs, states);
    scan_kernel<<<4096, 256, 0, stream>>>(states, cdec, hst);
    yfused_kernel<<<2048, 256, 0, stream>>>(xc, cbuf, hst, dtv, dacs, Ybf);
    gatenorm_kernel<<<4096, 256, 0, stream>>>(Ybf, zx, xc, Dp, nw, ybn);

    // GEMM2: [4096,4096] x [2048,4096]^T, split-K=2 -> partials, then reduce
    gemm256_kernel<2><<<256, 512, 0, stream>>>(ybn, woutb, (void*)part, nullptr,
                                               8, 16, DI, DMODEL);
    reduce_add_kernel<<<8192, 256, 0, stream>>>(part, out, NTOK*DMODEL);
}

// Round 5
// 602.145 us; speedup vs baseline: 1.6128x; 1.0061x over previous
//
#include <hip/hip_runtime.h>
#include <hip/hip_bf16.h>
#include <stdint.h>

typedef __bf16 bf16;
typedef __bf16 bf16x8 __attribute__((ext_vector_type(8)));
typedef __bf16 bf16x4 __attribute__((ext_vector_type(4)));
typedef float f32x4v __attribute__((ext_vector_type(4)));

#define SEQ    2048
#define DMODEL 2048
#define DI     4096
#define NH     64
#define PDIM   64
#define CHUNKL 128
#define NCH    16
#define CONVD  4352
#define DPROJ  8512
#define ZLD    8704   // zxbcdt leading dim, padded to 34*256
#define NTOK   4096
#define LP     136    // padded LDS leading dim for middle kernels

__device__ __forceinline__ float sigmoid_f(float x){ return 1.f/(1.f+expf(-x)); }
__device__ __forceinline__ float silu_f(float x){ return x*sigmoid_f(x); }
__device__ __forceinline__ float softplus_f(float x){ return x > 20.f ? x : log1pf(expf(x)); }

// ---------------- conversions ----------------
__global__ __launch_bounds__(256) void cvt_f32_bf16(const float* __restrict__ src,
                                                    bf16* __restrict__ dst, int n){
    int i = (blockIdx.x*256 + threadIdx.x)*4;
    if (i + 3 >= n) return;
    float4 v = *(const float4*)&src[i];
    bf16x4 o; o[0]=(bf16)v.x; o[1]=(bf16)v.y; o[2]=(bf16)v.z; o[3]=(bf16)v.w;
    *(bf16x4*)&dst[i] = o;
}

__global__ __launch_bounds__(256) void cvt_pad_rows(const float* __restrict__ src,
                                                    bf16* __restrict__ dst,
                                                    int rows_valid, int total){
    int i = (blockIdx.x*256 + threadIdx.x)*4;
    if (i + 3 >= total) return;
    int r = i >> 11;
    bf16x4 o;
    if (r < rows_valid){
        float4 v = *(const float4*)&src[i];
        o[0]=(bf16)v.x; o[1]=(bf16)v.y; o[2]=(bf16)v.z; o[3]=(bf16)v.w;
    } else {
        o[0]=(bf16)0.f; o[1]=(bf16)0.f; o[2]=(bf16)0.f; o[3]=(bf16)0.f;
    }
    *(bf16x4*)&dst[i] = o;
}

// ============ 256x256 8-phase bf16 GEMM: C = A * B^T ============
// Template-exact schedule: per phase {ds_read frags || stage gload || counted vmcnt}
// -> sched_barrier -> s_barrier -> lgkmcnt(0) -> setprio(1) 16xMFMA setprio(0) -> s_barrier.
// LDS per buffer: A'[256][64] + B'[256][64]; row remap A': [qm][wm-half][64], B': [qn][wn][32]
// swizzle: 16B slot ^= (ldsrow&7) on BOTH global-source (stage) and ds_read.
#define READ_A(BUFP, QM)                                                               \
    {                                                                                  \
        _Pragma("unroll")                                                              \
        for (int i=0;i<4;i++)                                                          \
            _Pragma("unroll")                                                          \
            for (int k2=0;k2<2;k2++){                                                  \
                int ra = (QM)*128 + wm*64 + i*16 + (lane&15);                          \
                int slot = (k2*4 + (lane>>4)) ^ (ra&7);                                \
                af[i][k2] = *(const bf16x8*)&(BUFP)[ra*64 + slot*8];                   \
            }                                                                          \
    }

#define READ_B(BUFP, QN)                                                               \
    {                                                                                  \
        const bf16* Bp = (BUFP) + 16384;                                               \
        _Pragma("unroll")                                                              \
        for (int nf=0;nf<2;nf++)                                                       \
            _Pragma("unroll")                                                          \
            for (int k2=0;k2<2;k2++){                                                  \
                int rb = (QN)*128 + wn*32 + nf*16 + (lane&15);                         \
                int slot = (k2*4 + (lane>>4)) ^ (rb&7);                                \
                bfr[nf][k2] = *(const bf16x8*)&Bp[rb*64 + slot*8];                     \
            }                                                                          \
    }

#define MMA_Q(QM, QN)                                                                  \
    {                                                                                  \
        __builtin_amdgcn_s_setprio(1);                                                 \
        _Pragma("unroll")                                                              \
        for (int i=0;i<4;i++)                                                          \
            _Pragma("unroll")                                                          \
            for (int nf=0;nf<2;nf++)                                                   \
                _Pragma("unroll")                                                      \
                for (int k2=0;k2<2;k2++)                                               \
                    acc[(QM)*4+i][(QN)*2+nf] = __builtin_amdgcn_mfma_f32_16x16x32_bf16( \
                        af[i][k2], bfr[nf][k2], acc[(QM)*4+i][(QN)*2+nf], 0,0,0);      \
        __builtin_amdgcn_s_setprio(0);                                                 \
    }

#define SBAR() do { __builtin_amdgcn_sched_barrier(0);                                 \
                    __builtin_amdgcn_s_barrier();                                      \
                    asm volatile("s_waitcnt lgkmcnt(0)" ::: "memory");                 \
                    __builtin_amdgcn_sched_barrier(0); } while(0)
#define EBAR() do { __builtin_amdgcn_s_barrier();                                      \
                    __builtin_amdgcn_sched_barrier(0); } while(0)

template<int MODE>
__global__ __launch_bounds__(512) void gemm256_kernel(const bf16* __restrict__ A,
                                                      const bf16* __restrict__ Bmat,
                                                      void* __restrict__ Cout,
                                                      float* __restrict__ dtf,
                                                      int NXB, int NYB, int K, int ldc){
    __shared__ __align__(16) bf16 lds[2][2*16384];   // [buf][A(16384) | B(16384)]
    const int tid  = threadIdx.x;
    const int w    = tid >> 6;
    const int lane = tid & 63;
    const int wm   = w >> 2, wn = w & 3;

    int bid  = blockIdx.x;
    int nb2  = (MODE==2) ? ((int)gridDim.x >> 1) : (int)gridDim.x;
    int kz   = (MODE==2) ? (bid / nb2) : 0;
    int bid2 = (MODE==2) ? (bid % nb2) : bid;
    int wg   = (bid2 & 7)*(nb2 >> 3) + (bid2 >> 3);
    const int SW = 8;
    int sup = wg / (SW*NYB);
    int rr  = wg % (SW*NYB);
    int x0  = sup*SW;
    int wl  = (NXB - x0 < SW) ? (NXB - x0) : SW;
    int x   = x0 + rr % wl;
    int y   = rr / wl;
    const int tm = y*256, tn = x*256;

    const int KT  = (MODE==2) ? (K >> 7) : (K >> 6);   // K-tiles this block handles
    const int kt0 = (MODE==2) ? kz*KT : 0;

    f32x4v acc[8][4];
    #pragma unroll
    for (int i=0;i<8;i++)
        #pragma unroll
        for (int j=0;j<4;j++) acc[i][j] = {0.f,0.f,0.f,0.f};
    bf16x8 af[4][2];
    bf16x8 bfr[2][2];

    auto stageA = [&](int buf, int t, int r0){
        bf16* mat = &lds[buf][0];
        int ktcol = (kt0 + t)*64;
        #pragma unroll
        for (int i=0;i<2;i++){
            int lr = r0 + i*64 + (tid>>3);
            int grow = tm + ((lr>>6)&1)*128 + (lr>>7)*64 + (lr&63);
            int gslot = (tid&7) ^ (lr&7);
            const bf16* src = A + (long)grow*K + ktcol + gslot*8;
            bf16* dst = mat + (size_t)(r0 + i*64 + w*8)*64;   // wave-uniform; HW adds lane*16B
            __builtin_amdgcn_global_load_lds(
                (const __attribute__((address_space(1))) void*)src,
                (__attribute__((address_space(3))) void*)dst, 16, 0, 0);
        }
    };
    auto stageB = [&](int buf, int t, int r0){
        bf16* mat = &lds[buf][16384];
        int ktcol = (kt0 + t)*64;
        #pragma unroll
        for (int i=0;i<2;i++){
            int lr = r0 + i*64 + (tid>>3);
            int grow = tn + ((lr>>5)&3)*64 + (lr>>7)*32 + (lr&31);
            int gslot = (tid&7) ^ (lr&7);
            const bf16* src = Bmat + (long)grow*K + ktcol + gslot*8;
            bf16* dst = mat + (size_t)(r0 + i*64 + w*8)*64;
            __builtin_amdgcn_global_load_lds(
                (const __attribute__((address_space(1))) void*)src,
                (__attribute__((address_space(3))) void*)dst, 16, 0, 0);
        }
    };

    // ---- prologue: A0(0) B0(0) A1(0) B1(0) A0(1) B0(1); wait oldest 2 stages ----
    stageA(0, 0, 0);
    stageB(0, 0, 0);
    stageA(0, 0, 128);
    stageB(0, 0, 128);
    if (KT > 1){ stageA(1, 1, 0); stageB(1, 1, 0); }
    asm volatile("s_waitcnt vmcnt(8)" ::: "memory");
    __builtin_amdgcn_s_barrier();

    int cur = 0;
    for (int t = 0; t < KT; ++t){
        int nxt = cur ^ 1;
        const bf16* bufc = &lds[cur][0];
        // ---- P0: quadrant (0,0) ----
        READ_A(bufc, 0)
        READ_B(bufc, 0)
        if (t+1 < KT) stageA(nxt, t+1, 128);          // A1(t+1)
        asm volatile("s_waitcnt vmcnt(6)" ::: "memory");
        SBAR();
        MMA_Q(0, 0)
        EBAR();
        // ---- P1: quadrant (0,1) ----
        READ_B(bufc, 1)
        if (t+1 < KT) stageB(nxt, t+1, 128);          // B1(t+1)
        asm volatile("s_waitcnt vmcnt(4)" ::: "memory");
        SBAR();
        MMA_Q(0, 1)
        EBAR();
        // ---- P2: quadrant (1,0) ----
        READ_A(bufc, 1)
        READ_B(bufc, 0)
        if (t+2 < KT) stageA(cur, t+2, 0);            // A0(t+2) into freed region
        SBAR();
        MMA_Q(1, 0)
        EBAR();
        // ---- P3: quadrant (1,1) ----
        READ_B(bufc, 1)
        if (t+2 < KT) stageB(cur, t+2, 0);            // B0(t+2) into freed region
        SBAR();
        MMA_Q(1, 1)
        EBAR();
        cur = nxt;
    }

    // ---- epilogue ----
    const int er = (lane>>4)*4, ec = lane&15;
    #pragma unroll
    for (int mi=0;mi<8;mi++)
        #pragma unroll
        for (int ni=0;ni<4;ni++){
            long r0 = tm + wm*128 + mi*16 + er;
            int  c0 = tn + wn*64 + ni*16 + ec;
            #pragma unroll
            for (int j=0;j<4;j++){
                float val = acc[mi][ni][j];
                if (MODE == 1){
                    ((bf16*)Cout)[(r0+j)*ldc + c0] = (bf16)val;
                    if (c0 >= 8448 && c0 < 8512)
                        dtf[(r0+j)*64 + (c0 - 8448)] = val;
                } else {
                    ((float*)Cout)[(long)kz*NYB*256*ldc + (r0+j)*ldc + c0] = val;
                }
            }
        }
}

// ---------------- split-K reduce: out = p0 + p1 ----------------
__global__ __launch_bounds__(256) void reduce_add_kernel(const float* __restrict__ p,
                                                         float* __restrict__ out, int n){
    int i = (blockIdx.x*256 + threadIdx.x)*4;
    if (i + 3 >= n) return;
    float4 a = *(const float4*)&p[i];
    float4 b = *(const float4*)&p[i + 8388608];
    a.x+=b.x; a.y+=b.y; a.z+=b.z; a.w+=b.w;
    *(float4*)&out[i] = a;
}

// ---------------- depthwise causal conv(4) + bias + silu ----------------
__global__ __launch_bounds__(256) void conv_silu_kernel(const bf16* __restrict__ zx,
                                                        const float* __restrict__ Wc,
                                                        const float* __restrict__ bc,
                                                        bf16* __restrict__ xc){
    int ch  = blockIdx.x*256 + threadIdx.x;
    int tok = blockIdx.y;
    int b = tok >> 11, t = tok & 2047;
    float w0=Wc[ch*4+0], w1=Wc[ch*4+1], w2=Wc[ch*4+2], w3=Wc[ch*4+3];
    const bf16* col = zx + (long)(b*SEQ)*ZLD + 4096 + ch;
    float acc = bc[ch];
    if (t>=3) acc += (float)col[(long)(t-3)*ZLD]*w0;
    if (t>=2) acc += (float)col[(long)(t-2)*ZLD]*w1;
    if (t>=1) acc += (float)col[(long)(t-1)*ZLD]*w2;
    acc += (float)col[(long)t*ZLD]*w3;
    xc[(long)tok*CONVD + ch] = (bf16)silu_f(acc);
}

// ---------------- dt softplus + per-chunk cumsum ----------------
__global__ void dtcum_kernel(const float* __restrict__ dtf, const float* __restrict__ A_log,
                             const float* __restrict__ dt_bias,
                             float* __restrict__ dtv, float* __restrict__ dacs,
                             float* __restrict__ cdec){
    int blk = blockIdx.x;        // b*16+c
    int h   = threadIdx.x;       // 0..63
    int b = blk >> 4, c = blk & 15;
    float Ah = -expf(A_log[h]);
    float bias = dt_bias[h];
    float cs = 0.f;
    long base_h = ((long)blk*64 + h)*128;
    const float* src = dtf + (long)(b*SEQ + c*CHUNKL)*64 + h;
    for (int l=0;l<CHUNKL;l++){
        float d = softplus_f(src[(long)l*64] + bias);
        cs += d*Ah;
        dtv[base_h+l]  = d;
        dacs[base_h+l] = cs;
    }
    cdec[blk*64 + h] = expf(cs);
}

// ---------------- CB[l][s] = sum_n C[l][n]*B[s][n] via MFMA, per (b,c) ----------------
__global__ __launch_bounds__(256) void cb_mfma_kernel(const bf16* __restrict__ xc,
                                                      float* __restrict__ cb){
    __shared__ __align__(16) bf16 A1[128*LP];
    __shared__ __align__(16) bf16 B1[128*LP];
    int blk = blockIdx.x;  int b = blk>>4, c = blk&15;
    int tid = threadIdx.x;
    const int w = tid >> 6, lane = tid & 63;
    long tok0 = (long)(b*SEQ + c*CHUNKL);
    int l = tid>>1, n0 = (tid&1)*64;
    const bf16* crow = xc + tok0*CONVD + (long)l*CONVD;
    #pragma unroll
    for (int v=0;v<8;v++){
        *(bf16x8*)&A1[l*LP + n0 + v*8] = *(const bf16x8*)&crow[4224 + n0 + v*8];
        *(bf16x8*)&B1[l*LP + n0 + v*8] = *(const bf16x8*)&crow[4096 + n0 + v*8];
    }
    __syncthreads();
    f32x4v acc[2][8];
    #pragma unroll
    for (int mi=0;mi<2;mi++)
        #pragma unroll
        for (int ni=0;ni<8;ni++) acc[mi][ni] = {0.f,0.f,0.f,0.f};
    #pragma unroll
    for (int kk=0; kk<128; kk+=32){
        bf16x8 afr[2], bfr2[8];
        #pragma unroll
        for (int mi=0;mi<2;mi++)
            afr[mi] = *(const bf16x8*)&A1[(w*32 + mi*16 + (lane&15))*LP + kk + (lane>>4)*8];
        #pragma unroll
        for (int ni=0;ni<8;ni++)
            bfr2[ni] = *(const bf16x8*)&B1[(ni*16 + (lane&15))*LP + kk + (lane>>4)*8];
        #pragma unroll
        for (int mi=0;mi<2;mi++)
            #pragma unroll
            for (int ni=0;ni<8;ni++)
                acc[mi][ni] = __builtin_amdgcn_mfma_f32_16x16x32_bf16(afr[mi], bfr2[ni], acc[mi][ni], 0,0,0);
    }
    float* out = cb + (long)blk*16384;
    #pragma unroll
    for (int mi=0;mi<2;mi++)
        #pragma unroll
        for (int ni=0;ni<8;ni++){
            int r0 = w*32 + mi*16 + (lane>>4)*4;
            int c0 = ni*16 + (lane&15);
            #pragma unroll
            for (int j=0;j<4;j++) out[(long)(r0+j)*128 + c0] = acc[mi][ni][j];
        }
}

// ---------------- states[p][n] via MFMA, per (b,c,h) ----------------
__global__ __launch_bounds__(256) void states_mfma_kernel(const bf16* __restrict__ xc,
                                                          const float* __restrict__ dtv,
                                                          const float* __restrict__ dacs,
                                                          float* __restrict__ states){
    __shared__ __align__(16) bf16 A1[64*LP];
    __shared__ __align__(16) bf16 B1[128*LP];
    __shared__ float wgtl[128];
    int blk = blockIdx.x;
    int h = blk & 63, bc = blk >> 6;
    int b = bc >> 4, c = bc & 15;
    int tid = threadIdx.x;
    const int w = tid >> 6, lane = tid & 63;
    long tok0 = (long)(b*SEQ + c*CHUNKL);
    long base_h = (long)blk*128;
    float cs_last = dacs[base_h + 127];
    if (tid < 128) wgtl[tid] = dtv[base_h+tid] * expf(cs_last - dacs[base_h+tid]);
    __syncthreads();
    #pragma unroll
    for (int t=0;t<4;t++){
        int l = (tid>>3) + t*32;
        int p0 = (tid&7)*8;
        bf16x8 xv = *(const bf16x8*)&xc[(tok0+l)*CONVD + h*64 + p0];
        float wv = wgtl[l];
        #pragma unroll
        for (int e=0;e<8;e++) A1[(p0+e)*LP + l] = (bf16)((float)xv[e]*wv);
    }
    {
        int l = tid>>1, n0 = (tid&1)*64;
        const bf16* brow = xc + (tok0+l)*CONVD + 4096;
        #pragma unroll
        for (int v=0;v<8;v++){
            bf16x8 bv = *(const bf16x8*)&brow[n0 + v*8];
            #pragma unroll
            for (int e=0;e<8;e++) B1[(n0+v*8+e)*LP + l] = bv[e];
        }
    }
    __syncthreads();
    f32x4v acc[8];
    #pragma unroll
    for (int ni=0;ni<8;ni++) acc[ni] = {0.f,0.f,0.f,0.f};
    #pragma unroll
    for (int kk=0; kk<128; kk+=32){
        bf16x8 afr = *(const bf16x8*)&A1[(w*16 + (lane&15))*LP + kk + (lane>>4)*8];
        #pragma unroll
        for (int ni=0;ni<8;ni++){
            bf16x8 bfr2 = *(const bf16x8*)&B1[(ni*16 + (lane&15))*LP + kk + (lane>>4)*8];
            acc[ni] = __builtin_amdgcn_mfma_f32_16x16x32_bf16(afr, bfr2, acc[ni], 0,0,0);
        }
    }
    float* out = states + (long)blk*8192;
    #pragma unroll
    for (int ni=0;ni<8;ni++){
        int p0 = w*16 + (lane>>4)*4;
        int n  = ni*16 + (lane&15);
        #pragma unroll
        for (int j=0;j<4;j++) out[(long)(p0+j)*128 + n] = acc[ni][j];
    }
}

// ---------------- sequential chunk scan ----------------
__global__ __launch_bounds__(256) void scan_kernel(const float* __restrict__ states,
                                                   const float* __restrict__ cdec,
                                                   bf16* __restrict__ hst){
    long gid = (long)blockIdx.x*256 + threadIdx.x;
    int n = gid & 127;
    int p = (gid >> 7) & 63;
    int h = (gid >> 13) & 63;
    int b = (int)(gid >> 19);
    float hrun = 0.f;
    for (int c=0;c<16;c++){
        long idx = ((((long)(b*16 + c)*64 + h)*64 + p)*128) + n;
        hst[idx] = (bf16)hrun;
        hrun = hrun * cdec[(b*16+c)*64 + h] + states[idx];
    }
}

// ---------------- fused Y = P@u^T + (C*sdo)@hst^T ----------------
__global__ __launch_bounds__(256) void yfused_kernel(const bf16* __restrict__ xc,
                                                     const float* __restrict__ cb,
                                                     const bf16* __restrict__ hst,
                                                     const float* __restrict__ dtv,
                                                     const float* __restrict__ dacs,
                                                     bf16* __restrict__ Ybf){
    __shared__ __align__(16) bf16 A1[128*LP];
    __shared__ __align__(16) bf16 B1[64*LP];
    __shared__ float csl[128];
    int blk = blockIdx.x;
    int h = blk & 63, bc = blk >> 6;
    int b = bc >> 4, c = bc & 15;
    int tid = threadIdx.x;
    const int w = tid >> 6, lane = tid & 63;
    long tok0 = (long)(b*SEQ + c*CHUNKL);
    long base_h = (long)blk*128;
    if (tid < 128) csl[tid] = dacs[base_h + tid];
    __syncthreads();
    {
        int l = tid>>1, s0 = (tid&1)*64;
        float el = csl[l];
        const float* cbrow = cb + (long)bc*16384 + (long)l*128 + s0;
        #pragma unroll 8
        for (int j=0;j<64;j++){
            int s = s0 + j;
            float v = (s <= l) ? cbrow[j]*expf(el - csl[s]) : 0.f;
            A1[l*LP + s] = (bf16)v;
        }
    }
    #pragma unroll
    for (int t=0;t<4;t++){
        int s = (tid>>3) + t*32;
        int p0 = (tid&7)*8;
        bf16x8 xv = *(const bf16x8*)&xc[(tok0+s)*CONVD + h*64 + p0];
        float wv = dtv[base_h + s];
        #pragma unroll
        for (int e=0;e<8;e++) B1[(p0+e)*LP + s] = (bf16)((float)xv[e]*wv);
    }
    __syncthreads();
    f32x4v acc[2][4];
    #pragma unroll
    for (int mi=0;mi<2;mi++)
        #pragma unroll
        for (int ni=0;ni<4;ni++) acc[mi][ni] = {0.f,0.f,0.f,0.f};
    #pragma unroll
    for (int kk=0; kk<128; kk+=32){
        bf16x8 afr[2], bfr2[4];
        #pragma unroll
        for (int mi=0;mi<2;mi++)
            afr[mi] = *(const bf16x8*)&A1[(w*32 + mi*16 + (lane&15))*LP + kk + (lane>>4)*8];
        #pragma unroll
        for (int ni=0;ni<4;ni++)
            bfr2[ni] = *(const bf16x8*)&B1[(ni*16 + (lane&15))*LP + kk + (lane>>4)*8];
        #pragma unroll
        for (int mi=0;mi<2;mi++)
            #pragma unroll
            for (int ni=0;ni<4;ni++)
                acc[mi][ni] = __builtin_amdgcn_mfma_f32_16x16x32_bf16(afr[mi], bfr2[ni], acc[mi][ni], 0,0,0);
    }
    __syncthreads();
    {
        int l = tid>>1, n0 = (tid&1)*64;
        float e1 = expf(csl[l]);
        const bf16* crow = xc + (tok0+l)*CONVD + 4224;
        #pragma unroll
        for (int v=0;v<8;v++){
            bf16x8 cv = *(const bf16x8*)&crow[n0 + v*8];
            bf16x8 o;
            #pragma unroll
            for (int e=0;e<8;e++) o[e] = (bf16)((float)cv[e]*e1);
            *(bf16x8*)&A1[l*LP + n0 + v*8] = o;
        }
    }
    {
        int p = tid>>2, n0 = (tid&3)*32;
        const bf16* hrow = hst + (long)blk*8192 + (long)p*128 + n0;
        #pragma unroll
        for (int v=0;v<4;v++)
            *(bf16x8*)&B1[p*LP + n0 + v*8] = *(const bf16x8*)&hrow[v*8];
    }
    __syncthreads();
    #pragma unroll
    for (int kk=0; kk<128; kk+=32){
        bf16x8 afr[2], bfr2[4];
        #pragma unroll
        for (int mi=0;mi<2;mi++)
            afr[mi] = *(const bf16x8*)&A1[(w*32 + mi*16 + (lane&15))*LP + kk + (lane>>4)*8];
        #pragma unroll
        for (int ni=0;ni<4;ni++)
            bfr2[ni] = *(const bf16x8*)&B1[(ni*16 + (lane&15))*LP + kk + (lane>>4)*8];
        #pragma unroll
        for (int mi=0;mi<2;mi++)
            #pragma unroll
            for (int ni=0;ni<4;ni++)
                acc[mi][ni] = __builtin_amdgcn_mfma_f32_16x16x32_bf16(afr[mi], bfr2[ni], acc[mi][ni], 0,0,0);
    }
    #pragma unroll
    for (int mi=0;mi<2;mi++)
        #pragma unroll
        for (int ni=0;ni<4;ni++){
            int l0 = w*32 + mi*16 + (lane>>4)*4;
            int p  = ni*16 + (lane&15);
            #pragma unroll
            for (int j=0;j<4;j++)
                Ybf[(tok0 + l0 + j)*DI + h*64 + p] = (bf16)acc[mi][ni][j];
        }
}

// ---------------- gate (silu(z)) + D*x + RMSNorm + cast bf16 ----------------
__global__ __launch_bounds__(256) void gatenorm_kernel(const bf16* __restrict__ Ybf,
                                                       const bf16* __restrict__ zx,
                                                       const bf16* __restrict__ xc,
                                                       const float* __restrict__ Dp,
                                                       const float* __restrict__ nw,
                                                       bf16* __restrict__ ybn){
    __shared__ float red[4];
    int tok = blockIdx.x, tid = threadIdx.x;
    const bf16* yrow = Ybf + (long)tok*DI;
    const bf16* zrow = zx  + (long)tok*ZLD;
    const bf16* xrow = xc  + (long)tok*CONVD;
    float yg[16];
    float ss = 0.f;
    #pragma unroll
    for (int k=0;k<4;k++){
        int d = (tid + k*256)*4;
        bf16x4 yv = *(const bf16x4*)&yrow[d];
        bf16x4 zv = *(const bf16x4*)&zrow[d];
        bf16x4 xv = *(const bf16x4*)&xrow[d];
        float dh = Dp[d>>6];
        #pragma unroll
        for (int e=0;e<4;e++){
            float yy = (float)yv[e] + dh*(float)xv[e];
            float g = yy*silu_f((float)zv[e]);
            yg[k*4+e] = g;
            ss += g*g;
        }
    }
    #pragma unroll
    for (int off=32; off>0; off>>=1) ss += __shfl_down(ss, off, 64);
    if ((tid & 63) == 0) red[tid>>6] = ss;
    __syncthreads();
    float tot = red[0]+red[1]+red[2]+red[3];
    float scale = rsqrtf(tot/(float)DI + 1e-5f);
    #pragma unroll
    for (int k=0;k<4;k++){
        int d = (tid + k*256)*4;
        float4 wv = *(const float4*)&nw[d];
        bf16x4 o;
        o[0]=(bf16)(yg[k*4+0]*scale*wv.x);
        o[1]=(bf16)(yg[k*4+1]*scale*wv.y);
        o[2]=(bf16)(yg[k*4+2]*scale*wv.z);
        o[3]=(bf16)(yg[k*4+3]*scale*wv.w);
        *(bf16x4*)&ybn[(long)tok*DI + d] = o;
    }
}

// ---------------- launch ----------------
extern "C" void kernel_launch(void* const* d_in, const int* in_sizes, int n_in,
                              void* d_out, int out_size, void* d_ws, size_t ws_size,
                              hipStream_t stream){
    const float* hs      = (const float*)d_in[0];
    const float* W_in    = (const float*)d_in[1];
    const float* W_conv  = (const float*)d_in[2];
    const float* b_conv  = (const float*)d_in[3];
    const float* A_log   = (const float*)d_in[4];
    const float* Dp      = (const float*)d_in[5];
    const float* dt_bias = (const float*)d_in[6];
    const float* nw      = (const float*)d_in[7];
    const float* W_out   = (const float*)d_in[8];
    float* out = (float*)d_out;

    char* ws = (char*)d_ws;
    const size_t OFF_ZX    = 0;                    // bf16 [4096][8704]      71,303,168
    const size_t OFF_DTF   = 71303168;             // f32  [4096][64]         1,048,576
    const size_t OFF_XC    = 72351744;             // bf16 [4096][4352]      35,651,584
    const size_t OFF_DTV   = 108003328;            // f32                     1,048,576
    const size_t OFF_DACS  = 109051904;            //                         1,048,576
    const size_t OFF_CDEC  = 110100480;            // f32 [2048]                  8,192
    const size_t OFF_CB    = 110108672;            // f32 [32][128][128]      2,097,152
    const size_t OFF_SLOTA = 112205824;            // 67,108,864: hsb+winb -> states -> Ybf -> gemm2 partials
    const size_t OFF_SLOTB = 179314688;            // 33,554,432: hst(bf16) -> ybn
    const size_t OFF_WOUTB = 212869120;            // bf16 [2048][4096]      16,777,216

    bf16*  zx    = (bf16*)(ws + OFF_ZX);
    float* dtf   = (float*)(ws + OFF_DTF);
    bf16*  xc    = (bf16*)(ws + OFF_XC);
    float* dtv   = (float*)(ws + OFF_DTV);
    float* dacs  = (float*)(ws + OFF_DACS);
    float* cdec  = (float*)(ws + OFF_CDEC);
    float* cbuf  = (float*)(ws + OFF_CB);
    bf16*  hsb   = (bf16*)(ws + OFF_SLOTA);
    bf16*  winb  = (bf16*)(ws + OFF_SLOTA + 16777216);
    float* states= (float*)(ws + OFF_SLOTA);
    bf16*  Ybf   = (bf16*)(ws + OFF_SLOTA);
    float* part  = (float*)(ws + OFF_SLOTA);       // 2 x [4096][2048] f32 split-K partials
    bf16*  hst   = (bf16*)(ws + OFF_SLOTB);
    bf16*  ybn   = (bf16*)(ws + OFF_SLOTB);
    bf16*  woutb = (bf16*)(ws + OFF_WOUTB);

    cvt_f32_bf16<<<8192, 256, 0, stream>>>(hs, hsb, NTOK*DMODEL);
    cvt_pad_rows<<<17408, 256, 0, stream>>>(W_in, winb, DPROJ, ZLD*DMODEL);
    cvt_f32_bf16<<<8192, 256, 0, stream>>>(W_out, woutb, DMODEL*DI);

    // GEMM1: [4096,2048] x [8704,2048]^T -> zx bf16 [4096][8704] + dtf
    gemm256_kernel<1><<<544, 512, 0, stream>>>(hsb, winb, (void*)zx, dtf,
                                               34, 16, DMODEL, ZLD);

    conv_silu_kernel<<<dim3(17, NTOK), 256, 0, stream>>>(zx, W_conv, b_conv, xc);
    dtcum_kernel<<<32, 64, 0, stream>>>(dtf, A_log, dt_bias, dtv, dacs, cdec);
    cb_mfma_kernel<<<32, 256, 0, stream>>>(xc, cbuf);
    states_mfma_kernel<<<2048, 256, 0, stream>>>(xc, dtv, dacs, states);
    scan_kernel<<<4096, 256, 0, stream>>>(states, cdec, hst);
    yfused_kernel<<<2048, 256, 0, stream>>>(xc, cbuf, hst, dtv, dacs, Ybf);
    gatenorm_kernel<<<4096, 256, 0, stream>>>(Ybf, zx, xc, Dp, nw, ybn);

    // GEMM2: [4096,4096] x [2048,4096]^T, split-K=2 -> partials, then reduce
    gemm256_kernel<2><<<256, 512, 0, stream>>>(ybn, woutb, (void*)part, nullptr,
                                               8, 16, DI, DMODEL);
    reduce_add_kernel<<<8192, 256, 0, stream>>>(part, out, NTOK*DMODEL);
}

// Round 6
// 532.924 us; speedup vs baseline: 1.8223x; 1.1299x over previous
//
#include <hip/hip_runtime.h>
#include <hip/hip_bf16.h>
#include <stdint.h>

typedef __bf16 bf16;
typedef __bf16 bf16x8 __attribute__((ext_vector_type(8)));
typedef __bf16 bf16x4 __attribute__((ext_vector_type(4)));
typedef float f32x4v __attribute__((ext_vector_type(4)));

#define SEQ    2048
#define DMODEL 2048
#define DI     4096
#define NH     64
#define PDIM   64
#define CHUNKL 128
#define NCH    16
#define CONVD  4352
#define DPROJ  8512
#define ZLD    8704   // zxbcdt leading dim, padded to 34*256
#define NTOK   4096
#define LP     136    // padded LDS leading dim for middle kernels

__device__ __forceinline__ float sigmoid_f(float x){ return 1.f/(1.f+expf(-x)); }
__device__ __forceinline__ float silu_f(float x){ return x*sigmoid_f(x); }
__device__ __forceinline__ float softplus_f(float x){ return x > 20.f ? x : log1pf(expf(x)); }

// ---------------- conversions ----------------
__global__ __launch_bounds__(256) void cvt_f32_bf16(const float* __restrict__ src,
                                                    bf16* __restrict__ dst, int n){
    int i = (blockIdx.x*256 + threadIdx.x)*4;
    if (i + 3 >= n) return;
    float4 v = *(const float4*)&src[i];
    bf16x4 o; o[0]=(bf16)v.x; o[1]=(bf16)v.y; o[2]=(bf16)v.z; o[3]=(bf16)v.w;
    *(bf16x4*)&dst[i] = o;
}

__global__ __launch_bounds__(256) void cvt_pad_rows(const float* __restrict__ src,
                                                    bf16* __restrict__ dst,
                                                    int rows_valid, int total){
    int i = (blockIdx.x*256 + threadIdx.x)*4;
    if (i + 3 >= total) return;
    int r = i >> 11;
    bf16x4 o;
    if (r < rows_valid){
        float4 v = *(const float4*)&src[i];
        o[0]=(bf16)v.x; o[1]=(bf16)v.y; o[2]=(bf16)v.z; o[3]=(bf16)v.w;
    } else {
        o[0]=(bf16)0.f; o[1]=(bf16)0.f; o[2]=(bf16)0.f; o[3]=(bf16)0.f;
    }
    *(bf16x4*)&dst[i] = o;
}

// ============ 256x256 8-phase bf16 GEMM: C = A * B^T ============
// MODE 1: bf16 C (cols < 8192 only, bulk of GEMM1)
// MODE 2: split-K=2, f32 partials (GEMM2)
// MODE 3: GEMM1 tail (x in {32,33}), split-K=4, f32 partials [kz][4096][512]
// All loop-invariant addressing hoisted: global src pointers + ds_read offsets.
#define READ_A(BUFP, QM)                                                               \
    {                                                                                  \
        _Pragma("unroll")                                                              \
        for (int i=0;i<4;i++)                                                          \
            _Pragma("unroll")                                                          \
            for (int k2=0;k2<2;k2++)                                                   \
                af[i][k2] = *(const bf16x8*)&(BUFP)[aoff[i][k2] + (QM)*8192];          \
    }

#define READ_B(BUFP, QN)                                                               \
    {                                                                                  \
        _Pragma("unroll")                                                              \
        for (int nf=0;nf<2;nf++)                                                       \
            _Pragma("unroll")                                                          \
            for (int k2=0;k2<2;k2++)                                                   \
                bfr[nf][k2] = *(const bf16x8*)&(BUFP)[boff[nf][k2] + (QN)*8192];       \
    }

#define MMA_Q(QM, QN)                                                                  \
    {                                                                                  \
        __builtin_amdgcn_s_setprio(1);                                                 \
        _Pragma("unroll")                                                              \
        for (int i=0;i<4;i++)                                                          \
            _Pragma("unroll")                                                          \
            for (int nf=0;nf<2;nf++)                                                   \
                _Pragma("unroll")                                                      \
                for (int k2=0;k2<2;k2++)                                               \
                    acc[(QM)*4+i][(QN)*2+nf] = __builtin_amdgcn_mfma_f32_16x16x32_bf16( \
                        af[i][k2], bfr[nf][k2], acc[(QM)*4+i][(QN)*2+nf], 0,0,0);      \
        __builtin_amdgcn_s_setprio(0);                                                 \
    }

#define SBAR() do { __builtin_amdgcn_sched_barrier(0);                                 \
                    __builtin_amdgcn_s_barrier();                                      \
                    asm volatile("s_waitcnt lgkmcnt(0)" ::: "memory");                 \
                    __builtin_amdgcn_sched_barrier(0); } while(0)
#define EBAR() do { __builtin_amdgcn_s_barrier();                                      \
                    __builtin_amdgcn_sched_barrier(0); } while(0)

template<int MODE>
__global__ __launch_bounds__(512) void gemm256_kernel(const bf16* __restrict__ A,
                                                      const bf16* __restrict__ Bmat,
                                                      void* __restrict__ Cout,
                                                      int NXB, int NYB, int K, int ldc){
    __shared__ __align__(16) bf16 lds[2][2*16384];   // [buf][A(16384) | B(16384)]
    const int tid  = threadIdx.x;
    const int w    = tid >> 6;
    const int lane = tid & 63;
    const int wm   = w >> 2, wn = w & 3;

    int bid = blockIdx.x;
    int x, y, kz = 0;
    if (MODE == 3){
        kz = bid >> 5;
        int t32 = bid & 31;
        x = 32 + (t32 & 1);
        y = t32 >> 1;
    } else {
        int nb2  = (MODE==2) ? ((int)gridDim.x >> 1) : (int)gridDim.x;
        if (MODE == 2){ kz = bid / nb2; bid = bid % nb2; }
        int wg   = (bid & 7)*(nb2 >> 3) + (bid >> 3);
        const int SW = 8;
        int sup = wg / (SW*NYB);
        int rr  = wg % (SW*NYB);
        int x0  = sup*SW;
        int wl  = (NXB - x0 < SW) ? (NXB - x0) : SW;
        x = x0 + rr % wl;
        y = rr / wl;
    }
    const int tm = y*256, tn = x*256;

    const int KT  = (MODE==3) ? 8 : ((MODE==2) ? (K >> 7) : (K >> 6));
    const int kt0 = kz * KT;

    f32x4v acc[8][4];
    #pragma unroll
    for (int i=0;i<8;i++)
        #pragma unroll
        for (int j=0;j<4;j++) acc[i][j] = {0.f,0.f,0.f,0.f};
    bf16x8 af[4][2];
    bf16x8 bfr[2][2];

    // ---- hoisted per-lane addressing ----
    const bf16* srcA[2][2];
    const bf16* srcB[2][2];
    #pragma unroll
    for (int r0h=0;r0h<2;r0h++)
        #pragma unroll
        for (int i=0;i<2;i++){
            int lr = r0h*128 + i*64 + (tid>>3);
            int growA = tm + ((lr>>6)&1)*128 + (lr>>7)*64 + (lr&63);
            int growB = tn + ((lr>>5)&3)*64 + (lr>>7)*32 + (lr&31);
            int gslot = (tid&7) ^ (lr&7);
            srcA[r0h][i] = A + (long)growA*K + gslot*8;
            srcB[r0h][i] = Bmat + (long)growB*K + gslot*8;
        }
    int aoff[4][2], boff[2][2];
    #pragma unroll
    for (int i=0;i<4;i++)
        #pragma unroll
        for (int k2=0;k2<2;k2++){
            int ra0 = wm*64 + i*16 + (lane&15);
            int slot = (k2*4 + (lane>>4)) ^ (ra0&7);
            aoff[i][k2] = ra0*64 + slot*8;
        }
    #pragma unroll
    for (int nf=0;nf<2;nf++)
        #pragma unroll
        for (int k2=0;k2<2;k2++){
            int rb0 = wn*32 + nf*16 + (lane&15);
            int slot = (k2*4 + (lane>>4)) ^ (rb0&7);
            boff[nf][k2] = 16384 + rb0*64 + slot*8;
        }

    auto stageA = [&](int buf, int t, int r0h){
        long koff = (long)(kt0 + t)*64;
        #pragma unroll
        for (int i=0;i<2;i++){
            bf16* dst = &lds[buf][0] + (size_t)(r0h*128 + i*64 + w*8)*64;
            __builtin_amdgcn_global_load_lds(
                (const __attribute__((address_space(1))) void*)(srcA[r0h][i] + koff),
                (__attribute__((address_space(3))) void*)dst, 16, 0, 0);
        }
    };
    auto stageB = [&](int buf, int t, int r0h){
        long koff = (long)(kt0 + t)*64;
        #pragma unroll
        for (int i=0;i<2;i++){
            bf16* dst = &lds[buf][16384] + (size_t)(r0h*128 + i*64 + w*8)*64;
            __builtin_amdgcn_global_load_lds(
                (const __attribute__((address_space(1))) void*)(srcB[r0h][i] + koff),
                (__attribute__((address_space(3))) void*)dst, 16, 0, 0);
        }
    };

    // ---- prologue ----
    stageA(0, 0, 0);
    stageB(0, 0, 0);
    stageA(0, 0, 1);
    stageB(0, 0, 1);
    if (KT > 1){ stageA(1, 1, 0); stageB(1, 1, 0); }
    asm volatile("s_waitcnt vmcnt(8)" ::: "memory");
    __builtin_amdgcn_s_barrier();

    int cur = 0;
    for (int t = 0; t < KT; ++t){
        int nxt = cur ^ 1;
        const bf16* bufc = &lds[cur][0];
        // ---- P0: quadrant (0,0) ----
        READ_A(bufc, 0)
        READ_B(bufc, 0)
        if (t+1 < KT) stageA(nxt, t+1, 1);
        asm volatile("s_waitcnt vmcnt(6)" ::: "memory");
        SBAR();
        MMA_Q(0, 0)
        EBAR();
        // ---- P1: quadrant (0,1) ----
        READ_B(bufc, 1)
        if (t+1 < KT) stageB(nxt, t+1, 1);
        asm volatile("s_waitcnt vmcnt(4)" ::: "memory");
        SBAR();
        MMA_Q(0, 1)
        EBAR();
        // ---- P2: quadrant (1,0) ----
        READ_A(bufc, 1)
        READ_B(bufc, 0)
        if (t+2 < KT) stageA(cur, t+2, 0);
        SBAR();
        MMA_Q(1, 0)
        EBAR();
        // ---- P3: quadrant (1,1) ----
        READ_B(bufc, 1)
        if (t+2 < KT) stageB(cur, t+2, 0);
        SBAR();
        MMA_Q(1, 1)
        EBAR();
        cur = nxt;
    }

    // ---- epilogue ----
    const int er = (lane>>4)*4, ec = lane&15;
    #pragma unroll
    for (int mi=0;mi<8;mi++)
        #pragma unroll
        for (int ni=0;ni<4;ni++){
            long r0 = tm + wm*128 + mi*16 + er;
            int  c0 = tn + wn*64 + ni*16 + ec;
            #pragma unroll
            for (int j=0;j<4;j++){
                float val = acc[mi][ni][j];
                if (MODE == 1){
                    ((bf16*)Cout)[(r0+j)*ldc + c0] = (bf16)val;
                } else if (MODE == 2){
                    ((float*)Cout)[(long)kz*NYB*256*ldc + (r0+j)*ldc + c0] = val;
                } else {
                    ((float*)Cout)[((long)kz*4096 + (r0+j))*512 + (c0 - 8192)] = val;
                }
            }
        }
}

// ---------------- GEMM1 tail reduce: 4 f32 partials -> zx bf16 + dtf f32 ----------------
__global__ __launch_bounds__(256) void tailreduce_kernel(const float* __restrict__ p,
                                                         bf16* __restrict__ zx,
                                                         float* __restrict__ dtf){
    long i = ((long)blockIdx.x*256 + threadIdx.x)*4;   // over 4096*512
    int r = (int)(i >> 9);
    int c = (int)(i & 511);
    const long Q = (long)4096*512;
    float4 a  = *(const float4*)&p[i];
    float4 b  = *(const float4*)&p[i+Q];
    float4 cc = *(const float4*)&p[i+2*Q];
    float4 d  = *(const float4*)&p[i+3*Q];
    float s0 = a.x+b.x+cc.x+d.x, s1 = a.y+b.y+cc.y+d.y;
    float s2 = a.z+b.z+cc.z+d.z, s3 = a.w+b.w+cc.w+d.w;
    bf16x4 o; o[0]=(bf16)s0; o[1]=(bf16)s1; o[2]=(bf16)s2; o[3]=(bf16)s3;
    *(bf16x4*)&zx[(long)r*ZLD + 8192 + c] = o;
    int col = 8192 + c;
    float sv[4] = {s0,s1,s2,s3};
    #pragma unroll
    for (int j=0;j<4;j++){
        int cj = col + j;
        if (cj >= 8448 && cj < 8512) dtf[(long)r*64 + (cj-8448)] = sv[j];
    }
}

// ---------------- split-K reduce for GEMM2: out = p0 + p1 ----------------
__global__ __launch_bounds__(256) void reduce_add_kernel(const float* __restrict__ p,
                                                         float* __restrict__ out, int n){
    int i = (blockIdx.x*256 + threadIdx.x)*4;
    if (i + 3 >= n) return;
    float4 a = *(const float4*)&p[i];
    float4 b = *(const float4*)&p[i + 8388608];
    a.x+=b.x; a.y+=b.y; a.z+=b.z; a.w+=b.w;
    *(float4*)&out[i] = a;
}

// ---------------- depthwise causal conv(4) + bias + silu, 8 tokens/thread ----------------
__global__ __launch_bounds__(256) void conv_silu_kernel(const bf16* __restrict__ zx,
                                                        const float* __restrict__ Wc,
                                                        const float* __restrict__ bc,
                                                        bf16* __restrict__ xc){
    int ch  = blockIdx.x*256 + threadIdx.x;   // 0..4351
    int byy = blockIdx.y;                      // 0..511
    int b = byy >> 8, t0 = (byy & 255)*8;
    float w0=Wc[ch*4+0], w1=Wc[ch*4+1], w2=Wc[ch*4+2], w3=Wc[ch*4+3];
    float bcv = bc[ch];
    const bf16* col = zx + (long)(b*SEQ)*ZLD + 4096 + ch;
    float v[11];
    #pragma unroll
    for (int k=0;k<11;k++){
        int t = t0 - 3 + k;
        v[k] = (t >= 0) ? (float)col[(long)t*ZLD] : 0.f;
    }
    bf16* orow = xc + (long)(b*SEQ + t0)*CONVD + ch;
    #pragma unroll
    for (int j=0;j<8;j++){
        float acc = bcv + v[j]*w0 + v[j+1]*w1 + v[j+2]*w2 + v[j+3]*w3;
        orow[(long)j*CONVD] = (bf16)silu_f(acc);
    }
}

// ---------------- dt softplus + per-chunk cumsum ----------------
__global__ void dtcum_kernel(const float* __restrict__ dtf, const float* __restrict__ A_log,
                             const float* __restrict__ dt_bias,
                             float* __restrict__ dtv, float* __restrict__ dacs,
                             float* __restrict__ cdec){
    int blk = blockIdx.x;        // b*16+c
    int h   = threadIdx.x;       // 0..63
    int b = blk >> 4, c = blk & 15;
    float Ah = -expf(A_log[h]);
    float bias = dt_bias[h];
    float cs = 0.f;
    long base_h = ((long)blk*64 + h)*128;
    const float* src = dtf + (long)(b*SEQ + c*CHUNKL)*64 + h;
    for (int l=0;l<CHUNKL;l++){
        float d = softplus_f(src[(long)l*64] + bias);
        cs += d*Ah;
        dtv[base_h+l]  = d;
        dacs[base_h+l] = cs;
    }
    cdec[blk*64 + h] = expf(cs);
}

// ---------------- CB[l][s] = sum_n C[l][n]*B[s][n] via MFMA, per (b,c) ----------------
__global__ __launch_bounds__(256) void cb_mfma_kernel(const bf16* __restrict__ xc,
                                                      float* __restrict__ cb){
    __shared__ __align__(16) bf16 A1[128*LP];
    __shared__ __align__(16) bf16 B1[128*LP];
    int blk = blockIdx.x;  int b = blk>>4, c = blk&15;
    int tid = threadIdx.x;
    const int w = tid >> 6, lane = tid & 63;
    long tok0 = (long)(b*SEQ + c*CHUNKL);
    int l = tid>>1, n0 = (tid&1)*64;
    const bf16* crow = xc + tok0*CONVD + (long)l*CONVD;
    #pragma unroll
    for (int v=0;v<8;v++){
        *(bf16x8*)&A1[l*LP + n0 + v*8] = *(const bf16x8*)&crow[4224 + n0 + v*8];
        *(bf16x8*)&B1[l*LP + n0 + v*8] = *(const bf16x8*)&crow[4096 + n0 + v*8];
    }
    __syncthreads();
    f32x4v acc[2][8];
    #pragma unroll
    for (int mi=0;mi<2;mi++)
        #pragma unroll
        for (int ni=0;ni<8;ni++) acc[mi][ni] = {0.f,0.f,0.f,0.f};
    #pragma unroll
    for (int kk=0; kk<128; kk+=32){
        bf16x8 afr[2], bfr2[8];
        #pragma unroll
        for (int mi=0;mi<2;mi++)
            afr[mi] = *(const bf16x8*)&A1[(w*32 + mi*16 + (lane&15))*LP + kk + (lane>>4)*8];
        #pragma unroll
        for (int ni=0;ni<8;ni++)
            bfr2[ni] = *(const bf16x8*)&B1[(ni*16 + (lane&15))*LP + kk + (lane>>4)*8];
        #pragma unroll
        for (int mi=0;mi<2;mi++)
            #pragma unroll
            for (int ni=0;ni<8;ni++)
                acc[mi][ni] = __builtin_amdgcn_mfma_f32_16x16x32_bf16(afr[mi], bfr2[ni], acc[mi][ni], 0,0,0);
    }
    float* out = cb + (long)blk*16384;
    #pragma unroll
    for (int mi=0;mi<2;mi++)
        #pragma unroll
        for (int ni=0;ni<8;ni++){
            int r0 = w*32 + mi*16 + (lane>>4)*4;
            int c0 = ni*16 + (lane&15);
            #pragma unroll
            for (int j=0;j<4;j++) out[(long)(r0+j)*128 + c0] = acc[mi][ni][j];
        }
}

// ---------------- states[p][n] via MFMA, per (b,c,h) ----------------
__global__ __launch_bounds__(256) void states_mfma_kernel(const bf16* __restrict__ xc,
                                                          const float* __restrict__ dtv,
                                                          const float* __restrict__ dacs,
                                                          float* __restrict__ states){
    __shared__ __align__(16) bf16 A1[64*LP];
    __shared__ __align__(16) bf16 B1[128*LP];
    __shared__ float wgtl[128];
    int blk = blockIdx.x;
    int h = blk & 63, bc = blk >> 6;
    int b = bc >> 4, c = bc & 15;
    int tid = threadIdx.x;
    const int w = tid >> 6, lane = tid & 63;
    long tok0 = (long)(b*SEQ + c*CHUNKL);
    long base_h = (long)blk*128;
    float cs_last = dacs[base_h + 127];
    if (tid < 128) wgtl[tid] = dtv[base_h+tid] * expf(cs_last - dacs[base_h+tid]);
    __syncthreads();
    #pragma unroll
    for (int t=0;t<4;t++){
        int l = (tid>>3) + t*32;
        int p0 = (tid&7)*8;
        bf16x8 xv = *(const bf16x8*)&xc[(tok0+l)*CONVD + h*64 + p0];
        float wv = wgtl[l];
        #pragma unroll
        for (int e=0;e<8;e++) A1[(p0+e)*LP + l] = (bf16)((float)xv[e]*wv);
    }
    {
        int l = tid>>1, n0 = (tid&1)*64;
        const bf16* brow = xc + (tok0+l)*CONVD + 4096;
        #pragma unroll
        for (int v=0;v<8;v++){
            bf16x8 bv = *(const bf16x8*)&brow[n0 + v*8];
            #pragma unroll
            for (int e=0;e<8;e++) B1[(n0+v*8+e)*LP + l] = bv[e];
        }
    }
    __syncthreads();
    f32x4v acc[8];
    #pragma unroll
    for (int ni=0;ni<8;ni++) acc[ni] = {0.f,0.f,0.f,0.f};
    #pragma unroll
    for (int kk=0; kk<128; kk+=32){
        bf16x8 afr = *(const bf16x8*)&A1[(w*16 + (lane&15))*LP + kk + (lane>>4)*8];
        #pragma unroll
        for (int ni=0;ni<8;ni++){
            bf16x8 bfr2 = *(const bf16x8*)&B1[(ni*16 + (lane&15))*LP + kk + (lane>>4)*8];
            acc[ni] = __builtin_amdgcn_mfma_f32_16x16x32_bf16(afr, bfr2, acc[ni], 0,0,0);
        }
    }
    float* out = states + (long)blk*8192;
    #pragma unroll
    for (int ni=0;ni<8;ni++){
        int p0 = w*16 + (lane>>4)*4;
        int n  = ni*16 + (lane&15);
        #pragma unroll
        for (int j=0;j<4;j++) out[(long)(p0+j)*128 + n] = acc[ni][j];
    }
}

// ---------------- sequential chunk scan ----------------
__global__ __launch_bounds__(256) void scan_kernel(const float* __restrict__ states,
                                                   const float* __restrict__ cdec,
                                                   bf16* __restrict__ hst){
    long gid = (long)blockIdx.x*256 + threadIdx.x;
    int n = gid & 127;
    int p = (gid >> 7) & 63;
    int h = (gid >> 13) & 63;
    int b = (int)(gid >> 19);
    float hrun = 0.f;
    for (int c=0;c<16;c++){
        long idx = ((((long)(b*16 + c)*64 + h)*64 + p)*128) + n;
        hst[idx] = (bf16)hrun;
        hrun = hrun * cdec[(b*16+c)*64 + h] + states[idx];
    }
}

// ---------------- fused Y = P@u^T + (C*sdo)@hst^T ----------------
__global__ __launch_bounds__(256) void yfused_kernel(const bf16* __restrict__ xc,
                                                     const float* __restrict__ cb,
                                                     const bf16* __restrict__ hst,
                                                     const float* __restrict__ dtv,
                                                     const float* __restrict__ dacs,
                                                     bf16* __restrict__ Ybf){
    __shared__ __align__(16) bf16 A1[128*LP];
    __shared__ __align__(16) bf16 B1[64*LP];
    __shared__ float csl[128];
    int blk = blockIdx.x;
    int h = blk & 63, bc = blk >> 6;
    int b = bc >> 4, c = bc & 15;
    int tid = threadIdx.x;
    const int w = tid >> 6, lane = tid & 63;
    long tok0 = (long)(b*SEQ + c*CHUNKL);
    long base_h = (long)blk*128;
    if (tid < 128) csl[tid] = dacs[base_h + tid];
    __syncthreads();
    {
        int l = tid>>1, s0 = (tid&1)*64;
        float el = csl[l];
        const float* cbrow = cb + (long)bc*16384 + (long)l*128 + s0;
        #pragma unroll 8
        for (int j=0;j<64;j++){
            int s = s0 + j;
            float v = (s <= l) ? cbrow[j]*expf(el - csl[s]) : 0.f;
            A1[l*LP + s] = (bf16)v;
        }
    }
    #pragma unroll
    for (int t=0;t<4;t++){
        int s = (tid>>3) + t*32;
        int p0 = (tid&7)*8;
        bf16x8 xv = *(const bf16x8*)&xc[(tok0+s)*CONVD + h*64 + p0];
        float wv = dtv[base_h + s];
        #pragma unroll
        for (int e=0;e<8;e++) B1[(p0+e)*LP + s] = (bf16)((float)xv[e]*wv);
    }
    __syncthreads();
    f32x4v acc[2][4];
    #pragma unroll
    for (int mi=0;mi<2;mi++)
        #pragma unroll
        for (int ni=0;ni<4;ni++) acc[mi][ni] = {0.f,0.f,0.f,0.f};
    #pragma unroll
    for (int kk=0; kk<128; kk+=32){
        bf16x8 afr[2], bfr2[4];
        #pragma unroll
        for (int mi=0;mi<2;mi++)
            afr[mi] = *(const bf16x8*)&A1[(w*32 + mi*16 + (lane&15))*LP + kk + (lane>>4)*8];
        #pragma unroll
        for (int ni=0;ni<4;ni++)
            bfr2[ni] = *(const bf16x8*)&B1[(ni*16 + (lane&15))*LP + kk + (lane>>4)*8];
        #pragma unroll
        for (int mi=0;mi<2;mi++)
            #pragma unroll
            for (int ni=0;ni<4;ni++)
                acc[mi][ni] = __builtin_amdgcn_mfma_f32_16x16x32_bf16(afr[mi], bfr2[ni], acc[mi][ni], 0,0,0);
    }
    __syncthreads();
    {
        int l = tid>>1, n0 = (tid&1)*64;
        float e1 = expf(csl[l]);
        const bf16* crow = xc + (tok0+l)*CONVD + 4224;
        #pragma unroll
        for (int v=0;v<8;v++){
            bf16x8 cv = *(const bf16x8*)&crow[n0 + v*8];
            bf16x8 o;
            #pragma unroll
            for (int e=0;e<8;e++) o[e] = (bf16)((float)cv[e]*e1);
            *(bf16x8*)&A1[l*LP + n0 + v*8] = o;
        }
    }
    {
        int p = tid>>2, n0 = (tid&3)*32;
        const bf16* hrow = hst + (long)blk*8192 + (long)p*128 + n0;
        #pragma unroll
        for (int v=0;v<4;v++)
            *(bf16x8*)&B1[p*LP + n0 + v*8] = *(const bf16x8*)&hrow[v*8];
    }
    __syncthreads();
    #pragma unroll
    for (int kk=0; kk<128; kk+=32){
        bf16x8 afr[2], bfr2[4];
        #pragma unroll
        for (int mi=0;mi<2;mi++)
            afr[mi] = *(const bf16x8*)&A1[(w*32 + mi*16 + (lane&15))*LP + kk + (lane>>4)*8];
        #pragma unroll
        for (int ni=0;ni<4;ni++)
            bfr2[ni] = *(const bf16x8*)&B1[(ni*16 + (lane&15))*LP + kk + (lane>>4)*8];
        #pragma unroll
        for (int mi=0;mi<2;mi++)
            #pragma unroll
            for (int ni=0;ni<4;ni++)
                acc[mi][ni] = __builtin_amdgcn_mfma_f32_16x16x32_bf16(afr[mi], bfr2[ni], acc[mi][ni], 0,0,0);
    }
    #pragma unroll
    for (int mi=0;mi<2;mi++)
        #pragma unroll
        for (int ni=0;ni<4;ni++){
            int l0 = w*32 + mi*16 + (lane>>4)*4;
            int p  = ni*16 + (lane&15);
            #pragma unroll
            for (int j=0;j<4;j++)
                Ybf[(tok0 + l0 + j)*DI + h*64 + p] = (bf16)acc[mi][ni][j];
        }
}

// ---------------- gate (silu(z)) + D*x + RMSNorm + cast bf16 ----------------
__global__ __launch_bounds__(256) void gatenorm_kernel(const bf16* __restrict__ Ybf,
                                                       const bf16* __restrict__ zx,
                                                       const bf16* __restrict__ xc,
                                                       const float* __restrict__ Dp,
                                                       const float* __restrict__ nw,
                                                       bf16* __restrict__ ybn){
    __shared__ float red[4];
    int tok = blockIdx.x, tid = threadIdx.x;
    const bf16* yrow = Ybf + (long)tok*DI;
    const bf16* zrow = zx  + (long)tok*ZLD;
    const bf16* xrow = xc  + (long)tok*CONVD;
    float yg[16];
    float ss = 0.f;
    #pragma unroll
    for (int k=0;k<4;k++){
        int d = (tid + k*256)*4;
        bf16x4 yv = *(const bf16x4*)&yrow[d];
        bf16x4 zv = *(const bf16x4*)&zrow[d];
        bf16x4 xv = *(const bf16x4*)&xrow[d];
        float dh = Dp[d>>6];
        #pragma unroll
        for (int e=0;e<4;e++){
            float yy = (float)yv[e] + dh*(float)xv[e];
            float g = yy*silu_f((float)zv[e]);
            yg[k*4+e] = g;
            ss += g*g;
        }
    }
    #pragma unroll
    for (int off=32; off>0; off>>=1) ss += __shfl_down(ss, off, 64);
    if ((tid & 63) == 0) red[tid>>6] = ss;
    __syncthreads();
    float tot = red[0]+red[1]+red[2]+red[3];
    float scale = rsqrtf(tot/(float)DI + 1e-5f);
    #pragma unroll
    for (int k=0;k<4;k++){
        int d = (tid + k*256)*4;
        float4 wv = *(const float4*)&nw[d];
        bf16x4 o;
        o[0]=(bf16)(yg[k*4+0]*scale*wv.x);
        o[1]=(bf16)(yg[k*4+1]*scale*wv.y);
        o[2]=(bf16)(yg[k*4+2]*scale*wv.z);
        o[3]=(bf16)(yg[k*4+3]*scale*wv.w);
        *(bf16x4*)&ybn[(long)tok*DI + d] = o;
    }
}

// ---------------- launch ----------------
extern "C" void kernel_launch(void* const* d_in, const int* in_sizes, int n_in,
                              void* d_out, int out_size, void* d_ws, size_t ws_size,
                              hipStream_t stream){
    const float* hs      = (const float*)d_in[0];
    const float* W_in    = (const float*)d_in[1];
    const float* W_conv  = (const float*)d_in[2];
    const float* b_conv  = (const float*)d_in[3];
    const float* A_log   = (const float*)d_in[4];
    const float* Dp      = (const float*)d_in[5];
    const float* dt_bias = (const float*)d_in[6];
    const float* nw      = (const float*)d_in[7];
    const float* W_out   = (const float*)d_in[8];
    float* out = (float*)d_out;

    char* ws = (char*)d_ws;
    const size_t OFF_ZX    = 0;                    // bf16 [4096][8704]      71,303,168
    const size_t OFF_DTF   = 71303168;             // f32  [4096][64]         1,048,576
    const size_t OFF_XC    = 72351744;             // bf16 [4096][4352]      35,651,584
    const size_t OFF_DTV   = 108003328;            // f32                     1,048,576
    const size_t OFF_DACS  = 109051904;            //                         1,048,576
    const size_t OFF_CDEC  = 110100480;            // f32 [2048]                  8,192
    const size_t OFF_CB    = 110108672;            // f32 [32][128][128]      2,097,152
    const size_t OFF_SLOTA = 112205824;            // 67,108,864: hsb+winb -> states -> Ybf -> gemm2 partials
    const size_t OFF_SLOTB = 179314688;            // 33,554,432: tailpart -> hst(bf16) -> ybn
    const size_t OFF_WOUTB = 212869120;            // bf16 [2048][4096]      16,777,216

    bf16*  zx    = (bf16*)(ws + OFF_ZX);
    float* dtf   = (float*)(ws + OFF_DTF);
    bf16*  xc    = (bf16*)(ws + OFF_XC);
    float* dtv   = (float*)(ws + OFF_DTV);
    float* dacs  = (float*)(ws + OFF_DACS);
    float* cdec  = (float*)(ws + OFF_CDEC);
    float* cbuf  = (float*)(ws + OFF_CB);
    bf16*  hsb   = (bf16*)(ws + OFF_SLOTA);
    bf16*  winb  = (bf16*)(ws + OFF_SLOTA + 16777216);
    float* states= (float*)(ws + OFF_SLOTA);
    bf16*  Ybf   = (bf16*)(ws + OFF_SLOTA);
    float* part  = (float*)(ws + OFF_SLOTA);       // 2 x [4096][2048] f32 GEMM2 partials
    float* tpart = (float*)(ws + OFF_SLOTB);       // 4 x [4096][512] f32 GEMM1-tail partials
    bf16*  hst   = (bf16*)(ws + OFF_SLOTB);
    bf16*  ybn   = (bf16*)(ws + OFF_SLOTB);
    bf16*  woutb = (bf16*)(ws + OFF_WOUTB);

    cvt_f32_bf16<<<8192, 256, 0, stream>>>(hs, hsb, NTOK*DMODEL);
    cvt_pad_rows<<<17408, 256, 0, stream>>>(W_in, winb, DPROJ, ZLD*DMODEL);
    cvt_f32_bf16<<<8192, 256, 0, stream>>>(W_out, woutb, DMODEL*DI);

    // GEMM1 bulk: cols [0,8192) -> zx bf16, 512 blocks = exactly 2 waves
    gemm256_kernel<1><<<512, 512, 0, stream>>>(hsb, winb, (void*)zx,
                                               32, 16, DMODEL, ZLD);
    // GEMM1 tail: cols [8192,8704), split-K=4 -> f32 partials
    gemm256_kernel<3><<<128, 512, 0, stream>>>(hsb, winb, (void*)tpart,
                                               34, 16, DMODEL, ZLD);
    tailreduce_kernel<<<2048, 256, 0, stream>>>(tpart, zx, dtf);

    conv_silu_kernel<<<dim3(17, 512), 256, 0, stream>>>(zx, W_conv, b_conv, xc);
    dtcum_kernel<<<32, 64, 0, stream>>>(dtf, A_log, dt_bias, dtv, dacs, cdec);
    cb_mfma_kernel<<<32, 256, 0, stream>>>(xc, cbuf);
    states_mfma_kernel<<<2048, 256, 0, stream>>>(xc, dtv, dacs, states);
    scan_kernel<<<4096, 256, 0, stream>>>(states, cdec, hst);
    yfused_kernel<<<2048, 256, 0, stream>>>(xc, cbuf, hst, dtv, dacs, Ybf);
    gatenorm_kernel<<<4096, 256, 0, stream>>>(Ybf, zx, xc, Dp, nw, ybn);

    // GEMM2: [4096,4096] x [2048,4096]^T, split-K=2 -> partials, then reduce
    gemm256_kernel<2><<<256, 512, 0, stream>>>(ybn, woutb, (void*)part,
                                               8, 16, DI, DMODEL);
    reduce_add_kernel<<<8192, 256, 0, stream>>>(part, out, NTOK*DMODEL);
}

// Round 7
// 444.700 us; speedup vs baseline: 2.1838x; 1.1984x over previous
//
#include <hip/hip_runtime.h>
#include <hip/hip_bf16.h>
#include <stdint.h>

typedef __bf16 bf16;
typedef __bf16 bf16x8 __attribute__((ext_vector_type(8)));
typedef __bf16 bf16x4 __attribute__((ext_vector_type(4)));
typedef float f32x4v __attribute__((ext_vector_type(4)));

#define SEQ    2048
#define DMODEL 2048
#define DI     4096
#define NH     64
#define PDIM   64
#define CHUNKL 128
#define NCH    16
#define CONVD  4352
#define DPROJ  8512
#define ZLD    8704   // zxbcdt leading dim, padded to 34*256
#define NTOK   4096
#define LP     136    // padded LDS leading dim for middle kernels

__device__ __forceinline__ float sigmoid_f(float x){ return 1.f/(1.f+expf(-x)); }
__device__ __forceinline__ float silu_f(float x){ return x*sigmoid_f(x); }
__device__ __forceinline__ float softplus_f(float x){ return x > 20.f ? x : log1pf(expf(x)); }

// ---------------- conversions ----------------
__global__ __launch_bounds__(256) void cvt_f32_bf16(const float* __restrict__ src,
                                                    bf16* __restrict__ dst, int n){
    int i = (blockIdx.x*256 + threadIdx.x)*4;
    if (i + 3 >= n) return;
    float4 v = *(const float4*)&src[i];
    bf16x4 o; o[0]=(bf16)v.x; o[1]=(bf16)v.y; o[2]=(bf16)v.z; o[3]=(bf16)v.w;
    *(bf16x4*)&dst[i] = o;
}

__global__ __launch_bounds__(256) void cvt_pad_rows(const float* __restrict__ src,
                                                    bf16* __restrict__ dst,
                                                    int rows_valid, int total){
    int i = (blockIdx.x*256 + threadIdx.x)*4;
    if (i + 3 >= total) return;
    int r = i >> 11;
    bf16x4 o;
    if (r < rows_valid){
        float4 v = *(const float4*)&src[i];
        o[0]=(bf16)v.x; o[1]=(bf16)v.y; o[2]=(bf16)v.z; o[3]=(bf16)v.w;
    } else {
        o[0]=(bf16)0.f; o[1]=(bf16)0.f; o[2]=(bf16)0.f; o[3]=(bf16)0.f;
    }
    *(bf16x4*)&dst[i] = o;
}

// ============ 256x256 8-phase bf16 GEMM: C = A * B^T ============
// Waits: vmcnt(6)@P0 + vmcnt(8)@P3 (FIFO-derived, provably cover all reads).
// Barriers: SBAR each phase + EBAR only after P2 (guards P3's 1-phase WAR stage).
#define READ_A(BUFP, QM)                                                               \
    {                                                                                  \
        _Pragma("unroll")                                                              \
        for (int i=0;i<4;i++)                                                          \
            _Pragma("unroll")                                                          \
            for (int k2=0;k2<2;k2++)                                                   \
                af[i][k2] = *(const bf16x8*)&(BUFP)[aoff[i][k2] + (QM)*8192];          \
    }

#define READ_B(BUFP, QN)                                                               \
    {                                                                                  \
        _Pragma("unroll")                                                              \
        for (int nf=0;nf<2;nf++)                                                       \
            _Pragma("unroll")                                                          \
            for (int k2=0;k2<2;k2++)                                                   \
                bfr[nf][k2] = *(const bf16x8*)&(BUFP)[boff[nf][k2] + (QN)*8192];       \
    }

#define MMA_Q(QM, QN)                                                                  \
    {                                                                                  \
        __builtin_amdgcn_s_setprio(1);                                                 \
        _Pragma("unroll")                                                              \
        for (int i=0;i<4;i++)                                                          \
            _Pragma("unroll")                                                          \
            for (int nf=0;nf<2;nf++)                                                   \
                _Pragma("unroll")                                                      \
                for (int k2=0;k2<2;k2++)                                               \
                    acc[(QM)*4+i][(QN)*2+nf] = __builtin_amdgcn_mfma_f32_16x16x32_bf16( \
                        af[i][k2], bfr[nf][k2], acc[(QM)*4+i][(QN)*2+nf], 0,0,0);      \
        __builtin_amdgcn_s_setprio(0);                                                 \
    }

#define SBAR() do { __builtin_amdgcn_sched_barrier(0);                                 \
                    __builtin_amdgcn_s_barrier();                                      \
                    asm volatile("s_waitcnt lgkmcnt(0)" ::: "memory");                 \
                    __builtin_amdgcn_sched_barrier(0); } while(0)
#define EBAR() do { __builtin_amdgcn_s_barrier();                                      \
                    __builtin_amdgcn_sched_barrier(0); } while(0)

template<int MODE>
__global__ __launch_bounds__(512) void gemm256_kernel(const bf16* __restrict__ A,
                                                      const bf16* __restrict__ Bmat,
                                                      void* __restrict__ Cout,
                                                      int NXB, int NYB, int K, int ldc){
    __shared__ __align__(16) bf16 lds[2][2*16384];   // [buf][A(16384) | B(16384)]
    const int tid  = threadIdx.x;
    const int w    = tid >> 6;
    const int lane = tid & 63;
    const int wm   = w >> 2, wn = w & 3;

    int bid = blockIdx.x;
    int x, y, kz = 0;
    if (MODE == 3){
        kz = bid >> 5;
        int t32 = bid & 31;
        x = 32 + (t32 & 1);
        y = t32 >> 1;
    } else {
        int nb2  = (MODE==2) ? ((int)gridDim.x >> 1) : (int)gridDim.x;
        if (MODE == 2){ kz = bid / nb2; bid = bid % nb2; }
        int wg   = (bid & 7)*(nb2 >> 3) + (bid >> 3);
        const int SW = 8;
        int sup = wg / (SW*NYB);
        int rr  = wg % (SW*NYB);
        int x0  = sup*SW;
        int wl  = (NXB - x0 < SW) ? (NXB - x0) : SW;
        x = x0 + rr % wl;
        y = rr / wl;
    }
    const int tm = y*256, tn = x*256;

    const int KT  = (MODE==3) ? 8 : ((MODE==2) ? (K >> 7) : (K >> 6));
    const int kt0 = kz * KT;

    f32x4v acc[8][4];
    #pragma unroll
    for (int i=0;i<8;i++)
        #pragma unroll
        for (int j=0;j<4;j++) acc[i][j] = {0.f,0.f,0.f,0.f};
    bf16x8 af[4][2];
    bf16x8 bfr[2][2];

    // ---- hoisted per-lane addressing ----
    const bf16* srcA[2][2];
    const bf16* srcB[2][2];
    #pragma unroll
    for (int r0h=0;r0h<2;r0h++)
        #pragma unroll
        for (int i=0;i<2;i++){
            int lr = r0h*128 + i*64 + (tid>>3);
            int growA = tm + ((lr>>6)&1)*128 + (lr>>7)*64 + (lr&63);
            int growB = tn + ((lr>>5)&3)*64 + (lr>>7)*32 + (lr&31);
            int gslot = (tid&7) ^ (lr&7);
            srcA[r0h][i] = A + (long)growA*K + gslot*8;
            srcB[r0h][i] = Bmat + (long)growB*K + gslot*8;
        }
    int aoff[4][2], boff[2][2];
    #pragma unroll
    for (int i=0;i<4;i++)
        #pragma unroll
        for (int k2=0;k2<2;k2++){
            int ra0 = wm*64 + i*16 + (lane&15);
            int slot = (k2*4 + (lane>>4)) ^ (ra0&7);
            aoff[i][k2] = ra0*64 + slot*8;
        }
    #pragma unroll
    for (int nf=0;nf<2;nf++)
        #pragma unroll
        for (int k2=0;k2<2;k2++){
            int rb0 = wn*32 + nf*16 + (lane&15);
            int slot = (k2*4 + (lane>>4)) ^ (rb0&7);
            boff[nf][k2] = 16384 + rb0*64 + slot*8;
        }

    auto stageA = [&](int buf, int t, int r0h){
        long koff = (long)(kt0 + t)*64;
        #pragma unroll
        for (int i=0;i<2;i++){
            bf16* dst = &lds[buf][0] + (size_t)(r0h*128 + i*64 + w*8)*64;
            __builtin_amdgcn_global_load_lds(
                (const __attribute__((address_space(1))) void*)(srcA[r0h][i] + koff),
                (__attribute__((address_space(3))) void*)dst, 16, 0, 0);
        }
    };
    auto stageB = [&](int buf, int t, int r0h){
        long koff = (long)(kt0 + t)*64;
        #pragma unroll
        for (int i=0;i<2;i++){
            bf16* dst = &lds[buf][16384] + (size_t)(r0h*128 + i*64 + w*8)*64;
            __builtin_amdgcn_global_load_lds(
                (const __attribute__((address_space(1))) void*)(srcB[r0h][i] + koff),
                (__attribute__((address_space(3))) void*)dst, 16, 0, 0);
        }
    };

    // ---- prologue: C0 all 4 regions + C1 r0 halves; wait oldest 2 stages ----
    stageA(0, 0, 0);
    stageB(0, 0, 0);
    stageA(0, 0, 1);
    stageB(0, 0, 1);
    if (KT > 1){ stageA(1, 1, 0); stageB(1, 1, 0); }
    asm volatile("s_waitcnt vmcnt(8)" ::: "memory");
    __builtin_amdgcn_s_barrier();

    int cur = 0;
    for (int t = 0; t < KT; ++t){
        int nxt = cur ^ 1;
        const bf16* bufc = &lds[cur][0];
        // ---- P0: quadrant (0,0) ----
        READ_A(bufc, 0)
        READ_B(bufc, 0)
        if (t+1 < KT) stageA(nxt, t+1, 1);
        asm volatile("s_waitcnt vmcnt(6)" ::: "memory");
        SBAR();
        MMA_Q(0, 0)
        // ---- P1: quadrant (0,1) ----
        READ_B(bufc, 1)
        if (t+1 < KT) stageB(nxt, t+1, 1);
        SBAR();
        MMA_Q(0, 1)
        // ---- P2: quadrant (1,0) ----
        READ_A(bufc, 1)
        READ_B(bufc, 0)
        if (t+2 < KT) stageA(cur, t+2, 0);
        SBAR();
        MMA_Q(1, 0)
        EBAR();                                  // guards P3's stage vs P2's B.r0 read
        // ---- P3: quadrant (1,1) ----
        READ_B(bufc, 1)
        if (t+2 < KT) stageB(cur, t+2, 0);
        asm volatile("s_waitcnt vmcnt(8)" ::: "memory");
        SBAR();
        MMA_Q(1, 1)
        cur = nxt;
    }

    // ---- epilogue ----
    const int er = (lane>>4)*4, ec = lane&15;
    #pragma unroll
    for (int mi=0;mi<8;mi++)
        #pragma unroll
        for (int ni=0;ni<4;ni++){
            long r0 = tm + wm*128 + mi*16 + er;
            int  c0 = tn + wn*64 + ni*16 + ec;
            #pragma unroll
            for (int j=0;j<4;j++){
                float val = acc[mi][ni][j];
                if (MODE == 1){
                    ((bf16*)Cout)[(r0+j)*ldc + c0] = (bf16)val;
                } else if (MODE == 2){
                    ((float*)Cout)[(long)kz*NYB*256*ldc + (r0+j)*ldc + c0] = val;
                } else {
                    ((float*)Cout)[((long)kz*4096 + (r0+j))*512 + (c0 - 8192)] = val;
                }
            }
        }
}

// ---------------- GEMM1 tail reduce: 4 f32 partials -> zx bf16 + dtf f32 ----------------
__global__ __launch_bounds__(256) void tailreduce_kernel(const float* __restrict__ p,
                                                         bf16* __restrict__ zx,
                                                         float* __restrict__ dtf){
    long i = ((long)blockIdx.x*256 + threadIdx.x)*4;   // over 4096*512
    int r = (int)(i >> 9);
    int c = (int)(i & 511);
    const long Q = (long)4096*512;
    float4 a  = *(const float4*)&p[i];
    float4 b  = *(const float4*)&p[i+Q];
    float4 cc = *(const float4*)&p[i+2*Q];
    float4 d  = *(const float4*)&p[i+3*Q];
    float s0 = a.x+b.x+cc.x+d.x, s1 = a.y+b.y+cc.y+d.y;
    float s2 = a.z+b.z+cc.z+d.z, s3 = a.w+b.w+cc.w+d.w;
    bf16x4 o; o[0]=(bf16)s0; o[1]=(bf16)s1; o[2]=(bf16)s2; o[3]=(bf16)s3;
    *(bf16x4*)&zx[(long)r*ZLD + 8192 + c] = o;
    int col = 8192 + c;
    float sv[4] = {s0,s1,s2,s3};
    #pragma unroll
    for (int j=0;j<4;j++){
        int cj = col + j;
        if (cj >= 8448 && cj < 8512) dtf[(long)r*64 + (cj-8448)] = sv[j];
    }
}

// ---------------- split-K reduce for GEMM2: out = p0 + p1 ----------------
__global__ __launch_bounds__(256) void reduce_add_kernel(const float* __restrict__ p,
                                                         float* __restrict__ out, int n){
    int i = (blockIdx.x*256 + threadIdx.x)*4;
    if (i + 3 >= n) return;
    float4 a = *(const float4*)&p[i];
    float4 b = *(const float4*)&p[i + 8388608];
    a.x+=b.x; a.y+=b.y; a.z+=b.z; a.w+=b.w;
    *(float4*)&out[i] = a;
}

// ---------------- depthwise causal conv(4) + bias + silu, 8 tokens/thread ----------------
__global__ __launch_bounds__(256) void conv_silu_kernel(const bf16* __restrict__ zx,
                                                        const float* __restrict__ Wc,
                                                        const float* __restrict__ bc,
                                                        bf16* __restrict__ xc){
    int ch  = blockIdx.x*256 + threadIdx.x;   // 0..4351
    int byy = blockIdx.y;                      // 0..511
    int b = byy >> 8, t0 = (byy & 255)*8;
    float w0=Wc[ch*4+0], w1=Wc[ch*4+1], w2=Wc[ch*4+2], w3=Wc[ch*4+3];
    float bcv = bc[ch];
    const bf16* col = zx + (long)(b*SEQ)*ZLD + 4096 + ch;
    float v[11];
    #pragma unroll
    for (int k=0;k<11;k++){
        int t = t0 - 3 + k;
        v[k] = (t >= 0) ? (float)col[(long)t*ZLD] : 0.f;
    }
    bf16* orow = xc + (long)(b*SEQ + t0)*CONVD + ch;
    #pragma unroll
    for (int j=0;j<8;j++){
        float acc = bcv + v[j]*w0 + v[j+1]*w1 + v[j+2]*w2 + v[j+3]*w3;
        orow[(long)j*CONVD] = (bf16)silu_f(acc);
    }
}

// ---------------- dt softplus + per-chunk cumsum: wave-parallel prefix scan ----------------
__global__ __launch_bounds__(256) void dtcum_kernel(const float* __restrict__ dtf,
                                                    const float* __restrict__ A_log,
                                                    const float* __restrict__ dt_bias,
                                                    float* __restrict__ dtv,
                                                    float* __restrict__ dacs,
                                                    float* __restrict__ cdec){
    int wid  = (blockIdx.x*256 + threadIdx.x) >> 6;   // chain id 0..2047 = (b*16+c)*64+h
    int lane = threadIdx.x & 63;
    int h  = wid & 63, bc = wid >> 6;
    int b  = bc >> 4,  c  = bc & 15;
    float Ah   = -expf(A_log[h]);
    float bias = dt_bias[h];
    long tok0 = (long)(b*SEQ + c*CHUNKL);
    int l0 = lane*2;
    float d0 = softplus_f(dtf[(tok0+l0)*64 + h] + bias);
    float d1 = softplus_f(dtf[(tok0+l0+1)*64 + h] + bias);
    float s = (d0 + d1)*Ah;
    #pragma unroll
    for (int off=1; off<64; off<<=1){
        float t = __shfl_up(s, off, 64);
        if (lane >= off) s += t;
    }
    long base_h = (long)wid*128;
    float cs1 = s;
    float cs0 = s - d1*Ah;
    dtv[base_h+l0]   = d0;  dtv[base_h+l0+1]  = d1;
    dacs[base_h+l0]  = cs0; dacs[base_h+l0+1] = cs1;
    if (lane == 63) cdec[wid] = expf(cs1);
}

// ---------------- CB[l][s] = sum_n C[l][n]*B[s][n] via MFMA, per (b,c) ----------------
__global__ __launch_bounds__(256) void cb_mfma_kernel(const bf16* __restrict__ xc,
                                                      float* __restrict__ cb){
    __shared__ __align__(16) bf16 A1[128*LP];
    __shared__ __align__(16) bf16 B1[128*LP];
    int blk = blockIdx.x;  int b = blk>>4, c = blk&15;
    int tid = threadIdx.x;
    const int w = tid >> 6, lane = tid & 63;
    long tok0 = (long)(b*SEQ + c*CHUNKL);
    int l = tid>>1, n0 = (tid&1)*64;
    const bf16* crow = xc + tok0*CONVD + (long)l*CONVD;
    #pragma unroll
    for (int v=0;v<8;v++){
        *(bf16x8*)&A1[l*LP + n0 + v*8] = *(const bf16x8*)&crow[4224 + n0 + v*8];
        *(bf16x8*)&B1[l*LP + n0 + v*8] = *(const bf16x8*)&crow[4096 + n0 + v*8];
    }
    __syncthreads();
    f32x4v acc[2][8];
    #pragma unroll
    for (int mi=0;mi<2;mi++)
        #pragma unroll
        for (int ni=0;ni<8;ni++) acc[mi][ni] = {0.f,0.f,0.f,0.f};
    #pragma unroll
    for (int kk=0; kk<128; kk+=32){
        bf16x8 afr[2], bfr2[8];
        #pragma unroll
        for (int mi=0;mi<2;mi++)
            afr[mi] = *(const bf16x8*)&A1[(w*32 + mi*16 + (lane&15))*LP + kk + (lane>>4)*8];
        #pragma unroll
        for (int ni=0;ni<8;ni++)
            bfr2[ni] = *(const bf16x8*)&B1[(ni*16 + (lane&15))*LP + kk + (lane>>4)*8];
        #pragma unroll
        for (int mi=0;mi<2;mi++)
            #pragma unroll
            for (int ni=0;ni<8;ni++)
                acc[mi][ni] = __builtin_amdgcn_mfma_f32_16x16x32_bf16(afr[mi], bfr2[ni], acc[mi][ni], 0,0,0);
    }
    float* out = cb + (long)blk*16384;
    #pragma unroll
    for (int mi=0;mi<2;mi++)
        #pragma unroll
        for (int ni=0;ni<8;ni++){
            int r0 = w*32 + mi*16 + (lane>>4)*4;
            int c0 = ni*16 + (lane&15);
            #pragma unroll
            for (int j=0;j<4;j++) out[(long)(r0+j)*128 + c0] = acc[mi][ni][j];
        }
}

// ---------------- states[p][n] via MFMA, per (b,c,h), bf16 out ----------------
__global__ __launch_bounds__(256) void states_mfma_kernel(const bf16* __restrict__ xc,
                                                          const float* __restrict__ dtv,
                                                          const float* __restrict__ dacs,
                                                          bf16* __restrict__ states){
    __shared__ __align__(16) bf16 A1[64*LP];
    __shared__ __align__(16) bf16 B1[128*LP];
    __shared__ float wgtl[128];
    int blk = blockIdx.x;
    int h = blk & 63, bc = blk >> 6;
    int b = bc >> 4, c = bc & 15;
    int tid = threadIdx.x;
    const int w = tid >> 6, lane = tid & 63;
    long tok0 = (long)(b*SEQ + c*CHUNKL);
    long base_h = (long)blk*128;
    float cs_last = dacs[base_h + 127];
    if (tid < 128) wgtl[tid] = dtv[base_h+tid] * expf(cs_last - dacs[base_h+tid]);
    __syncthreads();
    #pragma unroll
    for (int t=0;t<4;t++){
        int l = (tid>>3) + t*32;
        int p0 = (tid&7)*8;
        bf16x8 xv = *(const bf16x8*)&xc[(tok0+l)*CONVD + h*64 + p0];
        float wv = wgtl[l];
        #pragma unroll
        for (int e=0;e<8;e++) A1[(p0+e)*LP + l] = (bf16)((float)xv[e]*wv);
    }
    {
        int l = tid>>1, n0 = (tid&1)*64;
        const bf16* brow = xc + (tok0+l)*CONVD + 4096;
        #pragma unroll
        for (int v=0;v<8;v++){
            bf16x8 bv = *(const bf16x8*)&brow[n0 + v*8];
            #pragma unroll
            for (int e=0;e<8;e++) B1[(n0+v*8+e)*LP + l] = bv[e];
        }
    }
    __syncthreads();
    f32x4v acc[8];
    #pragma unroll
    for (int ni=0;ni<8;ni++) acc[ni] = {0.f,0.f,0.f,0.f};
    #pragma unroll
    for (int kk=0; kk<128; kk+=32){
        bf16x8 afr = *(const bf16x8*)&A1[(w*16 + (lane&15))*LP + kk + (lane>>4)*8];
        #pragma unroll
        for (int ni=0;ni<8;ni++){
            bf16x8 bfr2 = *(const bf16x8*)&B1[(ni*16 + (lane&15))*LP + kk + (lane>>4)*8];
            acc[ni] = __builtin_amdgcn_mfma_f32_16x16x32_bf16(afr, bfr2, acc[ni], 0,0,0);
        }
    }
    bf16* out = states + (long)blk*8192;
    #pragma unroll
    for (int ni=0;ni<8;ni++){
        int p0 = w*16 + (lane>>4)*4;
        int n  = ni*16 + (lane&15);
        #pragma unroll
        for (int j=0;j<4;j++) out[(long)(p0+j)*128 + n] = (bf16)acc[ni][j];
    }
}

// ---------------- sequential chunk scan (bf16 in/out, f32 accum) ----------------
__global__ __launch_bounds__(256) void scan_kernel(const bf16* __restrict__ states,
                                                   const float* __restrict__ cdec,
                                                   bf16* __restrict__ hst){
    long gid = (long)blockIdx.x*256 + threadIdx.x;
    int n = gid & 127;
    int p = (gid >> 7) & 63;
    int h = (gid >> 13) & 63;
    int b = (int)(gid >> 19);
    float hrun = 0.f;
    for (int c=0;c<16;c++){
        long idx = ((((long)(b*16 + c)*64 + h)*64 + p)*128) + n;
        hst[idx] = (bf16)hrun;
        hrun = hrun * cdec[(b*16+c)*64 + h] + (float)states[idx];
    }
}

// ---------------- fused Y = P@u^T + (C*sdo)@hst^T ----------------
__global__ __launch_bounds__(256) void yfused_kernel(const bf16* __restrict__ xc,
                                                     const float* __restrict__ cb,
                                                     const bf16* __restrict__ hst,
                                                     const float* __restrict__ dtv,
                                                     const float* __restrict__ dacs,
                                                     bf16* __restrict__ Ybf){
    __shared__ __align__(16) bf16 A1[128*LP];
    __shared__ __align__(16) bf16 B1[64*LP];
    __shared__ float csl[128];
    int blk = blockIdx.x;
    int h = blk & 63, bc = blk >> 6;
    int b = bc >> 4, c = bc & 15;
    int tid = threadIdx.x;
    const int w = tid >> 6, lane = tid & 63;
    long tok0 = (long)(b*SEQ + c*CHUNKL);
    long base_h = (long)blk*128;
    if (tid < 128) csl[tid] = dacs[base_h + tid];
    __syncthreads();
    {
        int l = tid>>1, s0 = (tid&1)*64;
        float el = csl[l];
        const float* cbrow = cb + (long)bc*16384 + (long)l*128 + s0;
        #pragma unroll 8
        for (int j=0;j<64;j++){
            int s = s0 + j;
            float v = (s <= l) ? cbrow[j]*expf(el - csl[s]) : 0.f;
            A1[l*LP + s] = (bf16)v;
        }
    }
    #pragma unroll
    for (int t=0;t<4;t++){
        int s = (tid>>3) + t*32;
        int p0 = (tid&7)*8;
        bf16x8 xv = *(const bf16x8*)&xc[(tok0+s)*CONVD + h*64 + p0];
        float wv = dtv[base_h + s];
        #pragma unroll
        for (int e=0;e<8;e++) B1[(p0+e)*LP + s] = (bf16)((float)xv[e]*wv);
    }
    __syncthreads();
    f32x4v acc[2][4];
    #pragma unroll
    for (int mi=0;mi<2;mi++)
        #pragma unroll
        for (int ni=0;ni<4;ni++) acc[mi][ni] = {0.f,0.f,0.f,0.f};
    #pragma unroll
    for (int kk=0; kk<128; kk+=32){
        bf16x8 afr[2], bfr2[4];
        #pragma unroll
        for (int mi=0;mi<2;mi++)
            afr[mi] = *(const bf16x8*)&A1[(w*32 + mi*16 + (lane&15))*LP + kk + (lane>>4)*8];
        #pragma unroll
        for (int ni=0;ni<4;ni++)
            bfr2[ni] = *(const bf16x8*)&B1[(ni*16 + (lane&15))*LP + kk + (lane>>4)*8];
        #pragma unroll
        for (int mi=0;mi<2;mi++)
            #pragma unroll
            for (int ni=0;ni<4;ni++)
                acc[mi][ni] = __builtin_amdgcn_mfma_f32_16x16x32_bf16(afr[mi], bfr2[ni], acc[mi][ni], 0,0,0);
    }
    __syncthreads();
    {
        int l = tid>>1, n0 = (tid&1)*64;
        float e1 = expf(csl[l]);
        const bf16* crow = xc + (tok0+l)*CONVD + 4224;
        #pragma unroll
        for (int v=0;v<8;v++){
            bf16x8 cv = *(const bf16x8*)&crow[n0 + v*8];
            bf16x8 o;
            #pragma unroll
            for (int e=0;e<8;e++) o[e] = (bf16)((float)cv[e]*e1);
            *(bf16x8*)&A1[l*LP + n0 + v*8] = o;
        }
    }
    {
        int p = tid>>2, n0 = (tid&3)*32;
        const bf16* hrow = hst + (long)blk*8192 + (long)p*128 + n0;
        #pragma unroll
        for (int v=0;v<4;v++)
            *(bf16x8*)&B1[p*LP + n0 + v*8] = *(const bf16x8*)&hrow[v*8];
    }
    __syncthreads();
    #pragma unroll
    for (int kk=0; kk<128; kk+=32){
        bf16x8 afr[2], bfr2[4];
        #pragma unroll
        for (int mi=0;mi<2;mi++)
            afr[mi] = *(const bf16x8*)&A1[(w*32 + mi*16 + (lane&15))*LP + kk + (lane>>4)*8];
        #pragma unroll
        for (int ni=0;ni<4;ni++)
            bfr2[ni] = *(const bf16x8*)&B1[(ni*16 + (lane&15))*LP + kk + (lane>>4)*8];
        #pragma unroll
        for (int mi=0;mi<2;mi++)
            #pragma unroll
            for (int ni=0;ni<4;ni++)
                acc[mi][ni] = __builtin_amdgcn_mfma_f32_16x16x32_bf16(afr[mi], bfr2[ni], acc[mi][ni], 0,0,0);
    }
    #pragma unroll
    for (int mi=0;mi<2;mi++)
        #pragma unroll
        for (int ni=0;ni<4;ni++){
            int l0 = w*32 + mi*16 + (lane>>4)*4;
            int p  = ni*16 + (lane&15);
            #pragma unroll
            for (int j=0;j<4;j++)
                Ybf[(tok0 + l0 + j)*DI + h*64 + p] = (bf16)acc[mi][ni][j];
        }
}

// ---------------- gate (silu(z)) + D*x + RMSNorm + cast bf16 ----------------
__global__ __launch_bounds__(256) void gatenorm_kernel(const bf16* __restrict__ Ybf,
                                                       const bf16* __restrict__ zx,
                                                       const bf16* __restrict__ xc,
                                                       const float* __restrict__ Dp,
                                                       const float* __restrict__ nw,
                                                       bf16* __restrict__ ybn){
    __shared__ float red[4];
    int tok = blockIdx.x, tid = threadIdx.x;
    const bf16* yrow = Ybf + (long)tok*DI;
    const bf16* zrow = zx  + (long)tok*ZLD;
    const bf16* xrow = xc  + (long)tok*CONVD;
    float yg[16];
    float ss = 0.f;
    #pragma unroll
    for (int k=0;k<4;k++){
        int d = (tid + k*256)*4;
        bf16x4 yv = *(const bf16x4*)&yrow[d];
        bf16x4 zv = *(const bf16x4*)&zrow[d];
        bf16x4 xv = *(const bf16x4*)&xrow[d];
        float dh = Dp[d>>6];
        #pragma unroll
        for (int e=0;e<4;e++){
            float yy = (float)yv[e] + dh*(float)xv[e];
            float g = yy*silu_f((float)zv[e]);
            yg[k*4+e] = g;
            ss += g*g;
        }
    }
    #pragma unroll
    for (int off=32; off>0; off>>=1) ss += __shfl_down(ss, off, 64);
    if ((tid & 63) == 0) red[tid>>6] = ss;
    __syncthreads();
    float tot = red[0]+red[1]+red[2]+red[3];
    float scale = rsqrtf(tot/(float)DI + 1e-5f);
    #pragma unroll
    for (int k=0;k<4;k++){
        int d = (tid + k*256)*4;
        float4 wv = *(const float4*)&nw[d];
        bf16x4 o;
        o[0]=(bf16)(yg[k*4+0]*scale*wv.x);
        o[1]=(bf16)(yg[k*4+1]*scale*wv.y);
        o[2]=(bf16)(yg[k*4+2]*scale*wv.z);
        o[3]=(bf16)(yg[k*4+3]*scale*wv.w);
        *(bf16x4*)&ybn[(long)tok*DI + d] = o;
    }
}

// ---------------- launch ----------------
extern "C" void kernel_launch(void* const* d_in, const int* in_sizes, int n_in,
                              void* d_out, int out_size, void* d_ws, size_t ws_size,
                              hipStream_t stream){
    const float* hs      = (const float*)d_in[0];
    const float* W_in    = (const float*)d_in[1];
    const float* W_conv  = (const float*)d_in[2];
    const float* b_conv  = (const float*)d_in[3];
    const float* A_log   = (const float*)d_in[4];
    const float* Dp      = (const float*)d_in[5];
    const float* dt_bias = (const float*)d_in[6];
    const float* nw      = (const float*)d_in[7];
    const float* W_out   = (const float*)d_in[8];
    float* out = (float*)d_out;

    char* ws = (char*)d_ws;
    const size_t OFF_ZX    = 0;                    // bf16 [4096][8704]      71,303,168
    const size_t OFF_DTF   = 71303168;             // f32  [4096][64]         1,048,576
    const size_t OFF_XC    = 72351744;             // bf16 [4096][4352]      35,651,584
    const size_t OFF_DTV   = 108003328;            // f32                     1,048,576
    const size_t OFF_DACS  = 109051904;            //                         1,048,576
    const size_t OFF_CDEC  = 110100480;            // f32 [2048]                  8,192
    const size_t OFF_CB    = 110108672;            // f32 [32][128][128]      2,097,152
    const size_t OFF_SLOTA = 112205824;            // 67,108,864: hsb+winb -> states(bf16) -> Ybf -> gemm2 partials
    const size_t OFF_SLOTB = 179314688;            // 33,554,432: tailpart -> hst(bf16) -> ybn
    const size_t OFF_WOUTB = 212869120;            // bf16 [2048][4096]      16,777,216

    bf16*  zx    = (bf16*)(ws + OFF_ZX);
    float* dtf   = (float*)(ws + OFF_DTF);
    bf16*  xc    = (bf16*)(ws + OFF_XC);
    float* dtv   = (float*)(ws + OFF_DTV);
    float* dacs  = (float*)(ws + OFF_DACS);
    float* cdec  = (float*)(ws + OFF_CDEC);
    float* cbuf  = (float*)(ws + OFF_CB);
    bf16*  hsb   = (bf16*)(ws + OFF_SLOTA);
    bf16*  winb  = (bf16*)(ws + OFF_SLOTA + 16777216);
    bf16*  states= (bf16*)(ws + OFF_SLOTA);
    bf16*  Ybf   = (bf16*)(ws + OFF_SLOTA);
    float* part  = (float*)(ws + OFF_SLOTA);       // 2 x [4096][2048] f32 GEMM2 partials
    float* tpart = (float*)(ws + OFF_SLOTB);       // 4 x [4096][512] f32 GEMM1-tail partials
    bf16*  hst   = (bf16*)(ws + OFF_SLOTB);
    bf16*  ybn   = (bf16*)(ws + OFF_SLOTB);
    bf16*  woutb = (bf16*)(ws + OFF_WOUTB);

    cvt_f32_bf16<<<8192, 256, 0, stream>>>(hs, hsb, NTOK*DMODEL);
    cvt_pad_rows<<<17408, 256, 0, stream>>>(W_in, winb, DPROJ, ZLD*DMODEL);
    cvt_f32_bf16<<<8192, 256, 0, stream>>>(W_out, woutb, DMODEL*DI);

    // GEMM1 bulk: cols [0,8192) -> zx bf16, 512 blocks = exactly 2 waves
    gemm256_kernel<1><<<512, 512, 0, stream>>>(hsb, winb, (void*)zx,
                                               32, 16, DMODEL, ZLD);
    // GEMM1 tail: cols [8192,8704), split-K=4 -> f32 partials
    gemm256_kernel<3><<<128, 512, 0, stream>>>(hsb, winb, (void*)tpart,
                                               34, 16, DMODEL, ZLD);
    tailreduce_kernel<<<2048, 256, 0, stream>>>(tpart, zx, dtf);

    conv_silu_kernel<<<dim3(17, 512), 256, 0, stream>>>(zx, W_conv, b_conv, xc);
    dtcum_kernel<<<512, 256, 0, stream>>>(dtf, A_log, dt_bias, dtv, dacs, cdec);
    cb_mfma_kernel<<<32, 256, 0, stream>>>(xc, cbuf);
    states_mfma_kernel<<<2048, 256, 0, stream>>>(xc, dtv, dacs, states);
    scan_kernel<<<4096, 256, 0, stream>>>(states, cdec, hst);
    yfused_kernel<<<2048, 256, 0, stream>>>(xc, cbuf, hst, dtv, dacs, Ybf);
    gatenorm_kernel<<<4096, 256, 0, stream>>>(Ybf, zx, xc, Dp, nw, ybn);

    // GEMM2: [4096,4096] x [2048,4096]^T, split-K=2 -> partials, then reduce
    gemm256_kernel<2><<<256, 512, 0, stream>>>(ybn, woutb, (void*)part,
                                               8, 16, DI, DMODEL);
    reduce_add_kernel<<<8192, 256, 0, stream>>>(part, out, NTOK*DMODEL);
}

// Round 8
// 438.079 us; speedup vs baseline: 2.2168x; 1.0151x over previous
//
#include <hip/hip_runtime.h>
#include <hip/hip_bf16.h>
#include <stdint.h>

typedef __bf16 bf16;
typedef __bf16 bf16x8 __attribute__((ext_vector_type(8)));
typedef __bf16 bf16x4 __attribute__((ext_vector_type(4)));
typedef float f32x4v __attribute__((ext_vector_type(4)));

#define SEQ    2048
#define DMODEL 2048
#define DI     4096
#define NH     64
#define PDIM   64
#define CHUNKL 128
#define NCH    16
#define CONVD  4352
#define DPROJ  8512
#define ZLD    8704   // zxbcdt leading dim, padded to 34*256
#define NTOK   4096
#define LP     136    // padded LDS leading dim for middle kernels

__device__ __forceinline__ float sigmoid_f(float x){ return 1.f/(1.f+expf(-x)); }
__device__ __forceinline__ float silu_f(float x){ return x*sigmoid_f(x); }
__device__ __forceinline__ float softplus_f(float x){ return x > 20.f ? x : log1pf(expf(x)); }

// ---------------- fused conversions: hs->bf16 | W_in->bf16 padded | W_out->bf16 ----------------
__global__ __launch_bounds__(256) void cvt_all_kernel(const float* __restrict__ hs,
                                                      const float* __restrict__ W_in,
                                                      const float* __restrict__ W_out,
                                                      bf16* __restrict__ hsb,
                                                      bf16* __restrict__ winb,
                                                      bf16* __restrict__ woutb){
    int blk = blockIdx.x;
    if (blk < 8192){
        int i = (blk*256 + threadIdx.x)*4;
        float4 v = *(const float4*)&hs[i];
        bf16x4 o; o[0]=(bf16)v.x; o[1]=(bf16)v.y; o[2]=(bf16)v.z; o[3]=(bf16)v.w;
        *(bf16x4*)&hsb[i] = o;
    } else if (blk < 25600){
        int i = ((blk-8192)*256 + threadIdx.x)*4;   // over 8704*2048
        int r = i >> 11;
        bf16x4 o;
        if (r < DPROJ){
            float4 v = *(const float4*)&W_in[i];
            o[0]=(bf16)v.x; o[1]=(bf16)v.y; o[2]=(bf16)v.z; o[3]=(bf16)v.w;
        } else {
            o[0]=(bf16)0.f; o[1]=(bf16)0.f; o[2]=(bf16)0.f; o[3]=(bf16)0.f;
        }
        *(bf16x4*)&winb[i] = o;
    } else {
        int i = ((blk-25600)*256 + threadIdx.x)*4;
        float4 v = *(const float4*)&W_out[i];
        bf16x4 o; o[0]=(bf16)v.x; o[1]=(bf16)v.y; o[2]=(bf16)v.z; o[3]=(bf16)v.w;
        *(bf16x4*)&woutb[i] = o;
    }
}

// ============ shared GEMM fragment macros ============
#define READ_A(BUFP, QM)                                                               \
    {                                                                                  \
        _Pragma("unroll")                                                              \
        for (int i=0;i<4;i++)                                                          \
            _Pragma("unroll")                                                          \
            for (int k2=0;k2<2;k2++)                                                   \
                af[i][k2] = *(const bf16x8*)&(BUFP)[aoff[i][k2] + (QM)*8192];          \
    }

#define READ_B(BUFP, QN)                                                               \
    {                                                                                  \
        _Pragma("unroll")                                                              \
        for (int nf=0;nf<2;nf++)                                                       \
            _Pragma("unroll")                                                          \
            for (int k2=0;k2<2;k2++)                                                   \
                bfr[nf][k2] = *(const bf16x8*)&(BUFP)[boff[nf][k2] + (QN)*8192];       \
    }

#define MMA_Q(QM, QN)                                                                  \
    {                                                                                  \
        __builtin_amdgcn_s_setprio(1);                                                 \
        _Pragma("unroll")                                                              \
        for (int i=0;i<4;i++)                                                          \
            _Pragma("unroll")                                                          \
            for (int nf=0;nf<2;nf++)                                                   \
                _Pragma("unroll")                                                      \
                for (int k2=0;k2<2;k2++)                                               \
                    acc[(QM)*4+i][(QN)*2+nf] = __builtin_amdgcn_mfma_f32_16x16x32_bf16( \
                        af[i][k2], bfr[nf][k2], acc[(QM)*4+i][(QN)*2+nf], 0,0,0);      \
        __builtin_amdgcn_s_setprio(0);                                                 \
    }

#define SBAR() do { __builtin_amdgcn_sched_barrier(0);                                 \
                    __builtin_amdgcn_s_barrier();                                      \
                    asm volatile("s_waitcnt lgkmcnt(0)" ::: "memory");                 \
                    __builtin_amdgcn_sched_barrier(0); } while(0)
#define EBAR() do { __builtin_amdgcn_s_barrier();                                      \
                    __builtin_amdgcn_sched_barrier(0); } while(0)

// ============ 256x256 8-phase bf16 GEMM: C = A * B^T ============
// MODE 1: bf16 C (cols < 8192 only, bulk of GEMM1)
// MODE 3: GEMM1 tail (x in {32,33}), split-K=4, f32 partials [kz][4096][512]
template<int MODE>
__global__ __launch_bounds__(512) void gemm256_kernel(const bf16* __restrict__ A,
                                                      const bf16* __restrict__ Bmat,
                                                      void* __restrict__ Cout,
                                                      int NXB, int NYB, int K, int ldc){
    __shared__ __align__(16) bf16 lds[2][2*16384];   // [buf][A(16384) | B(16384)]
    const int tid  = threadIdx.x;
    const int w    = tid >> 6;
    const int lane = tid & 63;
    const int wm   = w >> 2, wn = w & 3;

    int bid = blockIdx.x;
    int x, y, kz = 0;
    if (MODE == 3){
        kz = bid >> 5;
        int t32 = bid & 31;
        x = 32 + (t32 & 1);
        y = t32 >> 1;
    } else {
        int nb2  = (int)gridDim.x;
        int wg   = (bid & 7)*(nb2 >> 3) + (bid >> 3);
        const int SW = 8;
        int sup = wg / (SW*NYB);
        int rr  = wg % (SW*NYB);
        int x0  = sup*SW;
        int wl  = (NXB - x0 < SW) ? (NXB - x0) : SW;
        x = x0 + rr % wl;
        y = rr / wl;
    }
    const int tm = y*256, tn = x*256;

    const int KT  = (MODE==3) ? 8 : (K >> 6);
    const int kt0 = kz * KT;

    f32x4v acc[8][4];
    #pragma unroll
    for (int i=0;i<8;i++)
        #pragma unroll
        for (int j=0;j<4;j++) acc[i][j] = {0.f,0.f,0.f,0.f};
    bf16x8 af[4][2];
    bf16x8 bfr[2][2];

    // ---- hoisted per-lane addressing ----
    const bf16* srcA[2][2];
    const bf16* srcB[2][2];
    #pragma unroll
    for (int r0h=0;r0h<2;r0h++)
        #pragma unroll
        for (int i=0;i<2;i++){
            int lr = r0h*128 + i*64 + (tid>>3);
            int growA = tm + ((lr>>6)&1)*128 + (lr>>7)*64 + (lr&63);
            int growB = tn + ((lr>>5)&3)*64 + (lr>>7)*32 + (lr&31);
            int gslot = (tid&7) ^ (lr&7);
            srcA[r0h][i] = A + (long)growA*K + gslot*8;
            srcB[r0h][i] = Bmat + (long)growB*K + gslot*8;
        }
    int aoff[4][2], boff[2][2];
    #pragma unroll
    for (int i=0;i<4;i++)
        #pragma unroll
        for (int k2=0;k2<2;k2++){
            int ra0 = wm*64 + i*16 + (lane&15);
            int slot = (k2*4 + (lane>>4)) ^ (ra0&7);
            aoff[i][k2] = ra0*64 + slot*8;
        }
    #pragma unroll
    for (int nf=0;nf<2;nf++)
        #pragma unroll
        for (int k2=0;k2<2;k2++){
            int rb0 = wn*32 + nf*16 + (lane&15);
            int slot = (k2*4 + (lane>>4)) ^ (rb0&7);
            boff[nf][k2] = 16384 + rb0*64 + slot*8;
        }

    auto stageA = [&](int buf, int t, int r0h){
        long koff = (long)(kt0 + t)*64;
        #pragma unroll
        for (int i=0;i<2;i++){
            bf16* dst = &lds[buf][0] + (size_t)(r0h*128 + i*64 + w*8)*64;
            __builtin_amdgcn_global_load_lds(
                (const __attribute__((address_space(1))) void*)(srcA[r0h][i] + koff),
                (__attribute__((address_space(3))) void*)dst, 16, 0, 0);
        }
    };
    auto stageB = [&](int buf, int t, int r0h){
        long koff = (long)(kt0 + t)*64;
        #pragma unroll
        for (int i=0;i<2;i++){
            bf16* dst = &lds[buf][16384] + (size_t)(r0h*128 + i*64 + w*8)*64;
            __builtin_amdgcn_global_load_lds(
                (const __attribute__((address_space(1))) void*)(srcB[r0h][i] + koff),
                (__attribute__((address_space(3))) void*)dst, 16, 0, 0);
        }
    };

    // ---- prologue ----
    stageA(0, 0, 0);
    stageB(0, 0, 0);
    stageA(0, 0, 1);
    stageB(0, 0, 1);
    if (KT > 1){ stageA(1, 1, 0); stageB(1, 1, 0); }
    asm volatile("s_waitcnt vmcnt(8)" ::: "memory");
    __builtin_amdgcn_s_barrier();

    int cur = 0;
    for (int t = 0; t < KT; ++t){
        int nxt = cur ^ 1;
        const bf16* bufc = &lds[cur][0];
        // ---- P0: quadrant (0,0) ----
        READ_A(bufc, 0)
        READ_B(bufc, 0)
        if (t+1 < KT){
            stageA(nxt, t+1, 1);
            asm volatile("s_waitcnt vmcnt(6)" ::: "memory");
        } else {
            asm volatile("s_waitcnt vmcnt(0)" ::: "memory");
        }
        SBAR();
        MMA_Q(0, 0)
        // ---- P1: quadrant (0,1) ----
        READ_B(bufc, 1)
        if (t+1 < KT) stageB(nxt, t+1, 1);
        SBAR();
        MMA_Q(0, 1)
        // ---- P2: quadrant (1,0) ----
        READ_A(bufc, 1)
        READ_B(bufc, 0)
        if (t+2 < KT) stageA(cur, t+2, 0);
        SBAR();
        MMA_Q(1, 0)
        EBAR();                                  // guards P3's stage vs P2's B.r0 read
        // ---- P3: quadrant (1,1) ----
        READ_B(bufc, 1)
        if (t+2 < KT){
            stageB(cur, t+2, 0);
            asm volatile("s_waitcnt vmcnt(8)" ::: "memory");
        } else {
            asm volatile("s_waitcnt vmcnt(4)" ::: "memory");
        }
        SBAR();
        MMA_Q(1, 1)
        cur = nxt;
    }

    // ---- epilogue ----
    const int er = (lane>>4)*4, ec = lane&15;
    #pragma unroll
    for (int mi=0;mi<8;mi++)
        #pragma unroll
        for (int ni=0;ni<4;ni++){
            long r0 = tm + wm*128 + mi*16 + er;
            int  c0 = tn + wn*64 + ni*16 + ec;
            #pragma unroll
            for (int j=0;j<4;j++){
                float val = acc[mi][ni][j];
                if (MODE == 1){
                    ((bf16*)Cout)[(r0+j)*ldc + c0] = (bf16)val;
                } else {
                    ((float*)Cout)[((long)kz*4096 + (r0+j))*512 + (c0 - 8192)] = val;
                }
            }
        }
}

// ============ 256x128 triple-buffered bf16 GEMM (GEMM2): C(f32) = A * B^T ============
// 2 phases/K-tile; stages issued 2 tiles ahead; single vmcnt(6)@P1 (producer-guarantee
// for next tile's P0 reads, validated by the FIFO invariant of the 256x256 kernel).
__global__ __launch_bounds__(512) void gemm256x128_kernel(const bf16* __restrict__ A,
                                                          const bf16* __restrict__ Bmat,
                                                          float* __restrict__ C,
                                                          int NXB, int NYB, int K, int ldc){
    __shared__ __align__(16) bf16 lds[3][24576];   // [buf][A(16384) | B(8192)]
    const int tid  = threadIdx.x;
    const int w    = tid >> 6;
    const int lane = tid & 63;
    const int wm   = w >> 2, wn = w & 3;

    int bid = blockIdx.x, nb = gridDim.x;
    int wg = (bid & 7)*(nb >> 3) + (bid >> 3);
    const int SW = 8;
    int sup = wg / (SW*NYB);
    int rr  = wg % (SW*NYB);
    int x0  = sup*SW;
    int wl  = (NXB - x0 < SW) ? (NXB - x0) : SW;
    int x   = x0 + rr % wl;
    int y   = rr / wl;
    const int tm = y*256, tn = x*128;
    const int KT = K >> 6;

    f32x4v acc[8][2];
    #pragma unroll
    for (int i=0;i<8;i++)
        #pragma unroll
        for (int j=0;j<2;j++) acc[i][j] = {0.f,0.f,0.f,0.f};
    bf16x8 af[4][2];
    bf16x8 bfr[2][2];

    // ---- hoisted addressing ----
    const bf16* srcA[2][2];
    const bf16* srcB[2];
    #pragma unroll
    for (int r0h=0;r0h<2;r0h++)
        #pragma unroll
        for (int i=0;i<2;i++){
            int lr = r0h*128 + i*64 + (tid>>3);
            int growA = tm + ((lr>>6)&1)*128 + (lr>>7)*64 + (lr&63);
            int gslot = (tid&7) ^ (lr&7);
            srcA[r0h][i] = A + (long)growA*K + gslot*8;
        }
    #pragma unroll
    for (int i=0;i<2;i++){
        int lr = i*64 + (tid>>3);
        int growB = tn + lr;
        int gslot = (tid&7) ^ (lr&7);
        srcB[i] = Bmat + (long)growB*K + gslot*8;
    }
    int aoff[4][2], boff[2][2];
    #pragma unroll
    for (int i=0;i<4;i++)
        #pragma unroll
        for (int k2=0;k2<2;k2++){
            int ra0 = wm*64 + i*16 + (lane&15);
            int slot = (k2*4 + (lane>>4)) ^ (ra0&7);
            aoff[i][k2] = ra0*64 + slot*8;
        }
    #pragma unroll
    for (int nf=0;nf<2;nf++)
        #pragma unroll
        for (int k2=0;k2<2;k2++){
            int rb0 = wn*32 + nf*16 + (lane&15);
            int slot = (k2*4 + (lane>>4)) ^ (rb0&7);
            boff[nf][k2] = 16384 + rb0*64 + slot*8;
        }

    auto stageA = [&](int buf, int t, int r0h){
        long koff = (long)t*64;
        #pragma unroll
        for (int i=0;i<2;i++){
            bf16* dst = &lds[buf][0] + (size_t)(r0h*128 + i*64 + w*8)*64;
            __builtin_amdgcn_global_load_lds(
                (const __attribute__((address_space(1))) void*)(srcA[r0h][i] + koff),
                (__attribute__((address_space(3))) void*)dst, 16, 0, 0);
        }
    };
    auto stageB = [&](int buf, int t){
        long koff = (long)t*64;
        #pragma unroll
        for (int i=0;i<2;i++){
            bf16* dst = &lds[buf][16384] + (size_t)(i*64 + w*8)*64;
            __builtin_amdgcn_global_load_lds(
                (const __attribute__((address_space(1))) void*)(srcB[i] + koff),
                (__attribute__((address_space(3))) void*)dst, 16, 0, 0);
        }
    };

    // ---- prologue: tiles 0 and 1 fully staged ----
    stageA(0, 0, 0); stageA(0, 0, 1); stageB(0, 0);
    if (KT > 1){ stageA(1, 1, 0); stageA(1, 1, 1); stageB(1, 1); }
    asm volatile("s_waitcnt vmcnt(6)" ::: "memory");   // tile-0 A+B complete
    __builtin_amdgcn_s_barrier();

    int cur = 0;
    for (int t = 0; t < KT; ++t){
        int stb = cur + 2; if (stb >= 3) stb -= 3;     // buffer for tile t+2
        const bf16* bufc = &lds[cur][0];
        // ---- P0: row-half 0 ----
        READ_A(bufc, 0)
        READ_B(bufc, 0)
        if (t+2 < KT){ stageA(stb, t+2, 0); stageA(stb, t+2, 1); }
        SBAR();
        MMA_Q(0, 0)
        // ---- P1: row-half 1 (B frags reused from registers) ----
        READ_A(bufc, 1)
        if (t+2 < KT){
            stageB(stb, t+2);
            asm volatile("s_waitcnt vmcnt(6)" ::: "memory");   // tile t+1 A+B complete
        } else {
            asm volatile("s_waitcnt vmcnt(0)" ::: "memory");
        }
        SBAR();
        MMA_Q(1, 0)
        cur = (cur == 2) ? 0 : cur + 1;
    }

    // ---- epilogue: direct f32 store ----
    const int er = (lane>>4)*4, ec = lane&15;
    #pragma unroll
    for (int mi=0;mi<8;mi++)
        #pragma unroll
        for (int ni=0;ni<2;ni++){
            long r0 = tm + wm*128 + mi*16 + er;
            int  c0 = tn + wn*32 + ni*16 + ec;
            #pragma unroll
            for (int j=0;j<4;j++)
                C[(r0+j)*ldc + c0] = acc[mi][ni][j];
        }
}

// ---------------- GEMM1 tail reduce: 4 f32 partials -> zx bf16 + dtf f32 ----------------
__global__ __launch_bounds__(256) void tailreduce_kernel(const float* __restrict__ p,
                                                         bf16* __restrict__ zx,
                                                         float* __restrict__ dtf){
    long i = ((long)blockIdx.x*256 + threadIdx.x)*4;   // over 4096*512
    int r = (int)(i >> 9);
    int c = (int)(i & 511);
    const long Q = (long)4096*512;
    float4 a  = *(const float4*)&p[i];
    float4 b  = *(const float4*)&p[i+Q];
    float4 cc = *(const float4*)&p[i+2*Q];
    float4 d  = *(const float4*)&p[i+3*Q];
    float s0 = a.x+b.x+cc.x+d.x, s1 = a.y+b.y+cc.y+d.y;
    float s2 = a.z+b.z+cc.z+d.z, s3 = a.w+b.w+cc.w+d.w;
    bf16x4 o; o[0]=(bf16)s0; o[1]=(bf16)s1; o[2]=(bf16)s2; o[3]=(bf16)s3;
    *(bf16x4*)&zx[(long)r*ZLD + 8192 + c] = o;
    int col = 8192 + c;
    float sv[4] = {s0,s1,s2,s3};
    #pragma unroll
    for (int j=0;j<4;j++){
        int cj = col + j;
        if (cj >= 8448 && cj < 8512) dtf[(long)r*64 + (cj-8448)] = sv[j];
    }
}

// ---------------- depthwise causal conv(4) + bias + silu, 4ch x 8tok per thread ----------------
__global__ __launch_bounds__(256) void conv_silu_kernel(const bf16* __restrict__ zx,
                                                        const float* __restrict__ Wc,
                                                        const float* __restrict__ bc,
                                                        bf16* __restrict__ xc){
    int c4 = blockIdx.x*256 + threadIdx.x;    // 0..1087 (4352/4)
    if (c4 >= 1088) return;
    int ch = c4*4;
    int byy = blockIdx.y;                      // 0..511
    int b = byy >> 8, t0 = (byy & 255)*8;
    float4 tap[4];
    #pragma unroll
    for (int e=0;e<4;e++) tap[e] = *(const float4*)&Wc[(ch+e)*4];
    float4 bq = *(const float4*)&bc[ch];
    float bca[4] = {bq.x, bq.y, bq.z, bq.w};
    const bf16* col = zx + (long)(b*SEQ)*ZLD + 4096 + ch;
    bf16x4 v[11];
    #pragma unroll
    for (int k=0;k<11;k++){
        int t = t0 - 3 + k;
        if (t >= 0) v[k] = *(const bf16x4*)&col[(long)t*ZLD];
        else { v[k][0]=(bf16)0.f; v[k][1]=(bf16)0.f; v[k][2]=(bf16)0.f; v[k][3]=(bf16)0.f; }
    }
    #pragma unroll
    for (int j=0;j<8;j++){
        bf16x4 o;
        #pragma unroll
        for (int e=0;e<4;e++){
            float acc = bca[e] + (float)v[j][e]*tap[e].x + (float)v[j+1][e]*tap[e].y
                               + (float)v[j+2][e]*tap[e].z + (float)v[j+3][e]*tap[e].w;
            o[e] = (bf16)silu_f(acc);
        }
        *(bf16x4*)&xc[(long)(b*SEQ + t0 + j)*CONVD + ch] = o;
    }
}

// ---------------- dt softplus + per-chunk cumsum: wave-parallel prefix scan ----------------
__global__ __launch_bounds__(256) void dtcum_kernel(const float* __restrict__ dtf,
                                                    const float* __restrict__ A_log,
                                                    const float* __restrict__ dt_bias,
                                                    float* __restrict__ dtv,
                                                    float* __restrict__ dacs,
                                                    float* __restrict__ cdec){
    int wid  = (blockIdx.x*256 + threadIdx.x) >> 6;   // chain id 0..2047 = (b*16+c)*64+h
    int lane = threadIdx.x & 63;
    int h  = wid & 63, bc = wid >> 6;
    int b  = bc >> 4,  c  = bc & 15;
    float Ah   = -expf(A_log[h]);
    float bias = dt_bias[h];
    long tok0 = (long)(b*SEQ + c*CHUNKL);
    int l0 = lane*2;
    float d0 = softplus_f(dtf[(tok0+l0)*64 + h] + bias);
    float d1 = softplus_f(dtf[(tok0+l0+1)*64 + h] + bias);
    float s = (d0 + d1)*Ah;
    #pragma unroll
    for (int off=1; off<64; off<<=1){
        float t = __shfl_up(s, off, 64);
        if (lane >= off) s += t;
    }
    long base_h = (long)wid*128;
    float cs1 = s;
    float cs0 = s - d1*Ah;
    dtv[base_h+l0]   = d0;  dtv[base_h+l0+1]  = d1;
    dacs[base_h+l0]  = cs0; dacs[base_h+l0+1] = cs1;
    if (lane == 63) cdec[wid] = expf(cs1);
}

// ---------------- CB[l][s] = sum_n C[l][n]*B[s][n] via MFMA, per (b,c) ----------------
__global__ __launch_bounds__(256) void cb_mfma_kernel(const bf16* __restrict__ xc,
                                                      float* __restrict__ cb){
    __shared__ __align__(16) bf16 A1[128*LP];
    __shared__ __align__(16) bf16 B1[128*LP];
    int blk = blockIdx.x;  int b = blk>>4, c = blk&15;
    int tid = threadIdx.x;
    const int w = tid >> 6, lane = tid & 63;
    long tok0 = (long)(b*SEQ + c*CHUNKL);
    int l = tid>>1, n0 = (tid&1)*64;
    const bf16* crow = xc + tok0*CONVD + (long)l*CONVD;
    #pragma unroll
    for (int v=0;v<8;v++){
        *(bf16x8*)&A1[l*LP + n0 + v*8] = *(const bf16x8*)&crow[4224 + n0 + v*8];
        *(bf16x8*)&B1[l*LP + n0 + v*8] = *(const bf16x8*)&crow[4096 + n0 + v*8];
    }
    __syncthreads();
    f32x4v acc[2][8];
    #pragma unroll
    for (int mi=0;mi<2;mi++)
        #pragma unroll
        for (int ni=0;ni<8;ni++) acc[mi][ni] = {0.f,0.f,0.f,0.f};
    #pragma unroll
    for (int kk=0; kk<128; kk+=32){
        bf16x8 afr[2], bfr2[8];
        #pragma unroll
        for (int mi=0;mi<2;mi++)
            afr[mi] = *(const bf16x8*)&A1[(w*32 + mi*16 + (lane&15))*LP + kk + (lane>>4)*8];
        #pragma unroll
        for (int ni=0;ni<8;ni++)
            bfr2[ni] = *(const bf16x8*)&B1[(ni*16 + (lane&15))*LP + kk + (lane>>4)*8];
        #pragma unroll
        for (int mi=0;mi<2;mi++)
            #pragma unroll
            for (int ni=0;ni<8;ni++)
                acc[mi][ni] = __builtin_amdgcn_mfma_f32_16x16x32_bf16(afr[mi], bfr2[ni], acc[mi][ni], 0,0,0);
    }
    float* out = cb + (long)blk*16384;
    #pragma unroll
    for (int mi=0;mi<2;mi++)
        #pragma unroll
        for (int ni=0;ni<8;ni++){
            int r0 = w*32 + mi*16 + (lane>>4)*4;
            int c0 = ni*16 + (lane&15);
            #pragma unroll
            for (int j=0;j<4;j++) out[(long)(r0+j)*128 + c0] = acc[mi][ni][j];
        }
}

// ---------------- states[p][n] via MFMA, per (b,c,h), bf16 out ----------------
__global__ __launch_bounds__(256) void states_mfma_kernel(const bf16* __restrict__ xc,
                                                          const float* __restrict__ dtv,
                                                          const float* __restrict__ dacs,
                                                          bf16* __restrict__ states){
    __shared__ __align__(16) bf16 A1[64*LP];
    __shared__ __align__(16) bf16 B1[128*LP];
    __shared__ float wgtl[128];
    int blk = blockIdx.x;
    int h = blk & 63, bc = blk >> 6;
    int b = bc >> 4, c = bc & 15;
    int tid = threadIdx.x;
    const int w = tid >> 6, lane = tid & 63;
    long tok0 = (long)(b*SEQ + c*CHUNKL);
    long base_h = (long)blk*128;
    float cs_last = dacs[base_h + 127];
    if (tid < 128) wgtl[tid] = dtv[base_h+tid] * expf(cs_last - dacs[base_h+tid]);
    __syncthreads();
    #pragma unroll
    for (int t=0;t<4;t++){
        int l = (tid>>3) + t*32;
        int p0 = (tid&7)*8;
        bf16x8 xv = *(const bf16x8*)&xc[(tok0+l)*CONVD + h*64 + p0];
        float wv = wgtl[l];
        #pragma unroll
        for (int e=0;e<8;e++) A1[(p0+e)*LP + l] = (bf16)((float)xv[e]*wv);
    }
    {
        int l = tid>>1, n0 = (tid&1)*64;
        const bf16* brow = xc + (tok0+l)*CONVD + 4096;
        #pragma unroll
        for (int v=0;v<8;v++){
            bf16x8 bv = *(const bf16x8*)&brow[n0 + v*8];
            #pragma unroll
            for (int e=0;e<8;e++) B1[(n0+v*8+e)*LP + l] = bv[e];
        }
    }
    __syncthreads();
    f32x4v acc[8];
    #pragma unroll
    for (int ni=0;ni<8;ni++) acc[ni] = {0.f,0.f,0.f,0.f};
    #pragma unroll
    for (int kk=0; kk<128; kk+=32){
        bf16x8 afr = *(const bf16x8*)&A1[(w*16 + (lane&15))*LP + kk + (lane>>4)*8];
        #pragma unroll
        for (int ni=0;ni<8;ni++){
            bf16x8 bfr2 = *(const bf16x8*)&B1[(ni*16 + (lane&15))*LP + kk + (lane>>4)*8];
            acc[ni] = __builtin_amdgcn_mfma_f32_16x16x32_bf16(afr, bfr2, acc[ni], 0,0,0);
        }
    }
    bf16* out = states + (long)blk*8192;
    #pragma unroll
    for (int ni=0;ni<8;ni++){
        int p0 = w*16 + (lane>>4)*4;
        int n  = ni*16 + (lane&15);
        #pragma unroll
        for (int j=0;j<4;j++) out[(long)(p0+j)*128 + n] = (bf16)acc[ni][j];
    }
}

// ---------------- sequential chunk scan (bf16 in/out, f32 accum) ----------------
__global__ __launch_bounds__(256) void scan_kernel(const bf16* __restrict__ states,
                                                   const float* __restrict__ cdec,
                                                   bf16* __restrict__ hst){
    long gid = (long)blockIdx.x*256 + threadIdx.x;
    int n = gid & 127;
    int p = (gid >> 7) & 63;
    int h = (gid >> 13) & 63;
    int b = (int)(gid >> 19);
    float hrun = 0.f;
    for (int c=0;c<16;c++){
        long idx = ((((long)(b*16 + c)*64 + h)*64 + p)*128) + n;
        hst[idx] = (bf16)hrun;
        hrun = hrun * cdec[(b*16+c)*64 + h] + (float)states[idx];
    }
}

// ---------------- fused Y = P@u^T + (C*sdo)@hst^T ----------------
__global__ __launch_bounds__(256) void yfused_kernel(const bf16* __restrict__ xc,
                                                     const float* __restrict__ cb,
                                                     const bf16* __restrict__ hst,
                                                     const float* __restrict__ dtv,
                                                     const float* __restrict__ dacs,
                                                     bf16* __restrict__ Ybf){
    __shared__ __align__(16) bf16 A1[128*LP];
    __shared__ __align__(16) bf16 B1[64*LP];
    __shared__ float csl[128];
    int blk = blockIdx.x;
    int h = blk & 63, bc = blk >> 6;
    int b = bc >> 4, c = bc & 15;
    int tid = threadIdx.x;
    const int w = tid >> 6, lane = tid & 63;
    long tok0 = (long)(b*SEQ + c*CHUNKL);
    long base_h = (long)blk*128;
    if (tid < 128) csl[tid] = dacs[base_h + tid];
    __syncthreads();
    {
        int l = tid>>1, s0 = (tid&1)*64;
        float el = csl[l];
        const float* cbrow = cb + (long)bc*16384 + (long)l*128 + s0;
        #pragma unroll 8
        for (int j=0;j<64;j++){
            int s = s0 + j;
            float v = (s <= l) ? cbrow[j]*expf(el - csl[s]) : 0.f;
            A1[l*LP + s] = (bf16)v;
        }
    }
    #pragma unroll
    for (int t=0;t<4;t++){
        int s = (tid>>3) + t*32;
        int p0 = (tid&7)*8;
        bf16x8 xv = *(const bf16x8*)&xc[(tok0+s)*CONVD + h*64 + p0];
        float wv = dtv[base_h + s];
        #pragma unroll
        for (int e=0;e<8;e++) B1[(p0+e)*LP + s] = (bf16)((float)xv[e]*wv);
    }
    __syncthreads();
    f32x4v acc[2][4];
    #pragma unroll
    for (int mi=0;mi<2;mi++)
        #pragma unroll
        for (int ni=0;ni<4;ni++) acc[mi][ni] = {0.f,0.f,0.f,0.f};
    #pragma unroll
    for (int kk=0; kk<128; kk+=32){
        bf16x8 afr[2], bfr2[4];
        #pragma unroll
        for (int mi=0;mi<2;mi++)
            afr[mi] = *(const bf16x8*)&A1[(w*32 + mi*16 + (lane&15))*LP + kk + (lane>>4)*8];
        #pragma unroll
        for (int ni=0;ni<4;ni++)
            bfr2[ni] = *(const bf16x8*)&B1[(ni*16 + (lane&15))*LP + kk + (lane>>4)*8];
        #pragma unroll
        for (int mi=0;mi<2;mi++)
            #pragma unroll
            for (int ni=0;ni<4;ni++)
                acc[mi][ni] = __builtin_amdgcn_mfma_f32_16x16x32_bf16(afr[mi], bfr2[ni], acc[mi][ni], 0,0,0);
    }
    __syncthreads();
    {
        int l = tid>>1, n0 = (tid&1)*64;
        float e1 = expf(csl[l]);
        const bf16* crow = xc + (tok0+l)*CONVD + 4224;
        #pragma unroll
        for (int v=0;v<8;v++){
            bf16x8 cv = *(const bf16x8*)&crow[n0 + v*8];
            bf16x8 o;
            #pragma unroll
            for (int e=0;e<8;e++) o[e] = (bf16)((float)cv[e]*e1);
            *(bf16x8*)&A1[l*LP + n0 + v*8] = o;
        }
    }
    {
        int p = tid>>2, n0 = (tid&3)*32;
        const bf16* hrow = hst + (long)blk*8192 + (long)p*128 + n0;
        #pragma unroll
        for (int v=0;v<4;v++)
            *(bf16x8*)&B1[p*LP + n0 + v*8] = *(const bf16x8*)&hrow[v*8];
    }
    __syncthreads();
    #pragma unroll
    for (int kk=0; kk<128; kk+=32){
        bf16x8 afr[2], bfr2[4];
        #pragma unroll
        for (int mi=0;mi<2;mi++)
            afr[mi] = *(const bf16x8*)&A1[(w*32 + mi*16 + (lane&15))*LP + kk + (lane>>4)*8];
        #pragma unroll
        for (int ni=0;ni<4;ni++)
            bfr2[ni] = *(const bf16x8*)&B1[(ni*16 + (lane&15))*LP + kk + (lane>>4)*8];
        #pragma unroll
        for (int mi=0;mi<2;mi++)
            #pragma unroll
            for (int ni=0;ni<4;ni++)
                acc[mi][ni] = __builtin_amdgcn_mfma_f32_16x16x32_bf16(afr[mi], bfr2[ni], acc[mi][ni], 0,0,0);
    }
    #pragma unroll
    for (int mi=0;mi<2;mi++)
        #pragma unroll
        for (int ni=0;ni<4;ni++){
            int l0 = w*32 + mi*16 + (lane>>4)*4;
            int p  = ni*16 + (lane&15);
            #pragma unroll
            for (int j=0;j<4;j++)
                Ybf[(tok0 + l0 + j)*DI + h*64 + p] = (bf16)acc[mi][ni][j];
        }
}

// ---------------- gate (silu(z)) + D*x + RMSNorm + cast bf16 ----------------
__global__ __launch_bounds__(256) void gatenorm_kernel(const bf16* __restrict__ Ybf,
                                                       const bf16* __restrict__ zx,
                                                       const bf16* __restrict__ xc,
                                                       const float* __restrict__ Dp,
                                                       const float* __restrict__ nw,
                                                       bf16* __restrict__ ybn){
    __shared__ float red[4];
    int tok = blockIdx.x, tid = threadIdx.x;
    const bf16* yrow = Ybf + (long)tok*DI;
    const bf16* zrow = zx  + (long)tok*ZLD;
    const bf16* xrow = xc  + (long)tok*CONVD;
    float yg[16];
    float ss = 0.f;
    #pragma unroll
    for (int k=0;k<2;k++){
        int d = (tid + k*256)*8;
        bf16x8 yv = *(const bf16x8*)&yrow[d];
        bf16x8 zv = *(const bf16x8*)&zrow[d];
        bf16x8 xv = *(const bf16x8*)&xrow[d];
        float dh = Dp[d>>6];
        #pragma unroll
        for (int e=0;e<8;e++){
            float yy = (float)yv[e] + dh*(float)xv[e];
            float g = yy*silu_f((float)zv[e]);
            yg[k*8+e] = g;
            ss += g*g;
        }
    }
    #pragma unroll
    for (int off=32; off>0; off>>=1) ss += __shfl_down(ss, off, 64);
    if ((tid & 63) == 0) red[tid>>6] = ss;
    __syncthreads();
    float tot = red[0]+red[1]+red[2]+red[3];
    float scale = rsqrtf(tot/(float)DI + 1e-5f);
    #pragma unroll
    for (int k=0;k<2;k++){
        int d = (tid + k*256)*8;
        float4 w0 = *(const float4*)&nw[d];
        float4 w1 = *(const float4*)&nw[d+4];
        float wv[8] = {w0.x,w0.y,w0.z,w0.w,w1.x,w1.y,w1.z,w1.w};
        bf16x8 o;
        #pragma unroll
        for (int e=0;e<8;e++) o[e] = (bf16)(yg[k*8+e]*scale*wv[e]);
        *(bf16x8*)&ybn[(long)tok*DI + d] = o;
    }
}

// ---------------- launch ----------------
extern "C" void kernel_launch(void* const* d_in, const int* in_sizes, int n_in,
                              void* d_out, int out_size, void* d_ws, size_t ws_size,
                              hipStream_t stream){
    const float* hs      = (const float*)d_in[0];
    const float* W_in    = (const float*)d_in[1];
    const float* W_conv  = (const float*)d_in[2];
    const float* b_conv  = (const float*)d_in[3];
    const float* A_log   = (const float*)d_in[4];
    const float* Dp      = (const float*)d_in[5];
    const float* dt_bias = (const float*)d_in[6];
    const float* nw      = (const float*)d_in[7];
    const float* W_out   = (const float*)d_in[8];
    float* out = (float*)d_out;

    char* ws = (char*)d_ws;
    const size_t OFF_ZX    = 0;                    // bf16 [4096][8704]      71,303,168
    const size_t OFF_DTF   = 71303168;             // f32  [4096][64]         1,048,576
    const size_t OFF_XC    = 72351744;             // bf16 [4096][4352]      35,651,584
    const size_t OFF_DTV   = 108003328;            // f32                     1,048,576
    const size_t OFF_DACS  = 109051904;            //                         1,048,576
    const size_t OFF_CDEC  = 110100480;            // f32 [2048]                  8,192
    const size_t OFF_CB    = 110108672;            // f32 [32][128][128]      2,097,152
    const size_t OFF_SLOTA = 112205824;            // 67,108,864: hsb+winb -> states(bf16) -> Ybf
    const size_t OFF_SLOTB = 179314688;            // 33,554,432: tailpart -> hst(bf16) -> ybn
    const size_t OFF_WOUTB = 212869120;            // bf16 [2048][4096]      16,777,216

    bf16*  zx    = (bf16*)(ws + OFF_ZX);
    float* dtf   = (float*)(ws + OFF_DTF);
    bf16*  xc    = (bf16*)(ws + OFF_XC);
    float* dtv   = (float*)(ws + OFF_DTV);
    float* dacs  = (float*)(ws + OFF_DACS);
    float* cdec  = (float*)(ws + OFF_CDEC);
    float* cbuf  = (float*)(ws + OFF_CB);
    bf16*  hsb   = (bf16*)(ws + OFF_SLOTA);
    bf16*  winb  = (bf16*)(ws + OFF_SLOTA + 16777216);
    bf16*  states= (bf16*)(ws + OFF_SLOTA);
    bf16*  Ybf   = (bf16*)(ws + OFF_SLOTA);
    float* tpart = (float*)(ws + OFF_SLOTB);       // 4 x [4096][512] f32 GEMM1-tail partials
    bf16*  hst   = (bf16*)(ws + OFF_SLOTB);
    bf16*  ybn   = (bf16*)(ws + OFF_SLOTB);
    bf16*  woutb = (bf16*)(ws + OFF_WOUTB);

    cvt_all_kernel<<<33792, 256, 0, stream>>>(hs, W_in, W_out, hsb, winb, woutb);

    // GEMM1 bulk: cols [0,8192) -> zx bf16, 512 blocks = exactly 2 waves
    gemm256_kernel<1><<<512, 512, 0, stream>>>(hsb, winb, (void*)zx,
                                               32, 16, DMODEL, ZLD);
    // GEMM1 tail: cols [8192,8704), split-K=4 -> f32 partials
    gemm256_kernel<3><<<128, 512, 0, stream>>>(hsb, winb, (void*)tpart,
                                               34, 16, DMODEL, ZLD);
    tailreduce_kernel<<<2048, 256, 0, stream>>>(tpart, zx, dtf);

    conv_silu_kernel<<<dim3(5, 512), 256, 0, stream>>>(zx, W_conv, b_conv, xc);
    dtcum_kernel<<<512, 256, 0, stream>>>(dtf, A_log, dt_bias, dtv, dacs, cdec);
    cb_mfma_kernel<<<32, 256, 0, stream>>>(xc, cbuf);
    states_mfma_kernel<<<2048, 256, 0, stream>>>(xc, dtv, dacs, states);
    scan_kernel<<<4096, 256, 0, stream>>>(states, cdec, hst);
    yfused_kernel<<<2048, 256, 0, stream>>>(xc, cbuf, hst, dtv, dacs, Ybf);
    gatenorm_kernel<<<4096, 256, 0, stream>>>(Ybf, zx, xc, Dp, nw, ybn);

    // GEMM2: [4096,4096] x [2048,4096]^T -> out f32 direct (256x128 tiles, 1 round)
    gemm256x128_kernel<<<256, 512, 0, stream>>>(ybn, woutb, out, 16, 16, DI, DMODEL);
}

// Round 9
// 431.279 us; speedup vs baseline: 2.2518x; 1.0158x over previous
//
#include <hip/hip_runtime.h>
#include <hip/hip_bf16.h>
#include <stdint.h>

typedef __bf16 bf16;
typedef __bf16 bf16x8 __attribute__((ext_vector_type(8)));
typedef __bf16 bf16x4 __attribute__((ext_vector_type(4)));
typedef float f32x4v __attribute__((ext_vector_type(4)));

#define SEQ    2048
#define DMODEL 2048
#define DI     4096
#define NH     64
#define PDIM   64
#define CHUNKL 128
#define NCH    16
#define CONVD  4352
#define DPROJ  8512
#define ZLD    8704   // zxbcdt leading dim, padded to 34*256
#define NTOK   4096
#define LP     136    // padded LDS leading dim for middle kernels

__device__ __forceinline__ float sigmoid_f(float x){ return 1.f/(1.f+expf(-x)); }
__device__ __forceinline__ float silu_f(float x){ return x*sigmoid_f(x); }
__device__ __forceinline__ float softplus_f(float x){ return x > 20.f ? x : log1pf(expf(x)); }

// ---------------- fused conversions: hs->bf16 | W_in->bf16 padded | W_out->bf16 ----------------
__global__ __launch_bounds__(256) void cvt_all_kernel(const float* __restrict__ hs,
                                                      const float* __restrict__ W_in,
                                                      const float* __restrict__ W_out,
                                                      bf16* __restrict__ hsb,
                                                      bf16* __restrict__ winb,
                                                      bf16* __restrict__ woutb){
    int blk = blockIdx.x;
    if (blk < 8192){
        int i = (blk*256 + threadIdx.x)*4;
        float4 v = *(const float4*)&hs[i];
        bf16x4 o; o[0]=(bf16)v.x; o[1]=(bf16)v.y; o[2]=(bf16)v.z; o[3]=(bf16)v.w;
        *(bf16x4*)&hsb[i] = o;
    } else if (blk < 25600){
        int i = ((blk-8192)*256 + threadIdx.x)*4;   // over 8704*2048
        int r = i >> 11;
        bf16x4 o;
        if (r < DPROJ){
            float4 v = *(const float4*)&W_in[i];
            o[0]=(bf16)v.x; o[1]=(bf16)v.y; o[2]=(bf16)v.z; o[3]=(bf16)v.w;
        } else {
            o[0]=(bf16)0.f; o[1]=(bf16)0.f; o[2]=(bf16)0.f; o[3]=(bf16)0.f;
        }
        *(bf16x4*)&winb[i] = o;
    } else {
        int i = ((blk-25600)*256 + threadIdx.x)*4;
        float4 v = *(const float4*)&W_out[i];
        bf16x4 o; o[0]=(bf16)v.x; o[1]=(bf16)v.y; o[2]=(bf16)v.z; o[3]=(bf16)v.w;
        *(bf16x4*)&woutb[i] = o;
    }
}

// ============ shared GEMM fragment macros ============
#define READ_A(BUFP, QM)                                                               \
    {                                                                                  \
        _Pragma("unroll")                                                              \
        for (int i=0;i<4;i++)                                                          \
            _Pragma("unroll")                                                          \
            for (int k2=0;k2<2;k2++)                                                   \
                af[i][k2] = *(const bf16x8*)&(BUFP)[aoff[i][k2] + (QM)*8192];          \
    }

#define READ_B(BUFP, QN, BFR)                                                          \
    {                                                                                  \
        _Pragma("unroll")                                                              \
        for (int nf=0;nf<2;nf++)                                                       \
            _Pragma("unroll")                                                          \
            for (int k2=0;k2<2;k2++)                                                   \
                BFR[nf][k2] = *(const bf16x8*)&(BUFP)[boff[nf][k2] + (QN)*8192];       \
    }

#define MMA_Q(QM, QN, BFR)                                                             \
    {                                                                                  \
        __builtin_amdgcn_s_setprio(1);                                                 \
        _Pragma("unroll")                                                              \
        for (int i=0;i<4;i++)                                                          \
            _Pragma("unroll")                                                          \
            for (int nf=0;nf<2;nf++)                                                   \
                _Pragma("unroll")                                                      \
                for (int k2=0;k2<2;k2++)                                               \
                    acc[(QM)*4+i][(QN)*2+nf] = __builtin_amdgcn_mfma_f32_16x16x32_bf16( \
                        af[i][k2], BFR[nf][k2], acc[(QM)*4+i][(QN)*2+nf], 0,0,0);      \
        __builtin_amdgcn_s_setprio(0);                                                 \
    }

#define SBAR() do { __builtin_amdgcn_sched_barrier(0);                                 \
                    __builtin_amdgcn_s_barrier();                                      \
                    asm volatile("s_waitcnt lgkmcnt(0)" ::: "memory");                 \
                    __builtin_amdgcn_sched_barrier(0); } while(0)

// ============ 256x256 2-phase bf16 GEMM (GEMM1, bulk+tail merged) ============
// grid 640: bid<128 = tail blocks (x in {32,33}, split-K=4, f32 partials);
//           bid>=128 = bulk (cols<8192, bf16 C). 2 barriers + 1 vmcnt per K-tile.
// All re-stages into consumed regions sit AFTER a barrier following the reads.
__global__ __launch_bounds__(512) void gemm1_kernel(const bf16* __restrict__ A,
                                                    const bf16* __restrict__ Bmat,
                                                    bf16* __restrict__ Cz,
                                                    float* __restrict__ tpart,
                                                    int NXB, int NYB, int K){
    __shared__ __align__(16) bf16 lds[2][2*16384];   // [buf][A(16384) | B(16384)]
    const int tid  = threadIdx.x;
    const int w    = tid >> 6;
    const int lane = tid & 63;
    const int wm   = w >> 2, wn = w & 3;

    int bid = blockIdx.x;
    int x, y, kz = 0, KT, kt0;
    if (bid < 128){                       // tail: split-K=4 over cols [8192,8704)
        kz = bid >> 5;
        int t32 = bid & 31;
        x = 32 + (t32 & 1);
        y = t32 >> 1;
        KT = 8; kt0 = kz*8;
    } else {
        int bid2 = bid - 128;             // 0..511
        int wg   = (bid2 & 7)*64 + (bid2 >> 3);
        const int SW = 8;
        int sup = wg / (SW*NYB);
        int rr  = wg % (SW*NYB);
        int x0  = sup*SW;
        int wl  = (NXB - x0 < SW) ? (NXB - x0) : SW;
        x = x0 + rr % wl;
        y = rr / wl;
        KT = K >> 6; kt0 = 0;
    }
    const int tm = y*256, tn = x*256;

    f32x4v acc[8][4];
    #pragma unroll
    for (int i=0;i<8;i++)
        #pragma unroll
        for (int j=0;j<4;j++) acc[i][j] = {0.f,0.f,0.f,0.f};
    bf16x8 af[4][2];
    bf16x8 bfr0[2][2], bfr1[2][2];

    // ---- hoisted per-lane addressing ----
    const bf16* srcA[2][2];
    const bf16* srcB[2][2];
    #pragma unroll
    for (int r0h=0;r0h<2;r0h++)
        #pragma unroll
        for (int i=0;i<2;i++){
            int lr = r0h*128 + i*64 + (tid>>3);
            int growA = tm + ((lr>>6)&1)*128 + (lr>>7)*64 + (lr&63);
            int growB = tn + ((lr>>5)&3)*64 + (lr>>7)*32 + (lr&31);
            int gslot = (tid&7) ^ (lr&7);
            srcA[r0h][i] = A + (long)growA*K + gslot*8;
            srcB[r0h][i] = Bmat + (long)growB*K + gslot*8;
        }
    int aoff[4][2], boff[2][2];
    #pragma unroll
    for (int i=0;i<4;i++)
        #pragma unroll
        for (int k2=0;k2<2;k2++){
            int ra0 = wm*64 + i*16 + (lane&15);
            int slot = (k2*4 + (lane>>4)) ^ (ra0&7);
            aoff[i][k2] = ra0*64 + slot*8;
        }
    #pragma unroll
    for (int nf=0;nf<2;nf++)
        #pragma unroll
        for (int k2=0;k2<2;k2++){
            int rb0 = wn*32 + nf*16 + (lane&15);
            int slot = (k2*4 + (lane>>4)) ^ (rb0&7);
            boff[nf][k2] = 16384 + rb0*64 + slot*8;
        }

    auto stageA = [&](int buf, int t, int r0h){
        long koff = (long)(kt0 + t)*64;
        #pragma unroll
        for (int i=0;i<2;i++){
            bf16* dst = &lds[buf][0] + (size_t)(r0h*128 + i*64 + w*8)*64;
            __builtin_amdgcn_global_load_lds(
                (const __attribute__((address_space(1))) void*)(srcA[r0h][i] + koff),
                (__attribute__((address_space(3))) void*)dst, 16, 0, 0);
        }
    };
    auto stageB = [&](int buf, int t, int r0h){
        long koff = (long)(kt0 + t)*64;
        #pragma unroll
        for (int i=0;i<2;i++){
            bf16* dst = &lds[buf][16384] + (size_t)(r0h*128 + i*64 + w*8)*64;
            __builtin_amdgcn_global_load_lds(
                (const __attribute__((address_space(1))) void*)(srcB[r0h][i] + koff),
                (__attribute__((address_space(3))) void*)dst, 16, 0, 0);
        }
    };

    // ---- prologue: t0 and t1 fully staged (8 + 8 loads) ----
    stageA(0, 0, 0); stageB(0, 0, 0); stageA(0, 0, 1); stageB(0, 0, 1);
    if (KT > 1){ stageA(1, 1, 0); stageB(1, 1, 0); stageA(1, 1, 1); stageB(1, 1, 1); }
    asm volatile("s_waitcnt vmcnt(8)" ::: "memory");
    __builtin_amdgcn_s_barrier();

    int cur = 0;
    for (int t = 0; t < KT; ++t){
        int nxt = cur ^ 1;
        const bf16* bufc = &lds[cur][0];
        // ---- PhA: quadrants (0,0) and (0,1) ----
        READ_A(bufc, 0)
        READ_B(bufc, 0, bfr0)
        READ_B(bufc, 1, bfr1)
        if (t+1 < KT){ asm volatile("s_waitcnt vmcnt(8)" ::: "memory"); }
        else         { asm volatile("s_waitcnt vmcnt(0)" ::: "memory"); }
        SBAR();
        MMA_Q(0, 0, bfr0)
        MMA_Q(0, 1, bfr1)
        __builtin_amdgcn_sched_barrier(0);
        if (t+2 < KT){ stageA(cur, t+2, 0); stageB(cur, t+2, 0); }   // after SBAR(PhA): WAR-safe
        // ---- PhB: quadrants (1,0) and (1,1); B frags reused from registers ----
        READ_A(bufc, 1)
        SBAR();
        MMA_Q(1, 0, bfr0)
        MMA_Q(1, 1, bfr1)
        __builtin_amdgcn_sched_barrier(0);
        if (t+2 < KT){ stageA(cur, t+2, 1); stageB(cur, t+2, 1); }   // after SBAR(PhB): WAR-safe
        cur = nxt;
    }

    // ---- epilogue ----
    const int er = (lane>>4)*4, ec = lane&15;
    #pragma unroll
    for (int mi=0;mi<8;mi++)
        #pragma unroll
        for (int ni=0;ni<4;ni++){
            long r0 = tm + wm*128 + mi*16 + er;
            int  c0 = tn + wn*64 + ni*16 + ec;
            #pragma unroll
            for (int j=0;j<4;j++){
                float val = acc[mi][ni][j];
                if (x < 32){
                    Cz[(r0+j)*ZLD + c0] = (bf16)val;
                } else {
                    tpart[((long)kz*4096 + (r0+j))*512 + (c0 - 8192)] = val;
                }
            }
        }
}

// ============ 256x128 triple-buffered bf16 GEMM (GEMM2): C(f32) = A * B^T ============
__global__ __launch_bounds__(512) void gemm256x128_kernel(const bf16* __restrict__ A,
                                                          const bf16* __restrict__ Bmat,
                                                          float* __restrict__ C,
                                                          int NXB, int NYB, int K, int ldc){
    __shared__ __align__(16) bf16 lds[3][24576];   // [buf][A(16384) | B(8192)]
    const int tid  = threadIdx.x;
    const int w    = tid >> 6;
    const int lane = tid & 63;
    const int wm   = w >> 2, wn = w & 3;

    int bid = blockIdx.x, nb = gridDim.x;
    int wg = (bid & 7)*(nb >> 3) + (bid >> 3);
    const int SW = 8;
    int sup = wg / (SW*NYB);
    int rr  = wg % (SW*NYB);
    int x0  = sup*SW;
    int wl  = (NXB - x0 < SW) ? (NXB - x0) : SW;
    int x   = x0 + rr % wl;
    int y   = rr / wl;
    const int tm = y*256, tn = x*128;
    const int KT = K >> 6;

    f32x4v acc[8][2];
    #pragma unroll
    for (int i=0;i<8;i++)
        #pragma unroll
        for (int j=0;j<2;j++) acc[i][j] = {0.f,0.f,0.f,0.f};
    bf16x8 af[4][2];
    bf16x8 bfr[2][2];

    const bf16* srcA[2][2];
    const bf16* srcB[2];
    #pragma unroll
    for (int r0h=0;r0h<2;r0h++)
        #pragma unroll
        for (int i=0;i<2;i++){
            int lr = r0h*128 + i*64 + (tid>>3);
            int growA = tm + ((lr>>6)&1)*128 + (lr>>7)*64 + (lr&63);
            int gslot = (tid&7) ^ (lr&7);
            srcA[r0h][i] = A + (long)growA*K + gslot*8;
        }
    #pragma unroll
    for (int i=0;i<2;i++){
        int lr = i*64 + (tid>>3);
        int growB = tn + lr;
        int gslot = (tid&7) ^ (lr&7);
        srcB[i] = Bmat + (long)growB*K + gslot*8;
    }
    int aoff[4][2], boff[2][2];
    #pragma unroll
    for (int i=0;i<4;i++)
        #pragma unroll
        for (int k2=0;k2<2;k2++){
            int ra0 = wm*64 + i*16 + (lane&15);
            int slot = (k2*4 + (lane>>4)) ^ (ra0&7);
            aoff[i][k2] = ra0*64 + slot*8;
        }
    #pragma unroll
    for (int nf=0;nf<2;nf++)
        #pragma unroll
        for (int k2=0;k2<2;k2++){
            int rb0 = wn*32 + nf*16 + (lane&15);
            int slot = (k2*4 + (lane>>4)) ^ (rb0&7);
            boff[nf][k2] = 16384 + rb0*64 + slot*8;
        }

    auto stageA = [&](int buf, int t, int r0h){
        long koff = (long)t*64;
        #pragma unroll
        for (int i=0;i<2;i++){
            bf16* dst = &lds[buf][0] + (size_t)(r0h*128 + i*64 + w*8)*64;
            __builtin_amdgcn_global_load_lds(
                (const __attribute__((address_space(1))) void*)(srcA[r0h][i] + koff),
                (__attribute__((address_space(3))) void*)dst, 16, 0, 0);
        }
    };
    auto stageB = [&](int buf, int t){
        long koff = (long)t*64;
        #pragma unroll
        for (int i=0;i<2;i++){
            bf16* dst = &lds[buf][16384] + (size_t)(i*64 + w*8)*64;
            __builtin_amdgcn_global_load_lds(
                (const __attribute__((address_space(1))) void*)(srcB[i] + koff),
                (__attribute__((address_space(3))) void*)dst, 16, 0, 0);
        }
    };

    stageA(0, 0, 0); stageA(0, 0, 1); stageB(0, 0);
    if (KT > 1){ stageA(1, 1, 0); stageA(1, 1, 1); stageB(1, 1); }
    asm volatile("s_waitcnt vmcnt(6)" ::: "memory");
    __builtin_amdgcn_s_barrier();

    int cur = 0;
    for (int t = 0; t < KT; ++t){
        int stb = cur + 2; if (stb >= 3) stb -= 3;
        const bf16* bufc = &lds[cur][0];
        READ_A(bufc, 0)
        READ_B(bufc, 0, bfr)
        if (t+2 < KT){ stageA(stb, t+2, 0); stageA(stb, t+2, 1); }
        SBAR();
        MMA_Q(0, 0, bfr)
        READ_A(bufc, 1)
        if (t+2 < KT){
            stageB(stb, t+2);
            asm volatile("s_waitcnt vmcnt(6)" ::: "memory");
        } else {
            asm volatile("s_waitcnt vmcnt(0)" ::: "memory");
        }
        SBAR();
        MMA_Q(1, 0, bfr)
        cur = (cur == 2) ? 0 : cur + 1;
    }

    const int er = (lane>>4)*4, ec = lane&15;
    #pragma unroll
    for (int mi=0;mi<8;mi++)
        #pragma unroll
        for (int ni=0;ni<2;ni++){
            long r0 = tm + wm*128 + mi*16 + er;
            int  c0 = tn + wn*32 + ni*16 + ec;
            #pragma unroll
            for (int j=0;j<4;j++)
                C[(r0+j)*ldc + c0] = acc[mi][ni][j];
        }
}

// ---------------- GEMM1 tail reduce: 4 f32 partials -> zx bf16 + dtf f32 ----------------
__global__ __launch_bounds__(256) void tailreduce_kernel(const float* __restrict__ p,
                                                         bf16* __restrict__ zx,
                                                         float* __restrict__ dtf){
    long i = ((long)blockIdx.x*256 + threadIdx.x)*4;   // over 4096*512
    int r = (int)(i >> 9);
    int c = (int)(i & 511);
    const long Q = (long)4096*512;
    float4 a  = *(const float4*)&p[i];
    float4 b  = *(const float4*)&p[i+Q];
    float4 cc = *(const float4*)&p[i+2*Q];
    float4 d  = *(const float4*)&p[i+3*Q];
    float s0 = a.x+b.x+cc.x+d.x, s1 = a.y+b.y+cc.y+d.y;
    float s2 = a.z+b.z+cc.z+d.z, s3 = a.w+b.w+cc.w+d.w;
    bf16x4 o; o[0]=(bf16)s0; o[1]=(bf16)s1; o[2]=(bf16)s2; o[3]=(bf16)s3;
    *(bf16x4*)&zx[(long)r*ZLD + 8192 + c] = o;
    int col = 8192 + c;
    float sv[4] = {s0,s1,s2,s3};
    #pragma unroll
    for (int j=0;j<4;j++){
        int cj = col + j;
        if (cj >= 8448 && cj < 8512) dtf[(long)r*64 + (cj-8448)] = sv[j];
    }
}

// ---------------- depthwise causal conv(4) + bias + silu, 4ch x 8tok per thread ----------------
__global__ __launch_bounds__(256) void conv_silu_kernel(const bf16* __restrict__ zx,
                                                        const float* __restrict__ Wc,
                                                        const float* __restrict__ bc,
                                                        bf16* __restrict__ xc){
    int c4 = blockIdx.x*256 + threadIdx.x;    // 0..1087 (4352/4)
    if (c4 >= 1088) return;
    int ch = c4*4;
    int byy = blockIdx.y;                      // 0..511
    int b = byy >> 8, t0 = (byy & 255)*8;
    float4 tap[4];
    #pragma unroll
    for (int e=0;e<4;e++) tap[e] = *(const float4*)&Wc[(ch+e)*4];
    float4 bq = *(const float4*)&bc[ch];
    float bca[4] = {bq.x, bq.y, bq.z, bq.w};
    const bf16* col = zx + (long)(b*SEQ)*ZLD + 4096 + ch;
    bf16x4 v[11];
    #pragma unroll
    for (int k=0;k<11;k++){
        int t = t0 - 3 + k;
        if (t >= 0) v[k] = *(const bf16x4*)&col[(long)t*ZLD];
        else { v[k][0]=(bf16)0.f; v[k][1]=(bf16)0.f; v[k][2]=(bf16)0.f; v[k][3]=(bf16)0.f; }
    }
    #pragma unroll
    for (int j=0;j<8;j++){
        bf16x4 o;
        #pragma unroll
        for (int e=0;e<4;e++){
            float acc = bca[e] + (float)v[j][e]*tap[e].x + (float)v[j+1][e]*tap[e].y
                               + (float)v[j+2][e]*tap[e].z + (float)v[j+3][e]*tap[e].w;
            o[e] = (bf16)silu_f(acc);
        }
        *(bf16x4*)&xc[(long)(b*SEQ + t0 + j)*CONVD + ch] = o;
    }
}

// ---------------- dt softplus + per-chunk cumsum: wave-parallel prefix scan ----------------
__global__ __launch_bounds__(256) void dtcum_kernel(const float* __restrict__ dtf,
                                                    const float* __restrict__ A_log,
                                                    const float* __restrict__ dt_bias,
                                                    float* __restrict__ dtv,
                                                    float* __restrict__ dacs,
                                                    float* __restrict__ cdec){
    int wid  = (blockIdx.x*256 + threadIdx.x) >> 6;   // chain id 0..2047 = (b*16+c)*64+h
    int lane = threadIdx.x & 63;
    int h  = wid & 63, bc = wid >> 6;
    int b  = bc >> 4,  c  = bc & 15;
    float Ah   = -expf(A_log[h]);
    float bias = dt_bias[h];
    long tok0 = (long)(b*SEQ + c*CHUNKL);
    int l0 = lane*2;
    float d0 = softplus_f(dtf[(tok0+l0)*64 + h] + bias);
    float d1 = softplus_f(dtf[(tok0+l0+1)*64 + h] + bias);
    float s = (d0 + d1)*Ah;
    #pragma unroll
    for (int off=1; off<64; off<<=1){
        float t = __shfl_up(s, off, 64);
        if (lane >= off) s += t;
    }
    long base_h = (long)wid*128;
    float cs1 = s;
    float cs0 = s - d1*Ah;
    dtv[base_h+l0]   = d0;  dtv[base_h+l0+1]  = d1;
    dacs[base_h+l0]  = cs0; dacs[base_h+l0+1] = cs1;
    if (lane == 63) cdec[wid] = expf(cs1);
}

// ---------------- CB[l][s] = sum_n C[l][n]*B[s][n] via MFMA, per (b,c) ----------------
__global__ __launch_bounds__(256) void cb_mfma_kernel(const bf16* __restrict__ xc,
                                                      float* __restrict__ cb){
    __shared__ __align__(16) bf16 A1[128*LP];
    __shared__ __align__(16) bf16 B1[128*LP];
    int blk = blockIdx.x;  int b = blk>>4, c = blk&15;
    int tid = threadIdx.x;
    const int w = tid >> 6, lane = tid & 63;
    long tok0 = (long)(b*SEQ + c*CHUNKL);
    int l = tid>>1, n0 = (tid&1)*64;
    const bf16* crow = xc + tok0*CONVD + (long)l*CONVD;
    #pragma unroll
    for (int v=0;v<8;v++){
        *(bf16x8*)&A1[l*LP + n0 + v*8] = *(const bf16x8*)&crow[4224 + n0 + v*8];
        *(bf16x8*)&B1[l*LP + n0 + v*8] = *(const bf16x8*)&crow[4096 + n0 + v*8];
    }
    __syncthreads();
    f32x4v acc[2][8];
    #pragma unroll
    for (int mi=0;mi<2;mi++)
        #pragma unroll
        for (int ni=0;ni<8;ni++) acc[mi][ni] = {0.f,0.f,0.f,0.f};
    #pragma unroll
    for (int kk=0; kk<128; kk+=32){
        bf16x8 afr[2], bfr2[8];
        #pragma unroll
        for (int mi=0;mi<2;mi++)
            afr[mi] = *(const bf16x8*)&A1[(w*32 + mi*16 + (lane&15))*LP + kk + (lane>>4)*8];
        #pragma unroll
        for (int ni=0;ni<8;ni++)
            bfr2[ni] = *(const bf16x8*)&B1[(ni*16 + (lane&15))*LP + kk + (lane>>4)*8];
        #pragma unroll
        for (int mi=0;mi<2;mi++)
            #pragma unroll
            for (int ni=0;ni<8;ni++)
                acc[mi][ni] = __builtin_amdgcn_mfma_f32_16x16x32_bf16(afr[mi], bfr2[ni], acc[mi][ni], 0,0,0);
    }
    float* out = cb + (long)blk*16384;
    #pragma unroll
    for (int mi=0;mi<2;mi++)
        #pragma unroll
        for (int ni=0;ni<8;ni++){
            int r0 = w*32 + mi*16 + (lane>>4)*4;
            int c0 = ni*16 + (lane&15);
            #pragma unroll
            for (int j=0;j<4;j++) out[(long)(r0+j)*128 + c0] = acc[mi][ni][j];
        }
}

// ---------------- states[p][n] via MFMA, per (b,c,h), bf16 out ----------------
__global__ __launch_bounds__(256) void states_mfma_kernel(const bf16* __restrict__ xc,
                                                          const float* __restrict__ dtv,
                                                          const float* __restrict__ dacs,
                                                          bf16* __restrict__ states){
    __shared__ __align__(16) bf16 A1[64*LP];
    __shared__ __align__(16) bf16 B1[128*LP];
    __shared__ float wgtl[128];
    int blk = blockIdx.x;
    int h = blk & 63, bc = blk >> 6;
    int b = bc >> 4, c = bc & 15;
    int tid = threadIdx.x;
    const int w = tid >> 6, lane = tid & 63;
    long tok0 = (long)(b*SEQ + c*CHUNKL);
    long base_h = (long)blk*128;
    float cs_last = dacs[base_h + 127];
    if (tid < 128) wgtl[tid] = dtv[base_h+tid] * expf(cs_last - dacs[base_h+tid]);
    __syncthreads();
    #pragma unroll
    for (int t=0;t<4;t++){
        int l = (tid>>3) + t*32;
        int p0 = (tid&7)*8;
        bf16x8 xv = *(const bf16x8*)&xc[(tok0+l)*CONVD + h*64 + p0];
        float wv = wgtl[l];
        #pragma unroll
        for (int e=0;e<8;e++) A1[(p0+e)*LP + l] = (bf16)((float)xv[e]*wv);
    }
    {
        int l = tid>>1, n0 = (tid&1)*64;
        const bf16* brow = xc + (tok0+l)*CONVD + 4096;
        #pragma unroll
        for (int v=0;v<8;v++){
            bf16x8 bv = *(const bf16x8*)&brow[n0 + v*8];
            #pragma unroll
            for (int e=0;e<8;e++) B1[(n0+v*8+e)*LP + l] = bv[e];
        }
    }
    __syncthreads();
    f32x4v acc[8];
    #pragma unroll
    for (int ni=0;ni<8;ni++) acc[ni] = {0.f,0.f,0.f,0.f};
    #pragma unroll
    for (int kk=0; kk<128; kk+=32){
        bf16x8 afr = *(const bf16x8*)&A1[(w*16 + (lane&15))*LP + kk + (lane>>4)*8];
        #pragma unroll
        for (int ni=0;ni<8;ni++){
            bf16x8 bfr2 = *(const bf16x8*)&B1[(ni*16 + (lane&15))*LP + kk + (lane>>4)*8];
            acc[ni] = __builtin_amdgcn_mfma_f32_16x16x32_bf16(afr, bfr2, acc[ni], 0,0,0);
        }
    }
    bf16* out = states + (long)blk*8192;
    #pragma unroll
    for (int ni=0;ni<8;ni++){
        int p0 = w*16 + (lane>>4)*4;
        int n  = ni*16 + (lane&15);
        #pragma unroll
        for (int j=0;j<4;j++) out[(long)(p0+j)*128 + n] = (bf16)acc[ni][j];
    }
}

// ---------------- sequential chunk scan (bf16 in/out, f32 accum) ----------------
__global__ __launch_bounds__(256) void scan_kernel(const bf16* __restrict__ states,
                                                   const float* __restrict__ cdec,
                                                   bf16* __restrict__ hst){
    long gid = (long)blockIdx.x*256 + threadIdx.x;
    int n = gid & 127;
    int p = (gid >> 7) & 63;
    int h = (gid >> 13) & 63;
    int b = (int)(gid >> 19);
    float hrun = 0.f;
    for (int c=0;c<16;c++){
        long idx = ((((long)(b*16 + c)*64 + h)*64 + p)*128) + n;
        hst[idx] = (bf16)hrun;
        hrun = hrun * cdec[(b*16+c)*64 + h] + (float)states[idx];
    }
}

// ---------------- fused Y = P@u^T + (C*sdo)@hst^T ----------------
__global__ __launch_bounds__(256) void yfused_kernel(const bf16* __restrict__ xc,
                                                     const float* __restrict__ cb,
                                                     const bf16* __restrict__ hst,
                                                     const float* __restrict__ dtv,
                                                     const float* __restrict__ dacs,
                                                     bf16* __restrict__ Ybf){
    __shared__ __align__(16) bf16 A1[128*LP];
    __shared__ __align__(16) bf16 B1[64*LP];
    __shared__ float csl[128];
    int blk = blockIdx.x;
    int h = blk & 63, bc = blk >> 6;
    int b = bc >> 4, c = bc & 15;
    int tid = threadIdx.x;
    const int w = tid >> 6, lane = tid & 63;
    long tok0 = (long)(b*SEQ + c*CHUNKL);
    long base_h = (long)blk*128;
    if (tid < 128) csl[tid] = dacs[base_h + tid];
    __syncthreads();
    {
        int l = tid>>1, s0 = (tid&1)*64;
        float el = csl[l];
        const float* cbrow = cb + (long)bc*16384 + (long)l*128 + s0;
        #pragma unroll 8
        for (int j=0;j<64;j++){
            int s = s0 + j;
            float v = (s <= l) ? cbrow[j]*expf(el - csl[s]) : 0.f;
            A1[l*LP + s] = (bf16)v;
        }
    }
    #pragma unroll
    for (int t=0;t<4;t++){
        int s = (tid>>3) + t*32;
        int p0 = (tid&7)*8;
        bf16x8 xv = *(const bf16x8*)&xc[(tok0+s)*CONVD + h*64 + p0];
        float wv = dtv[base_h + s];
        #pragma unroll
        for (int e=0;e<8;e++) B1[(p0+e)*LP + s] = (bf16)((float)xv[e]*wv);
    }
    __syncthreads();
    f32x4v acc[2][4];
    #pragma unroll
    for (int mi=0;mi<2;mi++)
        #pragma unroll
        for (int ni=0;ni<4;ni++) acc[mi][ni] = {0.f,0.f,0.f,0.f};
    #pragma unroll
    for (int kk=0; kk<128; kk+=32){
        bf16x8 afr[2], bfr2[4];
        #pragma unroll
        for (int mi=0;mi<2;mi++)
            afr[mi] = *(const bf16x8*)&A1[(w*32 + mi*16 + (lane&15))*LP + kk + (lane>>4)*8];
        #pragma unroll
        for (int ni=0;ni<4;ni++)
            bfr2[ni] = *(const bf16x8*)&B1[(ni*16 + (lane&15))*LP + kk + (lane>>4)*8];
        #pragma unroll
        for (int mi=0;mi<2;mi++)
            #pragma unroll
            for (int ni=0;ni<4;ni++)
                acc[mi][ni] = __builtin_amdgcn_mfma_f32_16x16x32_bf16(afr[mi], bfr2[ni], acc[mi][ni], 0,0,0);
    }
    __syncthreads();
    {
        int l = tid>>1, n0 = (tid&1)*64;
        float e1 = expf(csl[l]);
        const bf16* crow = xc + (tok0+l)*CONVD + 4224;
        #pragma unroll
        for (int v=0;v<8;v++){
            bf16x8 cv = *(const bf16x8*)&crow[n0 + v*8];
            bf16x8 o;
            #pragma unroll
            for (int e=0;e<8;e++) o[e] = (bf16)((float)cv[e]*e1);
            *(bf16x8*)&A1[l*LP + n0 + v*8] = o;
        }
    }
    {
        int p = tid>>2, n0 = (tid&3)*32;
        const bf16* hrow = hst + (long)blk*8192 + (long)p*128 + n0;
        #pragma unroll
        for (int v=0;v<4;v++)
            *(bf16x8*)&B1[p*LP + n0 + v*8] = *(const bf16x8*)&hrow[v*8];
    }
    __syncthreads();
    #pragma unroll
    for (int kk=0; kk<128; kk+=32){
        bf16x8 afr[2], bfr2[4];
        #pragma unroll
        for (int mi=0;mi<2;mi++)
            afr[mi] = *(const bf16x8*)&A1[(w*32 + mi*16 + (lane&15))*LP + kk + (lane>>4)*8];
        #pragma unroll
        for (int ni=0;ni<4;ni++)
            bfr2[ni] = *(const bf16x8*)&B1[(ni*16 + (lane&15))*LP + kk + (lane>>4)*8];
        #pragma unroll
        for (int mi=0;mi<2;mi++)
            #pragma unroll
            for (int ni=0;ni<4;ni++)
                acc[mi][ni] = __builtin_amdgcn_mfma_f32_16x16x32_bf16(afr[mi], bfr2[ni], acc[mi][ni], 0,0,0);
    }
    #pragma unroll
    for (int mi=0;mi<2;mi++)
        #pragma unroll
        for (int ni=0;ni<4;ni++){
            int l0 = w*32 + mi*16 + (lane>>4)*4;
            int p  = ni*16 + (lane&15);
            #pragma unroll
            for (int j=0;j<4;j++)
                Ybf[(tok0 + l0 + j)*DI + h*64 + p] = (bf16)acc[mi][ni][j];
        }
}

// ---------------- gate (silu(z)) + D*x + RMSNorm + cast bf16 ----------------
__global__ __launch_bounds__(256) void gatenorm_kernel(const bf16* __restrict__ Ybf,
                                                       const bf16* __restrict__ zx,
                                                       const bf16* __restrict__ xc,
                                                       const float* __restrict__ Dp,
                                                       const float* __restrict__ nw,
                                                       bf16* __restrict__ ybn){
    __shared__ float red[4];
    int tok = blockIdx.x, tid = threadIdx.x;
    const bf16* yrow = Ybf + (long)tok*DI;
    const bf16* zrow = zx  + (long)tok*ZLD;
    const bf16* xrow = xc  + (long)tok*CONVD;
    float yg[16];
    float ss = 0.f;
    #pragma unroll
    for (int k=0;k<2;k++){
        int d = (tid + k*256)*8;
        bf16x8 yv = *(const bf16x8*)&yrow[d];
        bf16x8 zv = *(const bf16x8*)&zrow[d];
        bf16x8 xv = *(const bf16x8*)&xrow[d];
        float dh = Dp[d>>6];
        #pragma unroll
        for (int e=0;e<8;e++){
            float yy = (float)yv[e] + dh*(float)xv[e];
            float g = yy*silu_f((float)zv[e]);
            yg[k*8+e] = g;
            ss += g*g;
        }
    }
    #pragma unroll
    for (int off=32; off>0; off>>=1) ss += __shfl_down(ss, off, 64);
    if ((tid & 63) == 0) red[tid>>6] = ss;
    __syncthreads();
    float tot = red[0]+red[1]+red[2]+red[3];
    float scale = rsqrtf(tot/(float)DI + 1e-5f);
    #pragma unroll
    for (int k=0;k<2;k++){
        int d = (tid + k*256)*8;
        float4 w0 = *(const float4*)&nw[d];
        float4 w1 = *(const float4*)&nw[d+4];
        float wv[8] = {w0.x,w0.y,w0.z,w0.w,w1.x,w1.y,w1.z,w1.w};
        bf16x8 o;
        #pragma unroll
        for (int e=0;e<8;e++) o[e] = (bf16)(yg[k*8+e]*scale*wv[e]);
        *(bf16x8*)&ybn[(long)tok*DI + d] = o;
    }
}

// ---------------- launch ----------------
extern "C" void kernel_launch(void* const* d_in, const int* in_sizes, int n_in,
                              void* d_out, int out_size, void* d_ws, size_t ws_size,
                              hipStream_t stream){
    const float* hs      = (const float*)d_in[0];
    const float* W_in    = (const float*)d_in[1];
    const float* W_conv  = (const float*)d_in[2];
    const float* b_conv  = (const float*)d_in[3];
    const float* A_log   = (const float*)d_in[4];
    const float* Dp      = (const float*)d_in[5];
    const float* dt_bias = (const float*)d_in[6];
    const float* nw      = (const float*)d_in[7];
    const float* W_out   = (const float*)d_in[8];
    float* out = (float*)d_out;

    char* ws = (char*)d_ws;
    const size_t OFF_ZX    = 0;                    // bf16 [4096][8704]      71,303,168
    const size_t OFF_DTF   = 71303168;             // f32  [4096][64]         1,048,576
    const size_t OFF_XC    = 72351744;             // bf16 [4096][4352]      35,651,584
    const size_t OFF_DTV   = 108003328;            // f32                     1,048,576
    const size_t OFF_DACS  = 109051904;            //                         1,048,576
    const size_t OFF_CDEC  = 110100480;            // f32 [2048]                  8,192
    const size_t OFF_CB    = 110108672;            // f32 [32][128][128]      2,097,152
    const size_t OFF_SLOTA = 112205824;            // 67,108,864: hsb+winb -> states(bf16) -> Ybf
    const size_t OFF_SLOTB = 179314688;            // 33,554,432: tailpart -> hst(bf16) -> ybn
    const size_t OFF_WOUTB = 212869120;            // bf16 [2048][4096]      16,777,216

    bf16*  zx    = (bf16*)(ws + OFF_ZX);
    float* dtf   = (float*)(ws + OFF_DTF);
    bf16*  xc    = (bf16*)(ws + OFF_XC);
    float* dtv   = (float*)(ws + OFF_DTV);
    float* dacs  = (float*)(ws + OFF_DACS);
    float* cdec  = (float*)(ws + OFF_CDEC);
    float* cbuf  = (float*)(ws + OFF_CB);
    bf16*  hsb   = (bf16*)(ws + OFF_SLOTA);
    bf16*  winb  = (bf16*)(ws + OFF_SLOTA + 16777216);
    bf16*  states= (bf16*)(ws + OFF_SLOTA);
    bf16*  Ybf   = (bf16*)(ws + OFF_SLOTA);
    float* tpart = (float*)(ws + OFF_SLOTB);       // 4 x [4096][512] f32 GEMM1-tail partials
    bf16*  hst   = (bf16*)(ws + OFF_SLOTB);
    bf16*  ybn   = (bf16*)(ws + OFF_SLOTB);
    bf16*  woutb = (bf16*)(ws + OFF_WOUTB);

    cvt_all_kernel<<<33792, 256, 0, stream>>>(hs, W_in, W_out, hsb, winb, woutb);

    // GEMM1: merged bulk (512 blocks) + tail split-K=4 (128 blocks, first for packing)
    gemm1_kernel<<<640, 512, 0, stream>>>(hsb, winb, zx, tpart, 32, 16, DMODEL);
    tailreduce_kernel<<<2048, 256, 0, stream>>>(tpart, zx, dtf);

    conv_silu_kernel<<<dim3(5, 512), 256, 0, stream>>>(zx, W_conv, b_conv, xc);
    dtcum_kernel<<<512, 256, 0, stream>>>(dtf, A_log, dt_bias, dtv, dacs, cdec);
    cb_mfma_kernel<<<32, 256, 0, stream>>>(xc, cbuf);
    states_mfma_kernel<<<2048, 256, 0, stream>>>(xc, dtv, dacs, states);
    scan_kernel<<<4096, 256, 0, stream>>>(states, cdec, hst);
    yfused_kernel<<<2048, 256, 0, stream>>>(xc, cbuf, hst, dtv, dacs, Ybf);
    gatenorm_kernel<<<4096, 256, 0, stream>>>(Ybf, zx, xc, Dp, nw, ybn);

    // GEMM2: [4096,4096] x [2048,4096]^T -> out f32 direct (256x128 tiles, 1 round)
    gemm256x128_kernel<<<256, 512, 0, stream>>>(ybn, woutb, out, 16, 16, DI, DMODEL);
}

// Round 10
// 373.192 us; speedup vs baseline: 2.6023x; 1.1556x over previous
//
#include <hip/hip_runtime.h>
#include <hip/hip_bf16.h>
#include <stdint.h>

typedef __bf16 bf16;
typedef __bf16 bf16x8 __attribute__((ext_vector_type(8)));
typedef __bf16 bf16x4 __attribute__((ext_vector_type(4)));
typedef float f32x4v __attribute__((ext_vector_type(4)));

#define SEQ    2048
#define DMODEL 2048
#define DI     4096
#define NH     64
#define PDIM   64
#define CHUNKL 128
#define NCH    16
#define CONVD  4352
#define DPROJ  8512
#define ZLD    8704   // zxbcdt leading dim, padded to 34*256
#define NTOK   4096
#define LP     136    // padded LDS leading dim for middle kernels

__device__ __forceinline__ float sigmoid_f(float x){ return 1.f/(1.f+expf(-x)); }
__device__ __forceinline__ float silu_f(float x){ return x*sigmoid_f(x); }
__device__ __forceinline__ float softplus_f(float x){ return x > 20.f ? x : log1pf(expf(x)); }

// ---------------- fused conversions: hs->bf16 | W_in->bf16 padded | W_out->bf16 ----------------
__global__ __launch_bounds__(256) void cvt_all_kernel(const float* __restrict__ hs,
                                                      const float* __restrict__ W_in,
                                                      const float* __restrict__ W_out,
                                                      bf16* __restrict__ hsb,
                                                      bf16* __restrict__ winb,
                                                      bf16* __restrict__ woutb){
    int blk = blockIdx.x;
    if (blk < 8192){
        int i = (blk*256 + threadIdx.x)*4;
        float4 v = *(const float4*)&hs[i];
        bf16x4 o; o[0]=(bf16)v.x; o[1]=(bf16)v.y; o[2]=(bf16)v.z; o[3]=(bf16)v.w;
        *(bf16x4*)&hsb[i] = o;
    } else if (blk < 25600){
        int i = ((blk-8192)*256 + threadIdx.x)*4;   // over 8704*2048
        int r = i >> 11;
        bf16x4 o;
        if (r < DPROJ){
            float4 v = *(const float4*)&W_in[i];
            o[0]=(bf16)v.x; o[1]=(bf16)v.y; o[2]=(bf16)v.z; o[3]=(bf16)v.w;
        } else {
            o[0]=(bf16)0.f; o[1]=(bf16)0.f; o[2]=(bf16)0.f; o[3]=(bf16)0.f;
        }
        *(bf16x4*)&winb[i] = o;
    } else {
        int i = ((blk-25600)*256 + threadIdx.x)*4;
        float4 v = *(const float4*)&W_out[i];
        bf16x4 o; o[0]=(bf16)v.x; o[1]=(bf16)v.y; o[2]=(bf16)v.z; o[3]=(bf16)v.w;
        *(bf16x4*)&woutb[i] = o;
    }
}

// ============ shared GEMM fragment macros ============
#define READ_A(BUFP, QM)                                                               \
    {                                                                                  \
        _Pragma("unroll")                                                              \
        for (int i=0;i<4;i++)                                                          \
            _Pragma("unroll")                                                          \
            for (int k2=0;k2<2;k2++)                                                   \
                af[i][k2] = *(const bf16x8*)&(BUFP)[aoff[i][k2] + (QM)*8192];          \
    }

#define READ_B(BUFP, QN, BFR)                                                          \
    {                                                                                  \
        _Pragma("unroll")                                                              \
        for (int nf=0;nf<2;nf++)                                                       \
            _Pragma("unroll")                                                          \
            for (int k2=0;k2<2;k2++)                                                   \
                BFR[nf][k2] = *(const bf16x8*)&(BUFP)[boff[nf][k2] + (QN)*8192];       \
    }

#define MMA_Q(QM, QN, BFR)                                                             \
    {                                                                                  \
        __builtin_amdgcn_s_setprio(1);                                                 \
        _Pragma("unroll")                                                              \
        for (int i=0;i<4;i++)                                                          \
            _Pragma("unroll")                                                          \
            for (int nf=0;nf<2;nf++)                                                   \
                _Pragma("unroll")                                                      \
                for (int k2=0;k2<2;k2++)                                               \
                    acc[(QM)*4+i][(QN)*2+nf] = __builtin_amdgcn_mfma_f32_16x16x32_bf16( \
                        af[i][k2], BFR[nf][k2], acc[(QM)*4+i][(QN)*2+nf], 0,0,0);      \
        __builtin_amdgcn_s_setprio(0);                                                 \
    }

#define SBAR() do { __builtin_amdgcn_sched_barrier(0);                                 \
                    __builtin_amdgcn_s_barrier();                                      \
                    asm volatile("s_waitcnt lgkmcnt(0)" ::: "memory");                 \
                    __builtin_amdgcn_sched_barrier(0); } while(0)

// ============ GEMM1: bulk 256x256 2-phase (bid>=256) + tail 256x128 split-K4 (bid<256) ============
__global__ __launch_bounds__(512) void gemm1_kernel(const bf16* __restrict__ A,
                                                    const bf16* __restrict__ Bmat,
                                                    bf16* __restrict__ Cz,
                                                    float* __restrict__ tpart,
                                                    int NXB, int NYB, int K){
    __shared__ __align__(16) bf16 lds[2][2*16384];   // [buf][A(16384) | B(16384)]
    const int tid  = threadIdx.x;
    const int w    = tid >> 6;
    const int lane = tid & 63;
    const int wm   = w >> 2, wn = w & 3;
    const int bid  = blockIdx.x;

    int aoff[4][2], boff[2][2];
    #pragma unroll
    for (int i=0;i<4;i++)
        #pragma unroll
        for (int k2=0;k2<2;k2++){
            int ra0 = wm*64 + i*16 + (lane&15);
            int slot = (k2*4 + (lane>>4)) ^ (ra0&7);
            aoff[i][k2] = ra0*64 + slot*8;
        }
    #pragma unroll
    for (int nf=0;nf<2;nf++)
        #pragma unroll
        for (int k2=0;k2<2;k2++){
            int rb0 = wn*32 + nf*16 + (lane&15);
            int slot = (k2*4 + (lane>>4)) ^ (rb0&7);
            boff[nf][k2] = 16384 + rb0*64 + slot*8;
        }
    const int er = (lane>>4)*4, ec = lane&15;

    if (bid < 256){
        // ================= tail: 256x128 tile, split-K=4, KT=8 =================
        int kz  = bid >> 6;
        int t64 = bid & 63;
        const int tn2 = 8192 + (t64 & 3)*128;
        const int tm2 = (t64 >> 2)*256;
        const int kt0 = kz*8;

        const bf16* srcA2[2][2];
        const bf16* srcB2[2];
        #pragma unroll
        for (int r0h=0;r0h<2;r0h++)
            #pragma unroll
            for (int i=0;i<2;i++){
                int lr = r0h*128 + i*64 + (tid>>3);
                int growA = tm2 + ((lr>>6)&1)*128 + (lr>>7)*64 + (lr&63);
                int gslot = (tid&7) ^ (lr&7);
                srcA2[r0h][i] = A + (long)growA*K + gslot*8;
            }
        #pragma unroll
        for (int i=0;i<2;i++){
            int lr = i*64 + (tid>>3);
            int gslot = (tid&7) ^ (lr&7);
            srcB2[i] = Bmat + (long)(tn2 + lr)*K + gslot*8;
        }
        auto stA = [&](int buf, int t, int r0h){
            long koff = (long)(kt0 + t)*64;
            #pragma unroll
            for (int i=0;i<2;i++){
                bf16* dst = &lds[buf][0] + (size_t)(r0h*128 + i*64 + w*8)*64;
                __builtin_amdgcn_global_load_lds(
                    (const __attribute__((address_space(1))) void*)(srcA2[r0h][i] + koff),
                    (__attribute__((address_space(3))) void*)dst, 16, 0, 0);
            }
        };
        auto stB = [&](int buf, int t){
            long koff = (long)(kt0 + t)*64;
            #pragma unroll
            for (int i=0;i<2;i++){
                bf16* dst = &lds[buf][16384] + (size_t)(i*64 + w*8)*64;
                __builtin_amdgcn_global_load_lds(
                    (const __attribute__((address_space(1))) void*)(srcB2[i] + koff),
                    (__attribute__((address_space(3))) void*)dst, 16, 0, 0);
            }
        };

        f32x4v acc2[8][2];
        #pragma unroll
        for (int i=0;i<8;i++)
            #pragma unroll
            for (int j=0;j<2;j++) acc2[i][j] = {0.f,0.f,0.f,0.f};
        bf16x8 af[4][2], bfr0[2][2];

        stA(0,0,0); stA(0,0,1); stB(0,0);
        __syncthreads();
        int cur = 0;
        for (int t=0; t<8; ++t){
            int nxt = cur ^ 1;
            const bf16* bufc = &lds[cur][0];
            if (t+1 < 8){ stA(nxt,t+1,0); stA(nxt,t+1,1); stB(nxt,t+1); }
            READ_A(bufc, 0)
            READ_B(bufc, 0, bfr0)
            #pragma unroll
            for (int i=0;i<4;i++)
                #pragma unroll
                for (int nf=0;nf<2;nf++)
                    #pragma unroll
                    for (int k2=0;k2<2;k2++)
                        acc2[i][nf] = __builtin_amdgcn_mfma_f32_16x16x32_bf16(
                            af[i][k2], bfr0[nf][k2], acc2[i][nf], 0,0,0);
            READ_A(bufc, 1)
            #pragma unroll
            for (int i=0;i<4;i++)
                #pragma unroll
                for (int nf=0;nf<2;nf++)
                    #pragma unroll
                    for (int k2=0;k2<2;k2++)
                        acc2[4+i][nf] = __builtin_amdgcn_mfma_f32_16x16x32_bf16(
                            af[i][k2], bfr0[nf][k2], acc2[4+i][nf], 0,0,0);
            __syncthreads();
            cur = nxt;
        }
        #pragma unroll
        for (int mi=0;mi<8;mi++)
            #pragma unroll
            for (int nf=0;nf<2;nf++){
                long r0 = tm2 + wm*128 + mi*16 + er;
                int  c0 = tn2 + wn*32 + nf*16 + ec;
                #pragma unroll
                for (int j=0;j<4;j++)
                    tpart[((long)kz*4096 + (r0+j))*512 + (c0 - 8192)] = acc2[mi][nf][j];
            }
        return;
    }

    // ================= bulk: 256x256 2-phase =================
    int bid2 = bid - 256;             // 0..511
    int wg   = (bid2 & 7)*64 + (bid2 >> 3);
    const int SW = 8;
    int sup = wg / (SW*NYB);
    int rr  = wg % (SW*NYB);
    int x0  = sup*SW;
    int wl  = (NXB - x0 < SW) ? (NXB - x0) : SW;
    int x   = x0 + rr % wl;
    int y   = rr / wl;
    const int tm = y*256, tn = x*256;
    const int KT = K >> 6;

    f32x4v acc[8][4];
    #pragma unroll
    for (int i=0;i<8;i++)
        #pragma unroll
        for (int j=0;j<4;j++) acc[i][j] = {0.f,0.f,0.f,0.f};
    bf16x8 af[4][2];
    bf16x8 bfr0[2][2], bfr1[2][2];

    const bf16* srcA[2][2];
    const bf16* srcB[2][2];
    #pragma unroll
    for (int r0h=0;r0h<2;r0h++)
        #pragma unroll
        for (int i=0;i<2;i++){
            int lr = r0h*128 + i*64 + (tid>>3);
            int growA = tm + ((lr>>6)&1)*128 + (lr>>7)*64 + (lr&63);
            int growB = tn + ((lr>>5)&3)*64 + (lr>>7)*32 + (lr&31);
            int gslot = (tid&7) ^ (lr&7);
            srcA[r0h][i] = A + (long)growA*K + gslot*8;
            srcB[r0h][i] = Bmat + (long)growB*K + gslot*8;
        }

    auto stageA = [&](int buf, int t, int r0h){
        long koff = (long)t*64;
        #pragma unroll
        for (int i=0;i<2;i++){
            bf16* dst = &lds[buf][0] + (size_t)(r0h*128 + i*64 + w*8)*64;
            __builtin_amdgcn_global_load_lds(
                (const __attribute__((address_space(1))) void*)(srcA[r0h][i] + koff),
                (__attribute__((address_space(3))) void*)dst, 16, 0, 0);
        }
    };
    auto stageB = [&](int buf, int t, int r0h){
        long koff = (long)t*64;
        #pragma unroll
        for (int i=0;i<2;i++){
            bf16* dst = &lds[buf][16384] + (size_t)(r0h*128 + i*64 + w*8)*64;
            __builtin_amdgcn_global_load_lds(
                (const __attribute__((address_space(1))) void*)(srcB[r0h][i] + koff),
                (__attribute__((address_space(3))) void*)dst, 16, 0, 0);
        }
    };

    stageA(0, 0, 0); stageB(0, 0, 0); stageA(0, 0, 1); stageB(0, 0, 1);
    if (KT > 1){ stageA(1, 1, 0); stageB(1, 1, 0); stageA(1, 1, 1); stageB(1, 1, 1); }
    asm volatile("s_waitcnt vmcnt(8)" ::: "memory");
    __builtin_amdgcn_s_barrier();

    int cur = 0;
    for (int t = 0; t < KT; ++t){
        int nxt = cur ^ 1;
        const bf16* bufc = &lds[cur][0];
        // ---- PhA: quadrants (0,0) and (0,1) ----
        READ_A(bufc, 0)
        READ_B(bufc, 0, bfr0)
        READ_B(bufc, 1, bfr1)
        if (t+1 < KT){ asm volatile("s_waitcnt vmcnt(8)" ::: "memory"); }
        else         { asm volatile("s_waitcnt vmcnt(0)" ::: "memory"); }
        SBAR();
        MMA_Q(0, 0, bfr0)
        MMA_Q(0, 1, bfr1)
        __builtin_amdgcn_sched_barrier(0);
        if (t+2 < KT){ stageA(cur, t+2, 0); stageB(cur, t+2, 0); }
        // ---- PhB: quadrants (1,0) and (1,1) ----
        READ_A(bufc, 1)
        SBAR();
        MMA_Q(1, 0, bfr0)
        MMA_Q(1, 1, bfr1)
        __builtin_amdgcn_sched_barrier(0);
        if (t+2 < KT){ stageA(cur, t+2, 1); stageB(cur, t+2, 1); }
        cur = nxt;
    }

    #pragma unroll
    for (int mi=0;mi<8;mi++)
        #pragma unroll
        for (int ni=0;ni<4;ni++){
            long r0 = tm + wm*128 + mi*16 + er;
            int  c0 = tn + wn*64 + ni*16 + ec;
            #pragma unroll
            for (int j=0;j<4;j++)
                Cz[(r0+j)*ZLD + c0] = (bf16)acc[mi][ni][j];
        }
}

// ============ 256x128 triple-buffered bf16 GEMM (GEMM2): C(f32) = A * B^T ============
__global__ __launch_bounds__(512) void gemm256x128_kernel(const bf16* __restrict__ A,
                                                          const bf16* __restrict__ Bmat,
                                                          float* __restrict__ C,
                                                          int NXB, int NYB, int K, int ldc){
    __shared__ __align__(16) bf16 lds[3][24576];   // [buf][A(16384) | B(8192)]
    const int tid  = threadIdx.x;
    const int w    = tid >> 6;
    const int lane = tid & 63;
    const int wm   = w >> 2, wn = w & 3;

    int bid = blockIdx.x, nb = gridDim.x;
    int wg = (bid & 7)*(nb >> 3) + (bid >> 3);
    const int SW = 8;
    int sup = wg / (SW*NYB);
    int rr  = wg % (SW*NYB);
    int x0  = sup*SW;
    int wl  = (NXB - x0 < SW) ? (NXB - x0) : SW;
    int x   = x0 + rr % wl;
    int y   = rr / wl;
    const int tm = y*256, tn = x*128;
    const int KT = K >> 6;

    f32x4v acc[8][2];
    #pragma unroll
    for (int i=0;i<8;i++)
        #pragma unroll
        for (int j=0;j<2;j++) acc[i][j] = {0.f,0.f,0.f,0.f};
    bf16x8 af[4][2];
    bf16x8 bfr[2][2];

    const bf16* srcA[2][2];
    const bf16* srcB[2];
    #pragma unroll
    for (int r0h=0;r0h<2;r0h++)
        #pragma unroll
        for (int i=0;i<2;i++){
            int lr = r0h*128 + i*64 + (tid>>3);
            int growA = tm + ((lr>>6)&1)*128 + (lr>>7)*64 + (lr&63);
            int gslot = (tid&7) ^ (lr&7);
            srcA[r0h][i] = A + (long)growA*K + gslot*8;
        }
    #pragma unroll
    for (int i=0;i<2;i++){
        int lr = i*64 + (tid>>3);
        int gslot = (tid&7) ^ (lr&7);
        srcB[i] = Bmat + (long)(tn + lr)*K + gslot*8;
    }
    int aoff[4][2], boff[2][2];
    #pragma unroll
    for (int i=0;i<4;i++)
        #pragma unroll
        for (int k2=0;k2<2;k2++){
            int ra0 = wm*64 + i*16 + (lane&15);
            int slot = (k2*4 + (lane>>4)) ^ (ra0&7);
            aoff[i][k2] = ra0*64 + slot*8;
        }
    #pragma unroll
    for (int nf=0;nf<2;nf++)
        #pragma unroll
        for (int k2=0;k2<2;k2++){
            int rb0 = wn*32 + nf*16 + (lane&15);
            int slot = (k2*4 + (lane>>4)) ^ (rb0&7);
            boff[nf][k2] = 16384 + rb0*64 + slot*8;
        }

    auto stageA = [&](int buf, int t, int r0h){
        long koff = (long)t*64;
        #pragma unroll
        for (int i=0;i<2;i++){
            bf16* dst = &lds[buf][0] + (size_t)(r0h*128 + i*64 + w*8)*64;
            __builtin_amdgcn_global_load_lds(
                (const __attribute__((address_space(1))) void*)(srcA[r0h][i] + koff),
                (__attribute__((address_space(3))) void*)dst, 16, 0, 0);
        }
    };
    auto stageB = [&](int buf, int t){
        long koff = (long)t*64;
        #pragma unroll
        for (int i=0;i<2;i++){
            bf16* dst = &lds[buf][16384] + (size_t)(i*64 + w*8)*64;
            __builtin_amdgcn_global_load_lds(
                (const __attribute__((address_space(1))) void*)(srcB[i] + koff),
                (__attribute__((address_space(3))) void*)dst, 16, 0, 0);
        }
    };

    stageA(0, 0, 0); stageA(0, 0, 1); stageB(0, 0);
    if (KT > 1){ stageA(1, 1, 0); stageA(1, 1, 1); stageB(1, 1); }
    asm volatile("s_waitcnt vmcnt(6)" ::: "memory");
    __builtin_amdgcn_s_barrier();

    int cur = 0;
    for (int t = 0; t < KT; ++t){
        int stb = cur + 2; if (stb >= 3) stb -= 3;
        const bf16* bufc = &lds[cur][0];
        READ_A(bufc, 0)
        READ_B(bufc, 0, bfr)
        if (t+2 < KT){ stageA(stb, t+2, 0); stageA(stb, t+2, 1); }
        SBAR();
        MMA_Q(0, 0, bfr)
        READ_A(bufc, 1)
        if (t+2 < KT){
            stageB(stb, t+2);
            asm volatile("s_waitcnt vmcnt(6)" ::: "memory");
        } else {
            asm volatile("s_waitcnt vmcnt(0)" ::: "memory");
        }
        SBAR();
        MMA_Q(1, 0, bfr)
        cur = (cur == 2) ? 0 : cur + 1;
    }

    const int er = (lane>>4)*4, ec = lane&15;
    #pragma unroll
    for (int mi=0;mi<8;mi++)
        #pragma unroll
        for (int ni=0;ni<2;ni++){
            long r0 = tm + wm*128 + mi*16 + er;
            int  c0 = tn + wn*32 + ni*16 + ec;
            #pragma unroll
            for (int j=0;j<4;j++)
                C[(r0+j)*ldc + c0] = acc[mi][ni][j];
        }
}

// ---------------- GEMM1 tail reduce: 4 f32 partials -> zx bf16 + dtf f32 ----------------
__global__ __launch_bounds__(256) void tailreduce_kernel(const float* __restrict__ p,
                                                         bf16* __restrict__ zx,
                                                         float* __restrict__ dtf){
    long i = ((long)blockIdx.x*256 + threadIdx.x)*4;   // over 4096*512
    int r = (int)(i >> 9);
    int c = (int)(i & 511);
    const long Q = (long)4096*512;
    float4 a  = *(const float4*)&p[i];
    float4 b  = *(const float4*)&p[i+Q];
    float4 cc = *(const float4*)&p[i+2*Q];
    float4 d  = *(const float4*)&p[i+3*Q];
    float s0 = a.x+b.x+cc.x+d.x, s1 = a.y+b.y+cc.y+d.y;
    float s2 = a.z+b.z+cc.z+d.z, s3 = a.w+b.w+cc.w+d.w;
    bf16x4 o; o[0]=(bf16)s0; o[1]=(bf16)s1; o[2]=(bf16)s2; o[3]=(bf16)s3;
    *(bf16x4*)&zx[(long)r*ZLD + 8192 + c] = o;
    int col = 8192 + c;
    float sv[4] = {s0,s1,s2,s3};
    #pragma unroll
    for (int j=0;j<4;j++){
        int cj = col + j;
        if (cj >= 8448 && cj < 8512) dtf[(long)r*64 + (cj-8448)] = sv[j];
    }
}

// ---------------- merged: conv (blocks 0..2559) + dtcum (blocks 2560..3071) ----------------
__global__ __launch_bounds__(256) void mid1_kernel(const bf16* __restrict__ zx,
                                                   const float* __restrict__ Wc,
                                                   const float* __restrict__ bc,
                                                   const float* __restrict__ dtf,
                                                   const float* __restrict__ A_log,
                                                   const float* __restrict__ dt_bias,
                                                   bf16* __restrict__ xc,
                                                   float* __restrict__ dtv,
                                                   float* __restrict__ dacs,
                                                   float* __restrict__ cdec){
    int blk = blockIdx.x;
    if (blk < 2560){
        // ---- depthwise causal conv(4) + bias + silu, 4ch x 8tok per thread ----
        int by = blk/5, bx = blk%5;
        int c4 = bx*256 + threadIdx.x;
        if (c4 >= 1088) return;
        int ch = c4*4;
        int b = by >> 8, t0 = (by & 255)*8;
        float4 tap[4];
        #pragma unroll
        for (int e=0;e<4;e++) tap[e] = *(const float4*)&Wc[(ch+e)*4];
        float4 bq = *(const float4*)&bc[ch];
        float bca[4] = {bq.x, bq.y, bq.z, bq.w};
        const bf16* col = zx + (long)(b*SEQ)*ZLD + 4096 + ch;
        bf16x4 v[11];
        #pragma unroll
        for (int k=0;k<11;k++){
            int t = t0 - 3 + k;
            if (t >= 0) v[k] = *(const bf16x4*)&col[(long)t*ZLD];
            else { v[k][0]=(bf16)0.f; v[k][1]=(bf16)0.f; v[k][2]=(bf16)0.f; v[k][3]=(bf16)0.f; }
        }
        #pragma unroll
        for (int j=0;j<8;j++){
            bf16x4 o;
            #pragma unroll
            for (int e=0;e<4;e++){
                float acc = bca[e] + (float)v[j][e]*tap[e].x + (float)v[j+1][e]*tap[e].y
                                   + (float)v[j+2][e]*tap[e].z + (float)v[j+3][e]*tap[e].w;
                o[e] = (bf16)silu_f(acc);
            }
            *(bf16x4*)&xc[(long)(b*SEQ + t0 + j)*CONVD + ch] = o;
        }
    } else {
        // ---- dt softplus + per-chunk cumsum (wave-parallel prefix scan) ----
        int wid  = ((blk-2560)*256 + threadIdx.x) >> 6;   // 0..2047
        int lane = threadIdx.x & 63;
        int h  = wid & 63, bc2 = wid >> 6;
        int b  = bc2 >> 4,  c  = bc2 & 15;
        float Ah   = -expf(A_log[h]);
        float bias = dt_bias[h];
        long tok0 = (long)(b*SEQ + c*CHUNKL);
        int l0 = lane*2;
        float d0 = softplus_f(dtf[(tok0+l0)*64 + h] + bias);
        float d1 = softplus_f(dtf[(tok0+l0+1)*64 + h] + bias);
        float s = (d0 + d1)*Ah;
        #pragma unroll
        for (int off=1; off<64; off<<=1){
            float t = __shfl_up(s, off, 64);
            if (lane >= off) s += t;
        }
        long base_h = (long)wid*128;
        float cs1 = s;
        float cs0 = s - d1*Ah;
        dtv[base_h+l0]   = d0;  dtv[base_h+l0+1]  = d1;
        dacs[base_h+l0]  = cs0; dacs[base_h+l0+1] = cs1;
        if (lane == 63) cdec[wid] = expf(cs1);
    }
}

// ---------------- CB via MFMA, per (b,c); side output BT[bc][n][l] ----------------
__global__ __launch_bounds__(256) void cb_mfma_kernel(const bf16* __restrict__ xc,
                                                      float* __restrict__ cb,
                                                      bf16* __restrict__ BT){
    __shared__ __align__(16) bf16 A1[128*LP];
    __shared__ __align__(16) bf16 B1[128*LP];
    int blk = blockIdx.x;  int b = blk>>4, c = blk&15;
    int tid = threadIdx.x;
    const int w = tid >> 6, lane = tid & 63;
    long tok0 = (long)(b*SEQ + c*CHUNKL);
    int l = tid>>1, n0 = (tid&1)*64;
    const bf16* crow = xc + tok0*CONVD + (long)l*CONVD;
    #pragma unroll
    for (int v=0;v<8;v++){
        *(bf16x8*)&A1[l*LP + n0 + v*8] = *(const bf16x8*)&crow[4224 + n0 + v*8];
        *(bf16x8*)&B1[l*LP + n0 + v*8] = *(const bf16x8*)&crow[4096 + n0 + v*8];
    }
    __syncthreads();
    f32x4v acc[2][8];
    #pragma unroll
    for (int mi=0;mi<2;mi++)
        #pragma unroll
        for (int ni=0;ni<8;ni++) acc[mi][ni] = {0.f,0.f,0.f,0.f};
    #pragma unroll
    for (int kk=0; kk<128; kk+=32){
        bf16x8 afr[2], bfr2[8];
        #pragma unroll
        for (int mi=0;mi<2;mi++)
            afr[mi] = *(const bf16x8*)&A1[(w*32 + mi*16 + (lane&15))*LP + kk + (lane>>4)*8];
        #pragma unroll
        for (int ni=0;ni<8;ni++)
            bfr2[ni] = *(const bf16x8*)&B1[(ni*16 + (lane&15))*LP + kk + (lane>>4)*8];
        #pragma unroll
        for (int mi=0;mi<2;mi++)
            #pragma unroll
            for (int ni=0;ni<8;ni++)
                acc[mi][ni] = __builtin_amdgcn_mfma_f32_16x16x32_bf16(afr[mi], bfr2[ni], acc[mi][ni], 0,0,0);
    }
    float* out = cb + (long)blk*16384;
    #pragma unroll
    for (int mi=0;mi<2;mi++)
        #pragma unroll
        for (int ni=0;ni<8;ni++){
            int r0 = w*32 + mi*16 + (lane>>4)*4;
            int c0 = ni*16 + (lane&15);
            #pragma unroll
            for (int j=0;j<4;j++) out[(long)(r0+j)*128 + c0] = acc[mi][ni][j];
        }
    // BT side output: BT[blk][n][s] = B[s][n]
    {
        int n = tid>>1, s0 = (tid&1)*64;
        bf16* btp = BT + (long)blk*16384 + (long)n*128 + s0;
        #pragma unroll
        for (int v=0;v<8;v++){
            bf16x8 o;
            #pragma unroll
            for (int e=0;e<8;e++) o[e] = B1[(s0+v*8+e)*LP + n];
            *(bf16x8*)&btp[v*8] = o;
        }
    }
}

// ---------------- states[p][n] via MFMA, per (b,c,h), bf16 out; B from BT (vector) ----------------
__global__ __launch_bounds__(256) void states_mfma_kernel(const bf16* __restrict__ xc,
                                                          const bf16* __restrict__ BT,
                                                          const float* __restrict__ dtv,
                                                          const float* __restrict__ dacs,
                                                          bf16* __restrict__ states){
    __shared__ __align__(16) bf16 A1[64*LP];
    __shared__ __align__(16) bf16 B1[128*LP];
    __shared__ float wgtl[128];
    int blk = blockIdx.x;
    int h = blk & 63, bc = blk >> 6;
    int b = bc >> 4, c = bc & 15;
    int tid = threadIdx.x;
    const int w = tid >> 6, lane = tid & 63;
    long tok0 = (long)(b*SEQ + c*CHUNKL);
    long base_h = (long)blk*128;
    float cs_last = dacs[base_h + 127];
    if (tid < 128) wgtl[tid] = dtv[base_h+tid] * expf(cs_last - dacs[base_h+tid]);
    __syncthreads();
    #pragma unroll
    for (int t=0;t<4;t++){
        int l = (tid>>3) + t*32;
        int p0 = (tid&7)*8;
        bf16x8 xv = *(const bf16x8*)&xc[(tok0+l)*CONVD + h*64 + p0];
        float wv = wgtl[l];
        #pragma unroll
        for (int e=0;e<8;e++) A1[(p0+e)*LP + l] = (bf16)((float)xv[e]*wv);
    }
    {
        int n = tid>>1, l0 = (tid&1)*64;
        const bf16* btp = BT + (long)bc*16384 + (long)n*128 + l0;
        #pragma unroll
        for (int v=0;v<8;v++)
            *(bf16x8*)&B1[n*LP + l0 + v*8] = *(const bf16x8*)&btp[v*8];
    }
    __syncthreads();
    f32x4v acc[8];
    #pragma unroll
    for (int ni=0;ni<8;ni++) acc[ni] = {0.f,0.f,0.f,0.f};
    #pragma unroll
    for (int kk=0; kk<128; kk+=32){
        bf16x8 afr = *(const bf16x8*)&A1[(w*16 + (lane&15))*LP + kk + (lane>>4)*8];
        #pragma unroll
        for (int ni=0;ni<8;ni++){
            bf16x8 bfr2 = *(const bf16x8*)&B1[(ni*16 + (lane&15))*LP + kk + (lane>>4)*8];
            acc[ni] = __builtin_amdgcn_mfma_f32_16x16x32_bf16(afr, bfr2, acc[ni], 0,0,0);
        }
    }
    bf16* out = states + (long)blk*8192;
    #pragma unroll
    for (int ni=0;ni<8;ni++){
        int p0 = w*16 + (lane>>4)*4;
        int n  = ni*16 + (lane&15);
        #pragma unroll
        for (int j=0;j<4;j++) out[(long)(p0+j)*128 + n] = (bf16)acc[ni][j];
    }
}

// ---------------- sequential chunk scan (bf16 in/out, f32 accum) ----------------
__global__ __launch_bounds__(256) void scan_kernel(const bf16* __restrict__ states,
                                                   const float* __restrict__ cdec,
                                                   bf16* __restrict__ hst){
    long gid = (long)blockIdx.x*256 + threadIdx.x;
    int n = gid & 127;
    int p = (gid >> 7) & 63;
    int h = (gid >> 13) & 63;
    int b = (int)(gid >> 19);
    float hrun = 0.f;
    for (int c=0;c<16;c++){
        long idx = ((((long)(b*16 + c)*64 + h)*64 + p)*128) + n;
        hst[idx] = (bf16)hrun;
        hrun = hrun * cdec[(b*16+c)*64 + h] + (float)states[idx];
    }
}

// ---------------- fused Y = P@u^T + (C*sdo)@hst^T ----------------
__global__ __launch_bounds__(256) void yfused_kernel(const bf16* __restrict__ xc,
                                                     const float* __restrict__ cb,
                                                     const bf16* __restrict__ hst,
                                                     const float* __restrict__ dtv,
                                                     const float* __restrict__ dacs,
                                                     bf16* __restrict__ Ybf){
    __shared__ __align__(16) bf16 A1[128*LP];
    __shared__ __align__(16) bf16 B1[64*LP];
    __shared__ float csl[128];
    int blk = blockIdx.x;
    int h = blk & 63, bc = blk >> 6;
    int b = bc >> 4, c = bc & 15;
    int tid = threadIdx.x;
    const int w = tid >> 6, lane = tid & 63;
    long tok0 = (long)(b*SEQ + c*CHUNKL);
    long base_h = (long)blk*128;
    if (tid < 128) csl[tid] = dacs[base_h + tid];
    __syncthreads();
    {
        int l = tid>>1, s0 = (tid&1)*64;
        float el = csl[l];
        const float* cbrow = cb + (long)bc*16384 + (long)l*128 + s0;
        int jend = l - s0; if (jend > 63) jend = 63;
        for (int j=0; j<=jend; j++)
            A1[l*LP + s0 + j] = (bf16)(cbrow[j]*expf(el - csl[s0+j]));
        for (int j=jend+1; j<64; j++)
            A1[l*LP + s0 + j] = (bf16)0.f;
    }
    #pragma unroll
    for (int t=0;t<4;t++){
        int s = (tid>>3) + t*32;
        int p0 = (tid&7)*8;
        bf16x8 xv = *(const bf16x8*)&xc[(tok0+s)*CONVD + h*64 + p0];
        float wv = dtv[base_h + s];
        #pragma unroll
        for (int e=0;e<8;e++) B1[(p0+e)*LP + s] = (bf16)((float)xv[e]*wv);
    }
    __syncthreads();
    f32x4v acc[2][4];
    #pragma unroll
    for (int mi=0;mi<2;mi++)
        #pragma unroll
        for (int ni=0;ni<4;ni++) acc[mi][ni] = {0.f,0.f,0.f,0.f};
    #pragma unroll
    for (int kk=0; kk<128; kk+=32){
        bf16x8 afr[2], bfr2[4];
        #pragma unroll
        for (int mi=0;mi<2;mi++)
            afr[mi] = *(const bf16x8*)&A1[(w*32 + mi*16 + (lane&15))*LP + kk + (lane>>4)*8];
        #pragma unroll
        for (int ni=0;ni<4;ni++)
            bfr2[ni] = *(const bf16x8*)&B1[(ni*16 + (lane&15))*LP + kk + (lane>>4)*8];
        #pragma unroll
        for (int mi=0;mi<2;mi++)
            #pragma unroll
            for (int ni=0;ni<4;ni++)
                acc[mi][ni] = __builtin_amdgcn_mfma_f32_16x16x32_bf16(afr[mi], bfr2[ni], acc[mi][ni], 0,0,0);
    }
    __syncthreads();
    {
        int l = tid>>1, n0 = (tid&1)*64;
        float e1 = expf(csl[l]);
        const bf16* crow = xc + (tok0+l)*CONVD + 4224;
        #pragma unroll
        for (int v=0;v<8;v++){
            bf16x8 cv = *(const bf16x8*)&crow[n0 + v*8];
            bf16x8 o;
            #pragma unroll
            for (int e=0;e<8;e++) o[e] = (bf16)((float)cv[e]*e1);
            *(bf16x8*)&A1[l*LP + n0 + v*8] = o;
        }
    }
    {
        int p = tid>>2, n0 = (tid&3)*32;
        const bf16* hrow = hst + (long)blk*8192 + (long)p*128 + n0;
        #pragma unroll
        for (int v=0;v<4;v++)
            *(bf16x8*)&B1[p*LP + n0 + v*8] = *(const bf16x8*)&hrow[v*8];
    }
    __syncthreads();
    #pragma unroll
    for (int kk=0; kk<128; kk+=32){
        bf16x8 afr[2], bfr2[4];
        #pragma unroll
        for (int mi=0;mi<2;mi++)
            afr[mi] = *(const bf16x8*)&A1[(w*32 + mi*16 + (lane&15))*LP + kk + (lane>>4)*8];
        #pragma unroll
        for (int ni=0;ni<4;ni++)
            bfr2[ni] = *(const bf16x8*)&B1[(ni*16 + (lane&15))*LP + kk + (lane>>4)*8];
        #pragma unroll
        for (int mi=0;mi<2;mi++)
            #pragma unroll
            for (int ni=0;ni<4;ni++)
                acc[mi][ni] = __builtin_amdgcn_mfma_f32_16x16x32_bf16(afr[mi], bfr2[ni], acc[mi][ni], 0,0,0);
    }
    #pragma unroll
    for (int mi=0;mi<2;mi++)
        #pragma unroll
        for (int ni=0;ni<4;ni++){
            int l0 = w*32 + mi*16 + (lane>>4)*4;
            int p  = ni*16 + (lane&15);
            #pragma unroll
            for (int j=0;j<4;j++)
                Ybf[(tok0 + l0 + j)*DI + h*64 + p] = (bf16)acc[mi][ni][j];
        }
}

// ---------------- gate (silu(z)) + D*x + RMSNorm + cast bf16 ----------------
__global__ __launch_bounds__(256) void gatenorm_kernel(const bf16* __restrict__ Ybf,
                                                       const bf16* __restrict__ zx,
                                                       const bf16* __restrict__ xc,
                                                       const float* __restrict__ Dp,
                                                       const float* __restrict__ nw,
                                                       bf16* __restrict__ ybn){
    __shared__ float red[4];
    int tok = blockIdx.x, tid = threadIdx.x;
    const bf16* yrow = Ybf + (long)tok*DI;
    const bf16* zrow = zx  + (long)tok*ZLD;
    const bf16* xrow = xc  + (long)tok*CONVD;
    float yg[16];
    float ss = 0.f;
    #pragma unroll
    for (int k=0;k<2;k++){
        int d = (tid + k*256)*8;
        bf16x8 yv = *(const bf16x8*)&yrow[d];
        bf16x8 zv = *(const bf16x8*)&zrow[d];
        bf16x8 xv = *(const bf16x8*)&xrow[d];
        float dh = Dp[d>>6];
        #pragma unroll
        for (int e=0;e<8;e++){
            float yy = (float)yv[e] + dh*(float)xv[e];
            float g = yy*silu_f((float)zv[e]);
            yg[k*8+e] = g;
            ss += g*g;
        }
    }
    #pragma unroll
    for (int off=32; off>0; off>>=1) ss += __shfl_down(ss, off, 64);
    if ((tid & 63) == 0) red[tid>>6] = ss;
    __syncthreads();
    float tot = red[0]+red[1]+red[2]+red[3];
    float scale = rsqrtf(tot/(float)DI + 1e-5f);
    #pragma unroll
    for (int k=0;k<2;k++){
        int d = (tid + k*256)*8;
        float4 w0 = *(const float4*)&nw[d];
        float4 w1 = *(const float4*)&nw[d+4];
        float wv[8] = {w0.x,w0.y,w0.z,w0.w,w1.x,w1.y,w1.z,w1.w};
        bf16x8 o;
        #pragma unroll
        for (int e=0;e<8;e++) o[e] = (bf16)(yg[k*8+e]*scale*wv[e]);
        *(bf16x8*)&ybn[(long)tok*DI + d] = o;
    }
}

// ---------------- launch ----------------
extern "C" void kernel_launch(void* const* d_in, const int* in_sizes, int n_in,
                              void* d_out, int out_size, void* d_ws, size_t ws_size,
                              hipStream_t stream){
    const float* hs      = (const float*)d_in[0];
    const float* W_in    = (const float*)d_in[1];
    const float* W_conv  = (const float*)d_in[2];
    const float* b_conv  = (const float*)d_in[3];
    const float* A_log   = (const float*)d_in[4];
    const float* Dp      = (const float*)d_in[5];
    const float* dt_bias = (const float*)d_in[6];
    const float* nw      = (const float*)d_in[7];
    const float* W_out   = (const float*)d_in[8];
    float* out = (float*)d_out;

    char* ws = (char*)d_ws;
    const size_t OFF_ZX    = 0;                    // bf16 [4096][8704]      71,303,168
    const size_t OFF_DTF   = 71303168;             // f32  [4096][64]         1,048,576
    const size_t OFF_XC    = 72351744;             // bf16 [4096][4352]      35,651,584
    const size_t OFF_DTV   = 108003328;            // f32                     1,048,576
    const size_t OFF_DACS  = 109051904;            //                         1,048,576
    const size_t OFF_CDEC  = 110100480;            // f32 [2048]                  8,192
    const size_t OFF_CB    = 110108672;            // f32 [32][128][128]      2,097,152
    const size_t OFF_SLOTA = 112205824;            // 67,108,864: hsb+winb -> states(bf16) -> Ybf
    const size_t OFF_SLOTB = 179314688;            // 33,554,432: tailpart -> BT -> hst(bf16) -> ybn
    const size_t OFF_WOUTB = 212869120;            // bf16 [2048][4096]      16,777,216

    bf16*  zx    = (bf16*)(ws + OFF_ZX);
    float* dtf   = (float*)(ws + OFF_DTF);
    bf16*  xc    = (bf16*)(ws + OFF_XC);
    float* dtv   = (float*)(ws + OFF_DTV);
    float* dacs  = (float*)(ws + OFF_DACS);
    float* cdec  = (float*)(ws + OFF_CDEC);
    float* cbuf  = (float*)(ws + OFF_CB);
    bf16*  hsb   = (bf16*)(ws + OFF_SLOTA);
    bf16*  winb  = (bf16*)(ws + OFF_SLOTA + 16777216);
    bf16*  states= (bf16*)(ws + OFF_SLOTA);
    bf16*  Ybf   = (bf16*)(ws + OFF_SLOTA);
    float* tpart = (float*)(ws + OFF_SLOTB);       // 4 x [4096][512] f32 GEMM1-tail partials
    bf16*  BTb   = (bf16*)(ws + OFF_SLOTB);        // bf16 [32][128][128] (1MB), after tailreduce
    bf16*  hst   = (bf16*)(ws + OFF_SLOTB);        // written by scan (after states consumed BT)
    bf16*  ybn   = (bf16*)(ws + OFF_SLOTB);
    bf16*  woutb = (bf16*)(ws + OFF_WOUTB);

    cvt_all_kernel<<<33792, 256, 0, stream>>>(hs, W_in, W_out, hsb, winb, woutb);

    // GEMM1: 256 tail blocks (256x128, split-K=4) + 512 bulk blocks (256x256)
    gemm1_kernel<<<768, 512, 0, stream>>>(hsb, winb, zx, tpart, 32, 16, DMODEL);
    tailreduce_kernel<<<2048, 256, 0, stream>>>(tpart, zx, dtf);

    mid1_kernel<<<3072, 256, 0, stream>>>(zx, W_conv, b_conv, dtf, A_log, dt_bias,
                                          xc, dtv, dacs, cdec);
    cb_mfma_kernel<<<32, 256, 0, stream>>>(xc, cbuf, BTb);
    states_mfma_kernel<<<2048, 256, 0, stream>>>(xc, BTb, dtv, dacs, states);
    scan_kernel<<<4096, 256, 0, stream>>>(states, cdec, hst);
    yfused_kernel<<<2048, 256, 0, stream>>>(xc, cbuf, hst, dtv, dacs, Ybf);
    gatenorm_kernel<<<4096, 256, 0, stream>>>(Ybf, zx, xc, Dp, nw, ybn);

    // GEMM2: [4096,4096] x [2048,4096]^T -> out f32 direct (256x128 tiles, 1 round)
    gemm256x128_kernel<<<256, 512, 0, stream>>>(ybn, woutb, out, 16, 16, DI, DMODEL);
}